// Round 2
// baseline (1941.092 us; speedup 1.0000x reference)
//
#include <hip/hip_runtime.h>
#include <math.h>

static constexpr int SS = 4096;   // substructures
static constexpr int HH = 128;    // hidden
static constexpr float EPS_BN = 1e-5f;

// ---------- substructure attention ----------

__global__ void gcn_subst_accum(const float* __restrict__ x, float* __restrict__ cnt,
                                float* __restrict__ sums, int n) {
  int node = blockIdx.x * 4 + (threadIdx.x >> 6);
  int lane = threadIdx.x & 63;
  if (node >= n) return;
  const float* xr = x + (size_t)node * 64;
  float v = xr[lane];
  int sid = (int)__shfl(v, 5, 64);     // column 5 holds the substructure id
  if (lane == 0) atomicAdd(&cnt[sid], 1.0f);
  atomicAdd(&sums[(size_t)sid * 64 + lane], v);
}

__global__ void gcn_scores(const float* __restrict__ sums, const float* __restrict__ cnt,
                           const float* __restrict__ w1, const float* __restrict__ b1,
                           const float* __restrict__ w2, float* __restrict__ scores) {
  int s = blockIdx.x * 4 + (threadIdx.x >> 6);
  int j = threadIdx.x & 63;
  float r = 1.0f / fmaxf(cnt[s], 1.0f);
  const float* ss = sums + (size_t)s * 64;
  float acc = b1[j];
  #pragma unroll 8
  for (int d = 0; d < 64; ++d) acc = fmaf(ss[d] * r, w1[d * 64 + j], acc);
  float t = tanhf(acc) * w2[j];
  #pragma unroll
  for (int off = 32; off; off >>= 1) t += __shfl_down(t, off, 64);
  if (j == 0) scores[s] = t;
}

__global__ void gcn_softmax(float* __restrict__ sc) {
  // one block, 1024 threads, SS=4096 elements, in-place softmax
  int t = threadIdx.x;
  int wid = t >> 6;
  float v[4]; float m = -INFINITY;
  for (int i = 0; i < 4; ++i) { v[i] = sc[t + i * 1024]; m = fmaxf(m, v[i]); }
  for (int off = 32; off; off >>= 1) m = fmaxf(m, __shfl_xor(m, off, 64));
  __shared__ float wmax[16];
  if ((t & 63) == 0) wmax[wid] = m;
  __syncthreads();
  if (t == 0) { float mm = wmax[0]; for (int i = 1; i < 16; ++i) mm = fmaxf(mm, wmax[i]); wmax[0] = mm; }
  __syncthreads();
  float M = wmax[0];
  float s = 0.f;
  for (int i = 0; i < 4; ++i) { v[i] = expf(v[i] - M); s += v[i]; }
  for (int off = 32; off; off >>= 1) s += __shfl_xor(s, off, 64);
  __shared__ float wsum[16];
  if ((t & 63) == 0) wsum[wid] = s;
  __syncthreads();
  if (t == 0) { float ts = 0.f; for (int i = 0; i < 16; ++i) ts += wsum[i]; wsum[0] = ts; }
  __syncthreads();
  float inv = 1.0f / wsum[0];
  for (int i = 0; i < 4; ++i) sc[t + i * 1024] = v[i] * inv;
}

// ---------- degree / CSR build ----------

__global__ void gcn_deg(const int* __restrict__ col, float* __restrict__ deg, int e) {
  int i = blockIdx.x * 256 + threadIdx.x;
  if (i < e) atomicAdd(&deg[col[i]], 1.0f);
}

__global__ void gcn_dinv(const float* __restrict__ deg, float* __restrict__ dinv, int n) {
  int i = blockIdx.x * 256 + threadIdx.x;
  if (i < n) dinv[i] = rsqrtf(deg[i] + 1.0f);  // +1 = self loop; always >= 1
}

__global__ void gcn_scan1(const float* __restrict__ deg, int* __restrict__ rowstart,
                          int* __restrict__ bsum, int n) {
  __shared__ int tmp[1024];
  int t = threadIdx.x; int g = blockIdx.x * 1024 + t;
  int v = (g < n) ? (int)(deg[g] + 0.5f) : 0;
  tmp[t] = v; __syncthreads();
  for (int off = 1; off < 1024; off <<= 1) {
    int a = (t >= off) ? tmp[t - off] : 0; __syncthreads();
    tmp[t] += a; __syncthreads();
  }
  if (g < n) rowstart[g] = tmp[t] - v;   // exclusive within block
  if (t == 1023) bsum[blockIdx.x] = tmp[t];
}

__global__ void gcn_scan2(int* __restrict__ bsum, int nb) {
  __shared__ int tmp[128];
  int t = threadIdx.x;
  int v = (t < nb) ? bsum[t] : 0;
  tmp[t] = v; __syncthreads();
  for (int off = 1; off < 128; off <<= 1) {
    int a = (t >= off) ? tmp[t - off] : 0; __syncthreads();
    tmp[t] += a; __syncthreads();
  }
  if (t < nb) bsum[t] = tmp[t] - v;      // exclusive block offsets
}

__global__ void gcn_scan3(int* __restrict__ rowstart, const int* __restrict__ bsum, int n, int e) {
  int g = blockIdx.x * 1024 + threadIdx.x;
  if (g < n) rowstart[g] += bsum[blockIdx.x];
  if (g == 0) rowstart[n] = e;
}

__global__ void gcn_scatter(const int* __restrict__ row, const int* __restrict__ col,
                            const float* __restrict__ dinv, const int* __restrict__ rowstart,
                            int* __restrict__ fill, int2* __restrict__ sedge, int e) {
  int i = blockIdx.x * 256 + threadIdx.x;
  if (i >= e) return;
  int c = col[i], r = row[i];
  int pos = rowstart[c] + atomicAdd(&fill[c], 1);
  sedge[pos] = make_int2(r, __float_as_int(dinv[r] * dinv[c]));
}

// ---------- dense matmuls ----------

// layer 0: z = [x, attn] @ cw0   (K = 64 + 1)
__global__ void gcn_mm0(const float* __restrict__ x, const float* __restrict__ attn,
                        const float* __restrict__ cw0, float* __restrict__ z, int n) {
  int gt = blockIdx.x * 256 + threadIdx.x;
  int r = gt >> 5;
  if (r >= n) return;
  int cg = (gt & 31) << 2;
  const float* xr = x + (size_t)r * 64;
  float4 acc = make_float4(0.f, 0.f, 0.f, 0.f);
  #pragma unroll 8
  for (int d = 0; d < 64; ++d) {
    float xv = xr[d];
    float4 wv = *(const float4*)(cw0 + d * 128 + cg);
    acc.x = fmaf(xv, wv.x, acc.x); acc.y = fmaf(xv, wv.y, acc.y);
    acc.z = fmaf(xv, wv.z, acc.z); acc.w = fmaf(xv, wv.w, acc.w);
  }
  int sid = (int)xr[5];
  float a = attn[sid];
  float4 wv = *(const float4*)(cw0 + 64 * 128 + cg);
  acc.x = fmaf(a, wv.x, acc.x); acc.y = fmaf(a, wv.y, acc.y);
  acc.z = fmaf(a, wv.z, acc.z); acc.w = fmaf(a, wv.w, acc.w);
  *(float4*)(z + (size_t)r * 128 + cg) = acc;
}

// layers 1-3: z = h @ W   (K = 128)
__global__ void gcn_mm(const float* __restrict__ h, const float* __restrict__ W,
                       float* __restrict__ z, int n) {
  int gt = blockIdx.x * 256 + threadIdx.x;
  int r = gt >> 5;
  if (r >= n) return;
  int cg = (gt & 31) << 2;
  const float* hr = h + (size_t)r * 128;
  float4 acc = make_float4(0.f, 0.f, 0.f, 0.f);
  #pragma unroll 8
  for (int k = 0; k < 128; ++k) {
    float hv = hr[k];
    float4 wv = *(const float4*)(W + k * 128 + cg);
    acc.x = fmaf(hv, wv.x, acc.x); acc.y = fmaf(hv, wv.y, acc.y);
    acc.z = fmaf(hv, wv.z, acc.z); acc.w = fmaf(hv, wv.w, acc.w);
  }
  *(float4*)(z + (size_t)r * 128 + cg) = acc;
}

// ---------- aggregation + bias + BN + activation (fused) ----------

__global__ void gcn_agg(const float* __restrict__ z, const int2* __restrict__ sedge,
                        const int* __restrict__ rowstart, const float* __restrict__ dinv,
                        const float* __restrict__ bias, const float* __restrict__ bmean,
                        const float* __restrict__ bvar, const float* __restrict__ bgam,
                        const float* __restrict__ bbet, float* __restrict__ hout,
                        int n, int relu) {
  int node = blockIdx.x * 4 + (threadIdx.x >> 6);
  int lane = threadIdx.x & 63;
  if (node >= n) return;
  float di = dinv[node];
  float d2 = di * di;
  const float2* z2 = (const float2*)z;
  float2 v = z2[(size_t)node * 64 + lane];      // self loop
  float ax = v.x * d2, ay = v.y * d2;
  int s0 = rowstart[node], s1 = rowstart[node + 1];
  for (int ee = s0; ee < s1; ++ee) {
    int2 se = sedge[ee];
    float w = __int_as_float(se.y);
    float2 u = z2[(size_t)se.x * 64 + lane];
    ax = fmaf(u.x, w, ax); ay = fmaf(u.y, w, ay);
  }
  int f = lane * 2;
  float i0 = rsqrtf(bvar[f] + EPS_BN), i1 = rsqrtf(bvar[f + 1] + EPS_BN);
  float u0 = (ax + bias[f] - bmean[f]) * i0 * bgam[f] + bbet[f];
  float u1 = (ay + bias[f + 1] - bmean[f + 1]) * i1 * bgam[f + 1] + bbet[f + 1];
  if (relu) { u0 = fmaxf(u0, 0.f); u1 = fmaxf(u1, 0.f); }
  else {
    u0 = u0 > 0.f ? u0 : expf(u0) - 1.f;
    u1 = u1 > 0.f ? u1 : expf(u1) - 1.f;
  }
  float2 o; o.x = u0; o.y = u1;
  ((float2*)hout)[(size_t)node * 64 + lane] = o;
}

// ---------- pooling + head ----------

__global__ void gcn_pool(const float* __restrict__ h, const int* __restrict__ batch,
                         float* __restrict__ pooled, float* __restrict__ gcnt, int n) {
  int node = blockIdx.x * 2 + (threadIdx.x >> 7);
  int f = threadIdx.x & 127;
  if (node >= n) return;
  int g = batch[node];
  atomicAdd(&pooled[(size_t)g * 128 + f], h[(size_t)node * 128 + f]);
  if (f == 0) atomicAdd(&gcnt[g], 1.0f);
}

__global__ void gcn_head(const float* __restrict__ pooled, const float* __restrict__ gcnt,
                         const float* __restrict__ hw1, const float* __restrict__ hb1,
                         const float* __restrict__ hw2, const float* __restrict__ hb2,
                         float* __restrict__ out, int g) {
  int gi = blockIdx.x * 4 + (threadIdx.x >> 6);
  int j = threadIdx.x & 63;
  if (gi >= g) return;
  float r = 1.0f / fmaxf(gcnt[gi], 1.0f);
  const float* p = pooled + (size_t)gi * 128;
  float acc = hb1[j];
  #pragma unroll 8
  for (int k = 0; k < 128; ++k) acc = fmaf(p[k] * r, hw1[k * 64 + j], acc);
  float t = acc > 0.f ? acc : expf(acc) - 1.f;   // ELU
  t *= hw2[j];
  #pragma unroll
  for (int off = 32; off; off >>= 1) t += __shfl_down(t, off, 64);
  if (j == 0) out[gi] = t + hb2[0];
}

// ---------- launch ----------

extern "C" void kernel_launch(void* const* d_in, const int* in_sizes, int n_in,
                              void* d_out, int out_size, void* d_ws, size_t ws_size,
                              hipStream_t stream) {
  const float* x   = (const float*)d_in[0];
  const int*   ei  = (const int*)d_in[1];
  const int*   batch = (const int*)d_in[2];
  const float* w1  = (const float*)d_in[3];
  const float* b1  = (const float*)d_in[4];
  const float* w2  = (const float*)d_in[5];
  const float* cw0 = (const float*)d_in[6];
  const float* cb0 = (const float*)d_in[7];
  const float* cwr = (const float*)d_in[8];
  const float* cbr = (const float*)d_in[9];
  const float* bng = (const float*)d_in[10];
  const float* bnb = (const float*)d_in[11];
  const float* bnm = (const float*)d_in[12];
  const float* bnv = (const float*)d_in[13];
  const float* hw1 = (const float*)d_in[14];
  const float* hb1 = (const float*)d_in[15];
  const float* hw2 = (const float*)d_in[16];
  const float* hb2 = (const float*)d_in[17];
  float* out = (float*)d_out;
  (void)n_in; (void)ws_size;

  const int n = in_sizes[0] / 64;
  const int e = in_sizes[1] / 2;
  const int G = out_size;
  const int* row = ei;
  const int* col = ei + e;

  char* p = (char*)d_ws;
  auto take = [&](size_t bytes) { char* r = p; p += (bytes + 255) & ~(size_t)255; return r; };
  float* cnt    = (float*)take((size_t)SS * 4);
  float* sums   = (float*)take((size_t)SS * 64 * 4);
  float* attn   = (float*)take((size_t)SS * 4);      // scores, softmaxed in place
  float* deg    = (float*)take((size_t)n * 4);
  float* dinv   = (float*)take((size_t)n * 4);
  int*   rowst  = (int*)take(((size_t)n + 1) * 4);
  int*   fill   = (int*)take((size_t)n * 4);
  int*   bsum   = (int*)take(128 * 4);
  int2*  sedge  = (int2*)take((size_t)e * 8);
  float* pooled = (float*)take((size_t)G * HH * 4);
  float* gcnt   = (float*)take((size_t)G * 4);
  float* hA     = (float*)take((size_t)n * HH * 4);
  float* zb     = (float*)take((size_t)n * HH * 4);

  hipMemsetAsync(cnt, 0, (size_t)SS * 4, stream);
  hipMemsetAsync(sums, 0, (size_t)SS * 64 * 4, stream);
  hipMemsetAsync(deg, 0, (size_t)n * 4, stream);
  hipMemsetAsync(fill, 0, (size_t)n * 4, stream);
  hipMemsetAsync(pooled, 0, (size_t)G * HH * 4, stream);
  hipMemsetAsync(gcnt, 0, (size_t)G * 4, stream);

  gcn_subst_accum<<<(n + 3) / 4, 256, 0, stream>>>(x, cnt, sums, n);
  gcn_scores<<<SS / 4, 256, 0, stream>>>(sums, cnt, w1, b1, w2, attn);
  gcn_softmax<<<1, 1024, 0, stream>>>(attn);

  gcn_deg<<<(e + 255) / 256, 256, 0, stream>>>(col, deg, e);
  gcn_dinv<<<(n + 255) / 256, 256, 0, stream>>>(deg, dinv, n);
  int nb = (n + 1023) / 1024;                // 98 for n=100000, must be <= 128
  gcn_scan1<<<nb, 1024, 0, stream>>>(deg, rowst, bsum, n);
  gcn_scan2<<<1, 128, 0, stream>>>(bsum, nb);
  gcn_scan3<<<nb, 1024, 0, stream>>>(rowst, bsum, n, e);
  gcn_scatter<<<(e + 255) / 256, 256, 0, stream>>>(row, col, dinv, rowst, fill, sedge, e);

  int mmgrid = (int)(((size_t)n * 32 + 255) / 256);
  gcn_mm0<<<mmgrid, 256, 0, stream>>>(x, attn, cw0, zb, n);
  gcn_agg<<<(n + 3) / 4, 256, 0, stream>>>(zb, sedge, rowst, dinv, cb0,
      bnm, bnv, bng, bnb, hA, n, 0);
  for (int l = 0; l < 3; ++l) {
    gcn_mm<<<mmgrid, 256, 0, stream>>>(hA, cwr + (size_t)l * HH * HH, zb, n);
    gcn_agg<<<(n + 3) / 4, 256, 0, stream>>>(zb, sedge, rowst, dinv, cbr + l * HH,
        bnm + (l + 1) * HH, bnv + (l + 1) * HH, bng + (l + 1) * HH, bnb + (l + 1) * HH,
        hA, n, l == 2 ? 1 : 0);
  }

  gcn_pool<<<(n + 1) / 2, 256, 0, stream>>>(hA, batch, pooled, gcnt, n);
  gcn_head<<<(G + 3) / 4, 256, 0, stream>>>(pooled, gcnt, hw1, hb1, hw2, hb2, out, G);
}

// Round 3
// 1516.694 us; speedup vs baseline: 1.2798x; 1.2798x over previous
//
#include <hip/hip_runtime.h>
#include <math.h>

static constexpr int SS = 4096;   // substructures
static constexpr int HH = 128;    // hidden
static constexpr float EPS_BN = 1e-5f;

// ---------- substructure attention ----------

__global__ void gcn_subst_accum(const float* __restrict__ x, float* __restrict__ cnt,
                                float* __restrict__ sums, int n) {
  int node = blockIdx.x * 4 + (threadIdx.x >> 6);
  int lane = threadIdx.x & 63;
  if (node >= n) return;
  const float* xr = x + (size_t)node * 64;
  float v = xr[lane];
  int sid = (int)__shfl(v, 5, 64);     // column 5 holds the substructure id
  if (lane == 0) atomicAdd(&cnt[sid], 1.0f);
  atomicAdd(&sums[(size_t)sid * 64 + lane], v);
}

__global__ void gcn_scores(const float* __restrict__ sums, const float* __restrict__ cnt,
                           const float* __restrict__ w1, const float* __restrict__ b1,
                           const float* __restrict__ w2, float* __restrict__ scores) {
  int s = blockIdx.x * 4 + (threadIdx.x >> 6);
  int j = threadIdx.x & 63;
  float r = 1.0f / fmaxf(cnt[s], 1.0f);
  const float* ss = sums + (size_t)s * 64;
  float acc = b1[j];
  #pragma unroll 8
  for (int d = 0; d < 64; ++d) acc = fmaf(ss[d] * r, w1[d * 64 + j], acc);
  float t = tanhf(acc) * w2[j];
  #pragma unroll
  for (int off = 32; off; off >>= 1) t += __shfl_down(t, off, 64);
  if (j == 0) scores[s] = t;
}

__global__ void gcn_softmax(float* __restrict__ sc) {
  int t = threadIdx.x;
  int wid = t >> 6;
  float v[4]; float m = -INFINITY;
  for (int i = 0; i < 4; ++i) { v[i] = sc[t + i * 1024]; m = fmaxf(m, v[i]); }
  for (int off = 32; off; off >>= 1) m = fmaxf(m, __shfl_xor(m, off, 64));
  __shared__ float wmax[16];
  if ((t & 63) == 0) wmax[wid] = m;
  __syncthreads();
  if (t == 0) { float mm = wmax[0]; for (int i = 1; i < 16; ++i) mm = fmaxf(mm, wmax[i]); wmax[0] = mm; }
  __syncthreads();
  float M = wmax[0];
  float s = 0.f;
  for (int i = 0; i < 4; ++i) { v[i] = expf(v[i] - M); s += v[i]; }
  for (int off = 32; off; off >>= 1) s += __shfl_xor(s, off, 64);
  __shared__ float wsum[16];
  if ((t & 63) == 0) wsum[wid] = s;
  __syncthreads();
  if (t == 0) { float ts = 0.f; for (int i = 0; i < 16; ++i) ts += wsum[i]; wsum[0] = ts; }
  __syncthreads();
  float inv = 1.0f / wsum[0];
  for (int i = 0; i < 4; ++i) sc[t + i * 1024] = v[i] * inv;
}

// ---------- degree / CSR build ----------

__global__ void gcn_deg(const int* __restrict__ col, float* __restrict__ deg, int e) {
  int i = blockIdx.x * 256 + threadIdx.x;
  if (i < e) atomicAdd(&deg[col[i]], 1.0f);
}

__global__ void gcn_dinv(const float* __restrict__ deg, float* __restrict__ dinv, int n) {
  int i = blockIdx.x * 256 + threadIdx.x;
  if (i < n) dinv[i] = rsqrtf(deg[i] + 1.0f);  // +1 = self loop
}

__global__ void gcn_scan1(const float* __restrict__ deg, int* __restrict__ rowstart,
                          int* __restrict__ bsum, int n) {
  __shared__ int tmp[1024];
  int t = threadIdx.x; int g = blockIdx.x * 1024 + t;
  int v = (g < n) ? (int)(deg[g] + 0.5f) : 0;
  tmp[t] = v; __syncthreads();
  for (int off = 1; off < 1024; off <<= 1) {
    int a = (t >= off) ? tmp[t - off] : 0; __syncthreads();
    tmp[t] += a; __syncthreads();
  }
  if (g < n) rowstart[g] = tmp[t] - v;
  if (t == 1023) bsum[blockIdx.x] = tmp[t];
}

__global__ void gcn_scan2(int* __restrict__ bsum, int nb) {
  __shared__ int tmp[128];
  int t = threadIdx.x;
  int v = (t < nb) ? bsum[t] : 0;
  tmp[t] = v; __syncthreads();
  for (int off = 1; off < 128; off <<= 1) {
    int a = (t >= off) ? tmp[t - off] : 0; __syncthreads();
    tmp[t] += a; __syncthreads();
  }
  if (t < nb) bsum[t] = tmp[t] - v;
}

__global__ void gcn_scan3(int* __restrict__ rowstart, const int* __restrict__ bsum, int n, int e) {
  int g = blockIdx.x * 1024 + threadIdx.x;
  if (g < n) rowstart[g] += bsum[blockIdx.x];
  if (g == 0) rowstart[n] = e;
}

__global__ void gcn_scatter(const int* __restrict__ row, const int* __restrict__ col,
                            const float* __restrict__ dinv, const int* __restrict__ rowstart,
                            int* __restrict__ fill, int2* __restrict__ sedge, int e) {
  int i = blockIdx.x * 256 + threadIdx.x;
  if (i >= e) return;
  int c = col[i], r = row[i];
  int pos = rowstart[c] + atomicAdd(&fill[c], 1);
  sedge[pos] = make_int2(r, __float_as_int(dinv[r] * dinv[c]));
}

// ---------- dense matmuls (LDS-tiled, 128x128 tile, 8x8 per thread) ----------
// thread map: tr = t&15 (row group), tc = t>>4 (col group).
// Within a wave tc spans 4 values -> W ds_read_b128 addrs are 4 distinct,
// 32B apart, 16-lane broadcast each -> conflict-free on 32 banks.

__global__ __launch_bounds__(256, 2)
void gcn_mm_t(const float* __restrict__ h, const float* __restrict__ W,
              float* __restrict__ z, int n_pad) {
  __shared__ float Ws[128 * 128];   // 64 KB
  int t = threadIdx.x;
  #pragma unroll
  for (int i = 0; i < 16; ++i) {
    int idx = (i * 256 + t) * 4;
    *(float4*)&Ws[idx] = *(const float4*)&W[idx];
  }
  __syncthreads();
  int tr = t & 15, tc = t >> 4;
  int row0 = blockIdx.x * 128 + tr * 8;
  const float* A0 = h + (size_t)row0 * 128;
  float acc[8][8];
  #pragma unroll
  for (int r = 0; r < 8; ++r)
    #pragma unroll
    for (int c = 0; c < 8; ++c) acc[r][c] = 0.f;

  for (int k = 0; k < 128; k += 4) {
    float4 a[8];
    #pragma unroll
    for (int r = 0; r < 8; ++r) a[r] = *(const float4*)&A0[(size_t)r * 128 + k];
    #pragma unroll
    for (int kk = 0; kk < 4; ++kk) {
      float4 w0 = *(const float4*)&Ws[(k + kk) * 128 + tc * 8];
      float4 w1 = *(const float4*)&Ws[(k + kk) * 128 + tc * 8 + 4];
      #pragma unroll
      for (int r = 0; r < 8; ++r) {
        float av = (&a[r].x)[kk];
        acc[r][0] = fmaf(av, w0.x, acc[r][0]); acc[r][1] = fmaf(av, w0.y, acc[r][1]);
        acc[r][2] = fmaf(av, w0.z, acc[r][2]); acc[r][3] = fmaf(av, w0.w, acc[r][3]);
        acc[r][4] = fmaf(av, w1.x, acc[r][4]); acc[r][5] = fmaf(av, w1.y, acc[r][5]);
        acc[r][6] = fmaf(av, w1.z, acc[r][6]); acc[r][7] = fmaf(av, w1.w, acc[r][7]);
      }
    }
  }
  #pragma unroll
  for (int r = 0; r < 8; ++r) {
    float4 o0 = make_float4(acc[r][0], acc[r][1], acc[r][2], acc[r][3]);
    float4 o1 = make_float4(acc[r][4], acc[r][5], acc[r][6], acc[r][7]);
    *(float4*)&z[(size_t)(row0 + r) * 128 + tc * 8] = o0;
    *(float4*)&z[(size_t)(row0 + r) * 128 + tc * 8 + 4] = o1;
  }
  (void)n_pad;
}

// layer 0: z = [x, attn] @ cw0, K = 64 (+ attn row 64). x is exact-sized -> clamp rows.
__global__ __launch_bounds__(256, 2)
void gcn_mm0_t(const float* __restrict__ x, const float* __restrict__ attn,
               const float* __restrict__ cw0, float* __restrict__ z, int n) {
  __shared__ float Ws[65 * 128];    // 33.3 KB
  int t = threadIdx.x;
  for (int i = t; i < 65 * 128 / 4; i += 256)
    *(float4*)&Ws[i * 4] = *(const float4*)&cw0[i * 4];
  __syncthreads();
  int tr = t & 15, tc = t >> 4;
  int row0 = blockIdx.x * 128 + tr * 8;
  const float* ar[8];
  #pragma unroll
  for (int r = 0; r < 8; ++r) {
    int rr = row0 + r; if (rr >= n) rr = n - 1;
    ar[r] = x + (size_t)rr * 64;
  }
  float acc[8][8];
  #pragma unroll
  for (int r = 0; r < 8; ++r)
    #pragma unroll
    for (int c = 0; c < 8; ++c) acc[r][c] = 0.f;

  for (int k = 0; k < 64; k += 4) {
    float4 a[8];
    #pragma unroll
    for (int r = 0; r < 8; ++r) a[r] = *(const float4*)&ar[r][k];
    #pragma unroll
    for (int kk = 0; kk < 4; ++kk) {
      float4 w0 = *(const float4*)&Ws[(k + kk) * 128 + tc * 8];
      float4 w1 = *(const float4*)&Ws[(k + kk) * 128 + tc * 8 + 4];
      #pragma unroll
      for (int r = 0; r < 8; ++r) {
        float av = (&a[r].x)[kk];
        acc[r][0] = fmaf(av, w0.x, acc[r][0]); acc[r][1] = fmaf(av, w0.y, acc[r][1]);
        acc[r][2] = fmaf(av, w0.z, acc[r][2]); acc[r][3] = fmaf(av, w0.w, acc[r][3]);
        acc[r][4] = fmaf(av, w1.x, acc[r][4]); acc[r][5] = fmaf(av, w1.y, acc[r][5]);
        acc[r][6] = fmaf(av, w1.z, acc[r][6]); acc[r][7] = fmaf(av, w1.w, acc[r][7]);
      }
    }
  }
  // attn pseudo-feature (row 64 of W)
  float4 w0 = *(const float4*)&Ws[64 * 128 + tc * 8];
  float4 w1 = *(const float4*)&Ws[64 * 128 + tc * 8 + 4];
  #pragma unroll
  for (int r = 0; r < 8; ++r) {
    int sid = (int)ar[r][5];
    float av = attn[sid];
    acc[r][0] = fmaf(av, w0.x, acc[r][0]); acc[r][1] = fmaf(av, w0.y, acc[r][1]);
    acc[r][2] = fmaf(av, w0.z, acc[r][2]); acc[r][3] = fmaf(av, w0.w, acc[r][3]);
    acc[r][4] = fmaf(av, w1.x, acc[r][4]); acc[r][5] = fmaf(av, w1.y, acc[r][5]);
    acc[r][6] = fmaf(av, w1.z, acc[r][6]); acc[r][7] = fmaf(av, w1.w, acc[r][7]);
  }
  #pragma unroll
  for (int r = 0; r < 8; ++r) {
    float4 o0 = make_float4(acc[r][0], acc[r][1], acc[r][2], acc[r][3]);
    float4 o1 = make_float4(acc[r][4], acc[r][5], acc[r][6], acc[r][7]);
    *(float4*)&z[(size_t)(row0 + r) * 128 + tc * 8] = o0;
    *(float4*)&z[(size_t)(row0 + r) * 128 + tc * 8 + 4] = o1;
  }
}

// ---------- aggregation + bias + BN + activation (fused) ----------

__global__ void gcn_agg(const float* __restrict__ z, const int2* __restrict__ sedge,
                        const int* __restrict__ rowstart, const float* __restrict__ dinv,
                        const float* __restrict__ bias, const float* __restrict__ bmean,
                        const float* __restrict__ bvar, const float* __restrict__ bgam,
                        const float* __restrict__ bbet, float* __restrict__ hout,
                        int n, int relu) {
  int node = blockIdx.x * 4 + (threadIdx.x >> 6);
  int lane = threadIdx.x & 63;
  if (node >= n) return;
  float di = dinv[node];
  float d2 = di * di;
  const float2* z2 = (const float2*)z;
  float2 v = z2[(size_t)node * 64 + lane];      // self loop
  float ax = v.x * d2, ay = v.y * d2;
  int s0 = rowstart[node], s1 = rowstart[node + 1];
  for (int ee = s0; ee < s1; ++ee) {
    int2 se = sedge[ee];
    float w = __int_as_float(se.y);
    float2 u = z2[(size_t)se.x * 64 + lane];
    ax = fmaf(u.x, w, ax); ay = fmaf(u.y, w, ay);
  }
  int f = lane * 2;
  float i0 = rsqrtf(bvar[f] + EPS_BN), i1 = rsqrtf(bvar[f + 1] + EPS_BN);
  float u0 = (ax + bias[f] - bmean[f]) * i0 * bgam[f] + bbet[f];
  float u1 = (ay + bias[f + 1] - bmean[f + 1]) * i1 * bgam[f + 1] + bbet[f + 1];
  if (relu) { u0 = fmaxf(u0, 0.f); u1 = fmaxf(u1, 0.f); }
  else {
    u0 = u0 > 0.f ? u0 : expf(u0) - 1.f;
    u1 = u1 > 0.f ? u1 : expf(u1) - 1.f;
  }
  float2 o; o.x = u0; o.y = u1;
  ((float2*)hout)[(size_t)node * 64 + lane] = o;
}

// ---------- pooling (batch is sorted -> per-graph contiguous ranges) ----------

__global__ void gcn_gb(const int* __restrict__ batch, int* __restrict__ gstart, int n, int G) {
  int g = blockIdx.x * 256 + threadIdx.x;
  if (g > G) return;
  if (g == G) { gstart[G] = n; return; }
  int lo = 0, hi = n;
  while (lo < hi) { int mid = (lo + hi) >> 1; if (batch[mid] < g) lo = mid + 1; else hi = mid; }
  gstart[g] = lo;
}

__global__ void gcn_pool2(const float* __restrict__ h, const int* __restrict__ gstart,
                          float* __restrict__ pooled, int G) {
  int g = blockIdx.x * 4 + (threadIdx.x >> 6);
  int lane = threadIdx.x & 63;
  if (g >= G) return;
  int s = gstart[g], epos = gstart[g + 1];
  const float2* h2 = (const float2*)h;
  float ax = 0.f, ay = 0.f;
  for (int i = s; i < epos; ++i) {
    float2 v = h2[(size_t)i * 64 + lane];
    ax += v.x; ay += v.y;
  }
  float r = 1.0f / fmaxf((float)(epos - s), 1.0f);
  ((float2*)pooled)[(size_t)g * 64 + lane] = make_float2(ax * r, ay * r);
}

__global__ void gcn_head(const float* __restrict__ pooled,
                         const float* __restrict__ hw1, const float* __restrict__ hb1,
                         const float* __restrict__ hw2, const float* __restrict__ hb2,
                         float* __restrict__ out, int g) {
  int gi = blockIdx.x * 4 + (threadIdx.x >> 6);
  int j = threadIdx.x & 63;
  if (gi >= g) return;
  const float* p = pooled + (size_t)gi * 128;
  float acc = hb1[j];
  #pragma unroll 8
  for (int k = 0; k < 128; ++k) acc = fmaf(p[k], hw1[k * 64 + j], acc);
  float t = acc > 0.f ? acc : expf(acc) - 1.f;   // ELU
  t *= hw2[j];
  #pragma unroll
  for (int off = 32; off; off >>= 1) t += __shfl_down(t, off, 64);
  if (j == 0) out[gi] = t + hb2[0];
}

// ---------- launch ----------

extern "C" void kernel_launch(void* const* d_in, const int* in_sizes, int n_in,
                              void* d_out, int out_size, void* d_ws, size_t ws_size,
                              hipStream_t stream) {
  const float* x   = (const float*)d_in[0];
  const int*   ei  = (const int*)d_in[1];
  const int*   batch = (const int*)d_in[2];
  const float* w1  = (const float*)d_in[3];
  const float* b1  = (const float*)d_in[4];
  const float* w2  = (const float*)d_in[5];
  const float* cw0 = (const float*)d_in[6];
  const float* cb0 = (const float*)d_in[7];
  const float* cwr = (const float*)d_in[8];
  const float* cbr = (const float*)d_in[9];
  const float* bng = (const float*)d_in[10];
  const float* bnb = (const float*)d_in[11];
  const float* bnm = (const float*)d_in[12];
  const float* bnv = (const float*)d_in[13];
  const float* hw1 = (const float*)d_in[14];
  const float* hb1 = (const float*)d_in[15];
  const float* hw2 = (const float*)d_in[16];
  const float* hb2 = (const float*)d_in[17];
  float* out = (float*)d_out;
  (void)n_in; (void)ws_size;

  const int n = in_sizes[0] / 64;
  const int e = in_sizes[1] / 2;
  const int G = out_size;
  const int* row = ei;
  const int* col = ei + e;
  const int nb128 = (n + 127) / 128;
  const int n_pad = nb128 * 128;

  char* p = (char*)d_ws;
  auto take = [&](size_t bytes) { char* r = p; p += (bytes + 255) & ~(size_t)255; return r; };
  float* cnt    = (float*)take((size_t)SS * 4);
  float* sums   = (float*)take((size_t)SS * 64 * 4);
  float* attn   = (float*)take((size_t)SS * 4);
  float* deg    = (float*)take((size_t)n * 4);
  float* dinv   = (float*)take((size_t)n * 4);
  int*   rowst  = (int*)take(((size_t)n + 1) * 4);
  int*   fill   = (int*)take((size_t)n * 4);
  int*   bsum   = (int*)take(128 * 4);
  int*   gstart = (int*)take(((size_t)G + 1) * 4);
  int2*  sedge  = (int2*)take((size_t)e * 8);
  float* pooled = (float*)take((size_t)G * HH * 4);
  float* hA     = (float*)take((size_t)n_pad * HH * 4);
  float* zb     = (float*)take((size_t)n_pad * HH * 4);

  hipMemsetAsync(cnt, 0, (size_t)SS * 4, stream);
  hipMemsetAsync(sums, 0, (size_t)SS * 64 * 4, stream);
  hipMemsetAsync(deg, 0, (size_t)n * 4, stream);
  hipMemsetAsync(fill, 0, (size_t)n * 4, stream);

  gcn_subst_accum<<<(n + 3) / 4, 256, 0, stream>>>(x, cnt, sums, n);
  gcn_scores<<<SS / 4, 256, 0, stream>>>(sums, cnt, w1, b1, w2, attn);
  gcn_softmax<<<1, 1024, 0, stream>>>(attn);

  gcn_deg<<<(e + 255) / 256, 256, 0, stream>>>(col, deg, e);
  gcn_dinv<<<(n + 255) / 256, 256, 0, stream>>>(deg, dinv, n);
  int nb = (n + 1023) / 1024;
  gcn_scan1<<<nb, 1024, 0, stream>>>(deg, rowst, bsum, n);
  gcn_scan2<<<1, 128, 0, stream>>>(bsum, nb);
  gcn_scan3<<<nb, 1024, 0, stream>>>(rowst, bsum, n, e);
  gcn_scatter<<<(e + 255) / 256, 256, 0, stream>>>(row, col, dinv, rowst, fill, sedge, e);
  gcn_gb<<<(G + 256) / 256, 256, 0, stream>>>(batch, gstart, n, G);

  gcn_mm0_t<<<nb128, 256, 0, stream>>>(x, attn, cw0, zb, n);
  gcn_agg<<<(n + 3) / 4, 256, 0, stream>>>(zb, sedge, rowst, dinv, cb0,
      bnm, bnv, bng, bnb, hA, n, 0);
  for (int l = 0; l < 3; ++l) {
    gcn_mm_t<<<nb128, 256, 0, stream>>>(hA, cwr + (size_t)l * HH * HH, zb, n_pad);
    gcn_agg<<<(n + 3) / 4, 256, 0, stream>>>(zb, sedge, rowst, dinv, cbr + l * HH,
        bnm + (l + 1) * HH, bnv + (l + 1) * HH, bng + (l + 1) * HH, bnb + (l + 1) * HH,
        hA, n, l == 2 ? 1 : 0);
  }

  gcn_pool2<<<(G + 3) / 4, 256, 0, stream>>>(hA, gstart, pooled, G);
  gcn_head<<<(G + 3) / 4, 256, 0, stream>>>(pooled, hw1, hb1, hw2, hb2, out, G);
}

// Round 4
// 1482.520 us; speedup vs baseline: 1.3093x; 1.0231x over previous
//
#include <hip/hip_runtime.h>
#include <math.h>

static constexpr int SS = 4096;   // substructures
static constexpr int HH = 128;    // hidden
static constexpr float EPS_BN = 1e-5f;

__device__ inline unsigned short f2bf(float f) {       // RNE fp32 -> bf16
  unsigned int u = __float_as_uint(f);
  return (unsigned short)((u + 0x7fffu + ((u >> 16) & 1u)) >> 16);
}

// ---------- substructure attention ----------

__global__ void gcn_subst_accum(const float* __restrict__ x, float* __restrict__ cnt,
                                float* __restrict__ sums, int n) {
  int node = blockIdx.x * 4 + (threadIdx.x >> 6);
  int lane = threadIdx.x & 63;
  if (node >= n) return;
  const float* xr = x + (size_t)node * 64;
  float v = xr[lane];
  int sid = (int)__shfl(v, 5, 64);     // column 5 holds the substructure id
  if (lane == 0) atomicAdd(&cnt[sid], 1.0f);
  atomicAdd(&sums[(size_t)sid * 64 + lane], v);
}

__global__ void gcn_scores(const float* __restrict__ sums, const float* __restrict__ cnt,
                           const float* __restrict__ w1, const float* __restrict__ b1,
                           const float* __restrict__ w2, float* __restrict__ scores) {
  int s = blockIdx.x * 4 + (threadIdx.x >> 6);
  int j = threadIdx.x & 63;
  float r = 1.0f / fmaxf(cnt[s], 1.0f);
  const float* ss = sums + (size_t)s * 64;
  float acc = b1[j];
  #pragma unroll 8
  for (int d = 0; d < 64; ++d) acc = fmaf(ss[d] * r, w1[d * 64 + j], acc);
  float t = tanhf(acc) * w2[j];
  #pragma unroll
  for (int off = 32; off; off >>= 1) t += __shfl_down(t, off, 64);
  if (j == 0) scores[s] = t;
}

__global__ void gcn_softmax(float* __restrict__ sc) {
  int t = threadIdx.x;
  int wid = t >> 6;
  float v[4]; float m = -INFINITY;
  for (int i = 0; i < 4; ++i) { v[i] = sc[t + i * 1024]; m = fmaxf(m, v[i]); }
  for (int off = 32; off; off >>= 1) m = fmaxf(m, __shfl_xor(m, off, 64));
  __shared__ float wmax[16];
  if ((t & 63) == 0) wmax[wid] = m;
  __syncthreads();
  if (t == 0) { float mm = wmax[0]; for (int i = 1; i < 16; ++i) mm = fmaxf(mm, wmax[i]); wmax[0] = mm; }
  __syncthreads();
  float M = wmax[0];
  float s = 0.f;
  for (int i = 0; i < 4; ++i) { v[i] = expf(v[i] - M); s += v[i]; }
  for (int off = 32; off; off >>= 1) s += __shfl_xor(s, off, 64);
  __shared__ float wsum[16];
  if ((t & 63) == 0) wsum[wid] = s;
  __syncthreads();
  if (t == 0) { float ts = 0.f; for (int i = 0; i < 16; ++i) ts += wsum[i]; wsum[0] = ts; }
  __syncthreads();
  float inv = 1.0f / wsum[0];
  for (int i = 0; i < 4; ++i) sc[t + i * 1024] = v[i] * inv;
}

// ---------- degree / CSR build ----------

__global__ void gcn_deg(const int* __restrict__ col, float* __restrict__ deg, int e) {
  int i = blockIdx.x * 256 + threadIdx.x;
  if (i < e) atomicAdd(&deg[col[i]], 1.0f);
}

__global__ void gcn_dinv(const float* __restrict__ deg, float* __restrict__ dinv, int n) {
  int i = blockIdx.x * 256 + threadIdx.x;
  if (i < n) dinv[i] = rsqrtf(deg[i] + 1.0f);  // +1 = self loop
}

__global__ void gcn_scan1(const float* __restrict__ deg, int* __restrict__ rowstart,
                          int* __restrict__ bsum, int n) {
  __shared__ int tmp[1024];
  int t = threadIdx.x; int g = blockIdx.x * 1024 + t;
  int v = (g < n) ? (int)(deg[g] + 0.5f) : 0;
  tmp[t] = v; __syncthreads();
  for (int off = 1; off < 1024; off <<= 1) {
    int a = (t >= off) ? tmp[t - off] : 0; __syncthreads();
    tmp[t] += a; __syncthreads();
  }
  if (g < n) rowstart[g] = tmp[t] - v;
  if (t == 1023) bsum[blockIdx.x] = tmp[t];
}

__global__ void gcn_scan2(int* __restrict__ bsum, int nb) {
  __shared__ int tmp[128];
  int t = threadIdx.x;
  int v = (t < nb) ? bsum[t] : 0;
  tmp[t] = v; __syncthreads();
  for (int off = 1; off < 128; off <<= 1) {
    int a = (t >= off) ? tmp[t - off] : 0; __syncthreads();
    tmp[t] += a; __syncthreads();
  }
  if (t < nb) bsum[t] = tmp[t] - v;
}

__global__ void gcn_scan3(int* __restrict__ rowstart, const int* __restrict__ bsum, int n, int e) {
  int g = blockIdx.x * 1024 + threadIdx.x;
  if (g < n) rowstart[g] += bsum[blockIdx.x];
  if (g == 0) rowstart[n] = e;
}

__global__ void gcn_scatter(const int* __restrict__ row, const int* __restrict__ col,
                            const float* __restrict__ dinv, const int* __restrict__ rowstart,
                            int* __restrict__ fill, int2* __restrict__ sedge, int e) {
  int i = blockIdx.x * 256 + threadIdx.x;
  if (i >= e) return;
  int c = col[i], r = row[i];
  int pos = rowstart[c] + atomicAdd(&fill[c], 1);
  sedge[pos] = make_int2(r, __float_as_int(dinv[r] * dinv[c]));
}

// ---------- layer-0 aggregation: s0 = A_norm @ [x, attn]   (fp32, 65-wide) ----------

__global__ void gcn_agg65(const float* __restrict__ x, const float* __restrict__ attn,
                          const int2* __restrict__ sedge, const int* __restrict__ rowstart,
                          const float* __restrict__ dinv, float* __restrict__ s0, int n) {
  int node = blockIdx.x * 4 + (threadIdx.x >> 6);
  int lane = threadIdx.x & 63;
  if (node >= n) return;
  float di = dinv[node], d2 = di * di;
  float v = x[(size_t)node * 64 + lane];
  int sid = (int)__shfl(v, 5, 64);
  float acc = v * d2;
  float acat = attn[sid] * d2;
  int s_ = rowstart[node], e_ = rowstart[node + 1];
  for (int ee = s_; ee < e_; ++ee) {
    int2 se = sedge[ee];
    float w = __int_as_float(se.y);
    float u = x[(size_t)se.x * 64 + lane];
    int sd = (int)__shfl(u, 5, 64);
    acc = fmaf(u, w, acc);
    acat = fmaf(attn[sd], w, acat);
  }
  s0[(size_t)node * 68 + lane] = acc;
  if (lane == 0) s0[(size_t)node * 68 + 64] = acat;
}

// ---------- layers 1-3 aggregation: s = A_norm @ h (h in bf16, fp32 accumulate) ----------

__global__ void gcn_aggB(const unsigned short* __restrict__ hB, const int2* __restrict__ sedge,
                         const int* __restrict__ rowstart, const float* __restrict__ dinv,
                         float* __restrict__ s, int n) {
  int node = blockIdx.x * 4 + (threadIdx.x >> 6);
  int lane = threadIdx.x & 63;
  if (node >= n) return;
  float di = dinv[node], d2 = di * di;
  const unsigned int* h32 = (const unsigned int*)hB;
  unsigned int u = h32[(size_t)node * 64 + lane];          // features 2*lane, 2*lane+1
  float ax = __uint_as_float(u << 16) * d2;
  float ay = __uint_as_float(u & 0xffff0000u) * d2;
  int s_ = rowstart[node], e_ = rowstart[node + 1];
  for (int ee = s_; ee < e_; ++ee) {
    int2 se = sedge[ee];
    float w = __int_as_float(se.y);
    unsigned int g = h32[(size_t)se.x * 64 + lane];
    ax = fmaf(__uint_as_float(g << 16), w, ax);
    ay = fmaf(__uint_as_float(g & 0xffff0000u), w, ay);
  }
  ((float2*)s)[(size_t)node * 64 + lane] = make_float2(ax, ay);
}

// ---------- fused GEMM + bias + BN + activation -> bf16 h ----------
// 128x128 output tile, 8x8 per thread; W staged in LDS (conflict-free layout,
// verified SQ_LDS_BANK_CONFLICT=0).

__global__ __launch_bounds__(256, 2)
void gcn_mm_bn(const float* __restrict__ s, const float* __restrict__ W,
               const float* __restrict__ bias, const float* __restrict__ bmean,
               const float* __restrict__ bvar, const float* __restrict__ bgam,
               const float* __restrict__ bbet, unsigned short* __restrict__ hB, int relu) {
  __shared__ float Ws[128 * 128];   // 64 KB
  int t = threadIdx.x;
  #pragma unroll
  for (int i = 0; i < 16; ++i) {
    int idx = (i * 256 + t) * 4;
    *(float4*)&Ws[idx] = *(const float4*)&W[idx];
  }
  __syncthreads();
  int tr = t & 15, tc = t >> 4;
  int row0 = blockIdx.x * 128 + tr * 8;
  const float* A0 = s + (size_t)row0 * 128;
  float acc[8][8];
  #pragma unroll
  for (int r = 0; r < 8; ++r)
    #pragma unroll
    for (int c = 0; c < 8; ++c) acc[r][c] = 0.f;

  for (int k = 0; k < 128; k += 4) {
    float4 a[8];
    #pragma unroll
    for (int r = 0; r < 8; ++r) a[r] = *(const float4*)&A0[(size_t)r * 128 + k];
    #pragma unroll
    for (int kk = 0; kk < 4; ++kk) {
      float4 w0 = *(const float4*)&Ws[(k + kk) * 128 + tc * 8];
      float4 w1 = *(const float4*)&Ws[(k + kk) * 128 + tc * 8 + 4];
      #pragma unroll
      for (int r = 0; r < 8; ++r) {
        float av = (&a[r].x)[kk];
        acc[r][0] = fmaf(av, w0.x, acc[r][0]); acc[r][1] = fmaf(av, w0.y, acc[r][1]);
        acc[r][2] = fmaf(av, w0.z, acc[r][2]); acc[r][3] = fmaf(av, w0.w, acc[r][3]);
        acc[r][4] = fmaf(av, w1.x, acc[r][4]); acc[r][5] = fmaf(av, w1.y, acc[r][5]);
        acc[r][6] = fmaf(av, w1.z, acc[r][6]); acc[r][7] = fmaf(av, w1.w, acc[r][7]);
      }
    }
  }
  // epilogue: u = (acc + bias - mean)*rsqrt(var+eps)*gamma + beta; act; -> bf16
  int c0 = tc * 8;
  float sc[8], sh[8];
  #pragma unroll
  for (int c = 0; c < 8; ++c) {
    float inv = rsqrtf(bvar[c0 + c] + EPS_BN) * bgam[c0 + c];
    sc[c] = inv;
    sh[c] = (bias[c0 + c] - bmean[c0 + c]) * inv + bbet[c0 + c];
  }
  #pragma unroll
  for (int r = 0; r < 8; ++r) {
    unsigned int w[4];
    #pragma unroll
    for (int c = 0; c < 8; c += 2) {
      float v0 = fmaf(acc[r][c], sc[c], sh[c]);
      float v1 = fmaf(acc[r][c + 1], sc[c + 1], sh[c + 1]);
      if (relu) { v0 = fmaxf(v0, 0.f); v1 = fmaxf(v1, 0.f); }
      else {
        v0 = v0 > 0.f ? v0 : expf(v0) - 1.f;
        v1 = v1 > 0.f ? v1 : expf(v1) - 1.f;
      }
      w[c >> 1] = (unsigned int)f2bf(v0) | ((unsigned int)f2bf(v1) << 16);
    }
    *(uint4*)&hB[(size_t)(row0 + r) * 128 + c0] = make_uint4(w[0], w[1], w[2], w[3]);
  }
}

// layer 0 variant: K = 65, A = s0 (stride 68)
__global__ __launch_bounds__(256, 2)
void gcn_mm_bn0(const float* __restrict__ s0, const float* __restrict__ cw0,
                const float* __restrict__ bias, const float* __restrict__ bmean,
                const float* __restrict__ bvar, const float* __restrict__ bgam,
                const float* __restrict__ bbet, unsigned short* __restrict__ hB) {
  __shared__ float Ws[65 * 128];    // 33.3 KB
  int t = threadIdx.x;
  for (int i = t; i < 65 * 128 / 4; i += 256)
    *(float4*)&Ws[i * 4] = *(const float4*)&cw0[i * 4];
  __syncthreads();
  int tr = t & 15, tc = t >> 4;
  int row0 = blockIdx.x * 128 + tr * 8;
  const float* A0 = s0 + (size_t)row0 * 68;
  float acc[8][8];
  #pragma unroll
  for (int r = 0; r < 8; ++r)
    #pragma unroll
    for (int c = 0; c < 8; ++c) acc[r][c] = 0.f;

  for (int k = 0; k < 64; k += 4) {
    float4 a[8];
    #pragma unroll
    for (int r = 0; r < 8; ++r) a[r] = *(const float4*)&A0[(size_t)r * 68 + k];
    #pragma unroll
    for (int kk = 0; kk < 4; ++kk) {
      float4 w0 = *(const float4*)&Ws[(k + kk) * 128 + tc * 8];
      float4 w1 = *(const float4*)&Ws[(k + kk) * 128 + tc * 8 + 4];
      #pragma unroll
      for (int r = 0; r < 8; ++r) {
        float av = (&a[r].x)[kk];
        acc[r][0] = fmaf(av, w0.x, acc[r][0]); acc[r][1] = fmaf(av, w0.y, acc[r][1]);
        acc[r][2] = fmaf(av, w0.z, acc[r][2]); acc[r][3] = fmaf(av, w0.w, acc[r][3]);
        acc[r][4] = fmaf(av, w1.x, acc[r][4]); acc[r][5] = fmaf(av, w1.y, acc[r][5]);
        acc[r][6] = fmaf(av, w1.z, acc[r][6]); acc[r][7] = fmaf(av, w1.w, acc[r][7]);
      }
    }
  }
  { // attn pseudo-feature (k = 64)
    float4 w0 = *(const float4*)&Ws[64 * 128 + tc * 8];
    float4 w1 = *(const float4*)&Ws[64 * 128 + tc * 8 + 4];
    #pragma unroll
    for (int r = 0; r < 8; ++r) {
      float av = A0[(size_t)r * 68 + 64];
      acc[r][0] = fmaf(av, w0.x, acc[r][0]); acc[r][1] = fmaf(av, w0.y, acc[r][1]);
      acc[r][2] = fmaf(av, w0.z, acc[r][2]); acc[r][3] = fmaf(av, w0.w, acc[r][3]);
      acc[r][4] = fmaf(av, w1.x, acc[r][4]); acc[r][5] = fmaf(av, w1.y, acc[r][5]);
      acc[r][6] = fmaf(av, w1.z, acc[r][6]); acc[r][7] = fmaf(av, w1.w, acc[r][7]);
    }
  }
  int c0 = tc * 8;
  float sc[8], sh[8];
  #pragma unroll
  for (int c = 0; c < 8; ++c) {
    float inv = rsqrtf(bvar[c0 + c] + EPS_BN) * bgam[c0 + c];
    sc[c] = inv;
    sh[c] = (bias[c0 + c] - bmean[c0 + c]) * inv + bbet[c0 + c];
  }
  #pragma unroll
  for (int r = 0; r < 8; ++r) {
    unsigned int w[4];
    #pragma unroll
    for (int c = 0; c < 8; c += 2) {
      float v0 = fmaf(acc[r][c], sc[c], sh[c]);
      float v1 = fmaf(acc[r][c + 1], sc[c + 1], sh[c + 1]);
      v0 = v0 > 0.f ? v0 : expf(v0) - 1.f;   // ELU
      v1 = v1 > 0.f ? v1 : expf(v1) - 1.f;
      w[c >> 1] = (unsigned int)f2bf(v0) | ((unsigned int)f2bf(v1) << 16);
    }
    *(uint4*)&hB[(size_t)(row0 + r) * 128 + c0] = make_uint4(w[0], w[1], w[2], w[3]);
  }
}

// ---------- pooling (batch sorted -> contiguous ranges) ----------

__global__ void gcn_gb(const int* __restrict__ batch, int* __restrict__ gstart, int n, int G) {
  int g = blockIdx.x * 256 + threadIdx.x;
  if (g > G) return;
  if (g == G) { gstart[G] = n; return; }
  int lo = 0, hi = n;
  while (lo < hi) { int mid = (lo + hi) >> 1; if (batch[mid] < g) lo = mid + 1; else hi = mid; }
  gstart[g] = lo;
}

__global__ void gcn_pool2(const unsigned short* __restrict__ hB, const int* __restrict__ gstart,
                          float* __restrict__ pooled, int G) {
  int g = blockIdx.x * 4 + (threadIdx.x >> 6);
  int lane = threadIdx.x & 63;
  if (g >= G) return;
  int s = gstart[g], epos = gstart[g + 1];
  const unsigned int* h32 = (const unsigned int*)hB;
  float ax = 0.f, ay = 0.f;
  for (int i = s; i < epos; ++i) {
    unsigned int u = h32[(size_t)i * 64 + lane];
    ax += __uint_as_float(u << 16);
    ay += __uint_as_float(u & 0xffff0000u);
  }
  float r = 1.0f / fmaxf((float)(epos - s), 1.0f);
  ((float2*)pooled)[(size_t)g * 64 + lane] = make_float2(ax * r, ay * r);
}

__global__ void gcn_head(const float* __restrict__ pooled,
                         const float* __restrict__ hw1, const float* __restrict__ hb1,
                         const float* __restrict__ hw2, const float* __restrict__ hb2,
                         float* __restrict__ out, int g) {
  int gi = blockIdx.x * 4 + (threadIdx.x >> 6);
  int j = threadIdx.x & 63;
  if (gi >= g) return;
  const float* p = pooled + (size_t)gi * 128;
  float acc = hb1[j];
  #pragma unroll 8
  for (int k = 0; k < 128; ++k) acc = fmaf(p[k], hw1[k * 64 + j], acc);
  float t = acc > 0.f ? acc : expf(acc) - 1.f;   // ELU
  t *= hw2[j];
  #pragma unroll
  for (int off = 32; off; off >>= 1) t += __shfl_down(t, off, 64);
  if (j == 0) out[gi] = t + hb2[0];
}

// ---------- launch ----------

extern "C" void kernel_launch(void* const* d_in, const int* in_sizes, int n_in,
                              void* d_out, int out_size, void* d_ws, size_t ws_size,
                              hipStream_t stream) {
  const float* x   = (const float*)d_in[0];
  const int*   ei  = (const int*)d_in[1];
  const int*   batch = (const int*)d_in[2];
  const float* w1  = (const float*)d_in[3];
  const float* b1  = (const float*)d_in[4];
  const float* w2  = (const float*)d_in[5];
  const float* cw0 = (const float*)d_in[6];
  const float* cb0 = (const float*)d_in[7];
  const float* cwr = (const float*)d_in[8];
  const float* cbr = (const float*)d_in[9];
  const float* bng = (const float*)d_in[10];
  const float* bnb = (const float*)d_in[11];
  const float* bnm = (const float*)d_in[12];
  const float* bnv = (const float*)d_in[13];
  const float* hw1 = (const float*)d_in[14];
  const float* hb1 = (const float*)d_in[15];
  const float* hw2 = (const float*)d_in[16];
  const float* hb2 = (const float*)d_in[17];
  float* out = (float*)d_out;
  (void)n_in; (void)ws_size;

  const int n = in_sizes[0] / 64;
  const int e = in_sizes[1] / 2;
  const int G = out_size;
  const int* row = ei;
  const int* col = ei + e;
  const int nb128 = (n + 127) / 128;
  const int n_pad = nb128 * 128;

  char* p = (char*)d_ws;
  auto take = [&](size_t bytes) { char* r = p; p += (bytes + 255) & ~(size_t)255; return r; };
  float* cnt    = (float*)take((size_t)SS * 4);
  float* sums   = (float*)take((size_t)SS * 64 * 4);
  float* attn   = (float*)take((size_t)SS * 4);
  float* deg    = (float*)take((size_t)n * 4);
  float* dinv   = (float*)take((size_t)n * 4);
  int*   rowst  = (int*)take(((size_t)n + 1) * 4);
  int*   fill   = (int*)take((size_t)n * 4);
  int*   bsum   = (int*)take(128 * 4);
  int*   gstart = (int*)take(((size_t)G + 1) * 4);
  int2*  sedge  = (int2*)take((size_t)e * 8);
  float* pooled = (float*)take((size_t)G * HH * 4);
  float* s0     = (float*)take((size_t)n_pad * 68 * 4);
  float* sB     = (float*)take((size_t)n_pad * HH * 4);
  unsigned short* hB = (unsigned short*)take((size_t)n_pad * HH * 2);

  hipMemsetAsync(cnt, 0, (size_t)SS * 4, stream);
  hipMemsetAsync(sums, 0, (size_t)SS * 64 * 4, stream);
  hipMemsetAsync(deg, 0, (size_t)n * 4, stream);
  hipMemsetAsync(fill, 0, (size_t)n * 4, stream);

  gcn_subst_accum<<<(n + 3) / 4, 256, 0, stream>>>(x, cnt, sums, n);
  gcn_scores<<<SS / 4, 256, 0, stream>>>(sums, cnt, w1, b1, w2, attn);
  gcn_softmax<<<1, 1024, 0, stream>>>(attn);

  gcn_deg<<<(e + 255) / 256, 256, 0, stream>>>(col, deg, e);
  gcn_dinv<<<(n + 255) / 256, 256, 0, stream>>>(deg, dinv, n);
  int nb = (n + 1023) / 1024;
  gcn_scan1<<<nb, 1024, 0, stream>>>(deg, rowst, bsum, n);
  gcn_scan2<<<1, 128, 0, stream>>>(bsum, nb);
  gcn_scan3<<<nb, 1024, 0, stream>>>(rowst, bsum, n, e);
  gcn_scatter<<<(e + 255) / 256, 256, 0, stream>>>(row, col, dinv, rowst, fill, sedge, e);
  gcn_gb<<<(G + 256) / 256, 256, 0, stream>>>(batch, gstart, n, G);

  // layer 0: aggregate [x, attn] then transform+BN+ELU -> bf16 h
  gcn_agg65<<<(n + 3) / 4, 256, 0, stream>>>(x, attn, sedge, rowst, dinv, s0, n);
  gcn_mm_bn0<<<nb128, 256, 0, stream>>>(s0, cw0, cb0, bnm, bnv, bng, bnb, hB);

  // layers 1-3: aggregate bf16 h then transform+BN+act -> bf16 h
  for (int l = 0; l < 3; ++l) {
    gcn_aggB<<<(n + 3) / 4, 256, 0, stream>>>(hB, sedge, rowst, dinv, sB, n);
    gcn_mm_bn<<<nb128, 256, 0, stream>>>(sB, cwr + (size_t)l * HH * HH, cbr + l * HH,
        bnm + (l + 1) * HH, bnv + (l + 1) * HH, bng + (l + 1) * HH, bnb + (l + 1) * HH,
        hB, l == 2 ? 1 : 0);
  }

  gcn_pool2<<<(G + 3) / 4, 256, 0, stream>>>(hB, gstart, pooled, G);
  gcn_head<<<(G + 3) / 4, 256, 0, stream>>>(pooled, hw1, hb1, hw2, hb2, out, G);
}

// Round 5
// 1078.464 us; speedup vs baseline: 1.7999x; 1.3747x over previous
//
#include <hip/hip_runtime.h>
#include <math.h>

static constexpr int SS = 4096;   // substructures
static constexpr int HH = 128;    // hidden
static constexpr float EPS_BN = 1e-5f;

__device__ inline unsigned short f2bf(float f) {       // RNE fp32 -> bf16
  unsigned int u = __float_as_uint(f);
  return (unsigned short)((u + 0x7fffu + ((u >> 16) & 1u)) >> 16);
}
__device__ inline float bflo(unsigned int u) { return __uint_as_float(u << 16); }
__device__ inline float bfhi(unsigned int u) { return __uint_as_float(u & 0xffff0000u); }

// ---------- substructure attention ----------

__global__ void gcn_subst_accum(const float* __restrict__ x, float* __restrict__ cnt,
                                float* __restrict__ sums, int n) {
  int node = blockIdx.x * 4 + (threadIdx.x >> 6);
  int lane = threadIdx.x & 63;
  if (node >= n) return;
  const float* xr = x + (size_t)node * 64;
  float v = xr[lane];
  int sid = (int)__shfl(v, 5, 64);     // column 5 holds the substructure id
  if (lane == 0) atomicAdd(&cnt[sid], 1.0f);
  atomicAdd(&sums[(size_t)sid * 64 + lane], v);
}

__global__ void gcn_scores(const float* __restrict__ sums, const float* __restrict__ cnt,
                           const float* __restrict__ w1, const float* __restrict__ b1,
                           const float* __restrict__ w2, float* __restrict__ scores) {
  int s = blockIdx.x * 4 + (threadIdx.x >> 6);
  int j = threadIdx.x & 63;
  float r = 1.0f / fmaxf(cnt[s], 1.0f);
  const float* ss = sums + (size_t)s * 64;
  float acc = b1[j];
  #pragma unroll 8
  for (int d = 0; d < 64; ++d) acc = fmaf(ss[d] * r, w1[d * 64 + j], acc);
  float t = tanhf(acc) * w2[j];
  #pragma unroll
  for (int off = 32; off; off >>= 1) t += __shfl_down(t, off, 64);
  if (j == 0) scores[s] = t;
}

__global__ void gcn_softmax(float* __restrict__ sc) {
  int t = threadIdx.x;
  int wid = t >> 6;
  float v[4]; float m = -INFINITY;
  for (int i = 0; i < 4; ++i) { v[i] = sc[t + i * 1024]; m = fmaxf(m, v[i]); }
  for (int off = 32; off; off >>= 1) m = fmaxf(m, __shfl_xor(m, off, 64));
  __shared__ float wmax[16];
  if ((t & 63) == 0) wmax[wid] = m;
  __syncthreads();
  if (t == 0) { float mm = wmax[0]; for (int i = 1; i < 16; ++i) mm = fmaxf(mm, wmax[i]); wmax[0] = mm; }
  __syncthreads();
  float M = wmax[0];
  float s = 0.f;
  for (int i = 0; i < 4; ++i) { v[i] = expf(v[i] - M); s += v[i]; }
  for (int off = 32; off; off >>= 1) s += __shfl_xor(s, off, 64);
  __shared__ float wsum[16];
  if ((t & 63) == 0) wsum[wid] = s;
  __syncthreads();
  if (t == 0) { float ts = 0.f; for (int i = 0; i < 16; ++i) ts += wsum[i]; wsum[0] = ts; }
  __syncthreads();
  float inv = 1.0f / wsum[0];
  for (int i = 0; i < 4; ++i) sc[t + i * 1024] = v[i] * inv;
}

// ---------- degree / CSR build ----------

__global__ void gcn_deg(const int* __restrict__ col, float* __restrict__ deg, int e) {
  int i = blockIdx.x * 256 + threadIdx.x;
  if (i < e) atomicAdd(&deg[col[i]], 1.0f);
}

__global__ void gcn_dinv(const float* __restrict__ deg, float* __restrict__ dinv, int n) {
  int i = blockIdx.x * 256 + threadIdx.x;
  if (i < n) dinv[i] = rsqrtf(deg[i] + 1.0f);  // +1 = self loop
}

__global__ void gcn_scan1(const float* __restrict__ deg, int* __restrict__ rowstart,
                          int* __restrict__ bsum, int n) {
  __shared__ int tmp[1024];
  int t = threadIdx.x; int g = blockIdx.x * 1024 + t;
  int v = (g < n) ? (int)(deg[g] + 0.5f) : 0;
  tmp[t] = v; __syncthreads();
  for (int off = 1; off < 1024; off <<= 1) {
    int a = (t >= off) ? tmp[t - off] : 0; __syncthreads();
    tmp[t] += a; __syncthreads();
  }
  if (g < n) rowstart[g] = tmp[t] - v;
  if (t == 1023) bsum[blockIdx.x] = tmp[t];
}

__global__ void gcn_scan2(int* __restrict__ bsum, int nb) {
  __shared__ int tmp[128];
  int t = threadIdx.x;
  int v = (t < nb) ? bsum[t] : 0;
  tmp[t] = v; __syncthreads();
  for (int off = 1; off < 128; off <<= 1) {
    int a = (t >= off) ? tmp[t - off] : 0; __syncthreads();
    tmp[t] += a; __syncthreads();
  }
  if (t < nb) bsum[t] = tmp[t] - v;
}

__global__ void gcn_scan3(int* __restrict__ rowstart, const int* __restrict__ bsum, int n, int e) {
  int g = blockIdx.x * 1024 + threadIdx.x;
  if (g < n) rowstart[g] += bsum[blockIdx.x];
  if (g == 0) rowstart[n] = e;
}

__global__ void gcn_scatter(const int* __restrict__ row, const int* __restrict__ col,
                            const float* __restrict__ dinv, const int* __restrict__ rowstart,
                            int* __restrict__ fill, int2* __restrict__ sedge, int e) {
  int i = blockIdx.x * 256 + threadIdx.x;
  if (i >= e) return;
  int c = col[i], r = row[i];
  int pos = rowstart[c] + atomicAdd(&fill[c], 1);
  sedge[pos] = make_int2(r, __float_as_int(dinv[r] * dinv[c]));
}

// ---------- prep: bf16 x (col5 zeroed) and per-node {sid, attn} table ----------

__global__ void gcn_xb(const float* __restrict__ x, unsigned int* __restrict__ xh, int n) {
  int i = blockIdx.x * 256 + threadIdx.x;            // one uint = 2 features
  if (i >= n * 32) return;
  int pr = i & 31;
  float2 v = *(const float2*)&x[(size_t)(i >> 5) * 64 + pr * 2];
  if (pr == 2) v.y = 0.f;                            // feature 5 handled exactly elsewhere
  xh[i] = (unsigned int)f2bf(v.x) | ((unsigned int)f2bf(v.y) << 16);
}

__global__ void gcn_np(const float* __restrict__ x, const float* __restrict__ attn,
                       float2* __restrict__ np, int n) {
  int i = blockIdx.x * 256 + threadIdx.x;
  if (i >= n) return;
  int sid = (int)x[(size_t)i * 64 + 5];
  np[i] = make_float2((float)sid, attn[sid]);
}

// ---------- layer-0 aggregation ----------
// (a) 64 bf16 x-features, wave per node, 8-edge batches, 2 edges per load instr.
__global__ void gcn_agg_x(const unsigned int* __restrict__ xh, const int2* __restrict__ sedge,
                          const int* __restrict__ rowstart, const float* __restrict__ dinv,
                          float* __restrict__ s0, int n) {
  int node = blockIdx.x * 4 + (threadIdx.x >> 6);
  int lane = threadIdx.x & 63;
  if (node >= n) return;
  float di = dinv[node], d2 = di * di;
  unsigned int us = xh[(size_t)node * 32 + (lane & 31)];
  float ax = (lane < 32) ? bflo(us) * d2 : 0.f;
  float ay = (lane < 32) ? bfhi(us) * d2 : 0.f;
  int s_ = rowstart[node], e_ = rowstart[node + 1];
  for (int b = s_; b < e_; b += 8) {
    int idx = b + (lane & 7);
    int2 se = (idx < e_) ? sedge[idx] : make_int2(node, 0);
    #pragma unroll
    for (int j = 0; j < 8; j += 2) {
      int sa = __shfl(se.x, j, 8), sb = __shfl(se.x, j + 1, 8);
      float wa = __int_as_float(__shfl(se.y, j, 8));
      float wb = __int_as_float(__shfl(se.y, j + 1, 8));
      int src = (lane < 32) ? sa : sb;
      float w = (lane < 32) ? wa : wb;
      unsigned int u = xh[(size_t)src * 32 + (lane & 31)];
      ax = fmaf(bflo(u), w, ax);
      ay = fmaf(bfhi(u), w, ay);
    }
  }
  ax += __shfl_xor(ax, 32, 64);
  ay += __shfl_xor(ay, 32, 64);
  if (lane < 32)
    *(float2*)&s0[(size_t)node * 68 + (size_t)(lane & 31) * 2] = make_float2(ax, ay);
}

// (b) exact fp32 {sid, attn} aggregates -> s0 cols 64, 65. thread per node (high MLP).
__global__ void gcn_agg_np(const float2* __restrict__ np, const int2* __restrict__ sedge,
                           const int* __restrict__ rowstart, const float* __restrict__ dinv,
                           float* __restrict__ s0, int n) {
  int i = blockIdx.x * 256 + threadIdx.x;
  if (i >= n) return;
  float di = dinv[i], d2 = di * di;
  float2 self = np[i];
  float a5 = d2 * self.x, a64 = d2 * self.y;
  int s_ = rowstart[i], e_ = rowstart[i + 1];
  for (int ee = s_; ee < e_; ++ee) {
    int2 se = sedge[ee];
    float w = __int_as_float(se.y);
    float2 v = np[se.x];
    a5 = fmaf(v.x, w, a5);
    a64 = fmaf(v.y, w, a64);
  }
  s0[(size_t)i * 68 + 64] = a5;    // sid column aggregate (W row 5)
  s0[(size_t)i * 68 + 65] = a64;   // attn column aggregate (W row 64)
}

// ---------- layers 1-3 aggregation (bf16 h, 8-edge batches) ----------

__global__ void gcn_aggB(const unsigned short* __restrict__ hB, const int2* __restrict__ sedge,
                         const int* __restrict__ rowstart, const float* __restrict__ dinv,
                         float* __restrict__ s, int n) {
  int node = blockIdx.x * 4 + (threadIdx.x >> 6);
  int lane = threadIdx.x & 63;
  if (node >= n) return;
  float di = dinv[node], d2 = di * di;
  const unsigned int* h32 = (const unsigned int*)hB;
  unsigned int us = h32[(size_t)node * 64 + lane];
  float ax = bflo(us) * d2, ay = bfhi(us) * d2;
  int s_ = rowstart[node], e_ = rowstart[node + 1];
  for (int b = s_; b < e_; b += 8) {
    int idx = b + (lane & 7);
    int2 se = (idx < e_) ? sedge[idx] : make_int2(node, 0);
    #pragma unroll
    for (int j = 0; j < 8; ++j) {
      int src = __shfl(se.x, j, 8);
      float w = __int_as_float(__shfl(se.y, j, 8));
      unsigned int u = h32[(size_t)src * 64 + lane];
      ax = fmaf(bflo(u), w, ax);
      ay = fmaf(bfhi(u), w, ay);
    }
  }
  ((float2*)s)[(size_t)node * 64 + lane] = make_float2(ax, ay);
}

// ---------- fused GEMM + bias + BN + activation -> bf16 h ----------

__global__ __launch_bounds__(256, 2)
void gcn_mm_bn(const float* __restrict__ s, const float* __restrict__ W,
               const float* __restrict__ bias, const float* __restrict__ bmean,
               const float* __restrict__ bvar, const float* __restrict__ bgam,
               const float* __restrict__ bbet, unsigned short* __restrict__ hB, int relu) {
  __shared__ float Ws[128 * 128];   // 64 KB
  int t = threadIdx.x;
  #pragma unroll
  for (int i = 0; i < 16; ++i) {
    int idx = (i * 256 + t) * 4;
    *(float4*)&Ws[idx] = *(const float4*)&W[idx];
  }
  __syncthreads();
  int tr = t & 15, tc = t >> 4;
  int row0 = blockIdx.x * 128 + tr * 8;
  const float* A0 = s + (size_t)row0 * 128;
  float acc[8][8];
  #pragma unroll
  for (int r = 0; r < 8; ++r)
    #pragma unroll
    for (int c = 0; c < 8; ++c) acc[r][c] = 0.f;

  for (int k = 0; k < 128; k += 4) {
    float4 a[8];
    #pragma unroll
    for (int r = 0; r < 8; ++r) a[r] = *(const float4*)&A0[(size_t)r * 128 + k];
    #pragma unroll
    for (int kk = 0; kk < 4; ++kk) {
      float4 w0 = *(const float4*)&Ws[(k + kk) * 128 + tc * 8];
      float4 w1 = *(const float4*)&Ws[(k + kk) * 128 + tc * 8 + 4];
      #pragma unroll
      for (int r = 0; r < 8; ++r) {
        float av = (&a[r].x)[kk];
        acc[r][0] = fmaf(av, w0.x, acc[r][0]); acc[r][1] = fmaf(av, w0.y, acc[r][1]);
        acc[r][2] = fmaf(av, w0.z, acc[r][2]); acc[r][3] = fmaf(av, w0.w, acc[r][3]);
        acc[r][4] = fmaf(av, w1.x, acc[r][4]); acc[r][5] = fmaf(av, w1.y, acc[r][5]);
        acc[r][6] = fmaf(av, w1.z, acc[r][6]); acc[r][7] = fmaf(av, w1.w, acc[r][7]);
      }
    }
  }
  int c0 = tc * 8;
  float sc[8], sh[8];
  #pragma unroll
  for (int c = 0; c < 8; ++c) {
    float inv = rsqrtf(bvar[c0 + c] + EPS_BN) * bgam[c0 + c];
    sc[c] = inv;
    sh[c] = (bias[c0 + c] - bmean[c0 + c]) * inv + bbet[c0 + c];
  }
  #pragma unroll
  for (int r = 0; r < 8; ++r) {
    unsigned int w[4];
    #pragma unroll
    for (int c = 0; c < 8; c += 2) {
      float v0 = fmaf(acc[r][c], sc[c], sh[c]);
      float v1 = fmaf(acc[r][c + 1], sc[c + 1], sh[c + 1]);
      if (relu) { v0 = fmaxf(v0, 0.f); v1 = fmaxf(v1, 0.f); }
      else {
        v0 = v0 > 0.f ? v0 : expf(v0) - 1.f;
        v1 = v1 > 0.f ? v1 : expf(v1) - 1.f;
      }
      w[c >> 1] = (unsigned int)f2bf(v0) | ((unsigned int)f2bf(v1) << 16);
    }
    *(uint4*)&hB[(size_t)(row0 + r) * 128 + c0] = make_uint4(w[0], w[1], w[2], w[3]);
  }
}

// layer 0 variant: A = s0 (stride 68): cols 0..63 (col5=0), col64 -> W row5, col65 -> W row64
__global__ __launch_bounds__(256, 2)
void gcn_mm_bn0(const float* __restrict__ s0, const float* __restrict__ cw0,
                const float* __restrict__ bias, const float* __restrict__ bmean,
                const float* __restrict__ bvar, const float* __restrict__ bgam,
                const float* __restrict__ bbet, unsigned short* __restrict__ hB) {
  __shared__ float Ws[65 * 128];    // 33.3 KB
  int t = threadIdx.x;
  for (int i = t; i < 65 * 128 / 4; i += 256)
    *(float4*)&Ws[i * 4] = *(const float4*)&cw0[i * 4];
  __syncthreads();
  int tr = t & 15, tc = t >> 4;
  int row0 = blockIdx.x * 128 + tr * 8;
  const float* A0 = s0 + (size_t)row0 * 68;
  float acc[8][8];
  #pragma unroll
  for (int r = 0; r < 8; ++r)
    #pragma unroll
    for (int c = 0; c < 8; ++c) acc[r][c] = 0.f;

  for (int k = 0; k < 64; k += 4) {
    float4 a[8];
    #pragma unroll
    for (int r = 0; r < 8; ++r) a[r] = *(const float4*)&A0[(size_t)r * 68 + k];
    #pragma unroll
    for (int kk = 0; kk < 4; ++kk) {
      float4 w0 = *(const float4*)&Ws[(k + kk) * 128 + tc * 8];
      float4 w1 = *(const float4*)&Ws[(k + kk) * 128 + tc * 8 + 4];
      #pragma unroll
      for (int r = 0; r < 8; ++r) {
        float av = (&a[r].x)[kk];
        acc[r][0] = fmaf(av, w0.x, acc[r][0]); acc[r][1] = fmaf(av, w0.y, acc[r][1]);
        acc[r][2] = fmaf(av, w0.z, acc[r][2]); acc[r][3] = fmaf(av, w0.w, acc[r][3]);
        acc[r][4] = fmaf(av, w1.x, acc[r][4]); acc[r][5] = fmaf(av, w1.y, acc[r][5]);
        acc[r][6] = fmaf(av, w1.z, acc[r][6]); acc[r][7] = fmaf(av, w1.w, acc[r][7]);
      }
    }
  }
  { // exact sid aggregate (W row 5) and attn aggregate (W row 64)
    float4 w50 = *(const float4*)&Ws[5 * 128 + tc * 8];
    float4 w51 = *(const float4*)&Ws[5 * 128 + tc * 8 + 4];
    float4 w60 = *(const float4*)&Ws[64 * 128 + tc * 8];
    float4 w61 = *(const float4*)&Ws[64 * 128 + tc * 8 + 4];
    #pragma unroll
    for (int r = 0; r < 8; ++r) {
      float a5 = A0[(size_t)r * 68 + 64];
      float a6 = A0[(size_t)r * 68 + 65];
      acc[r][0] = fmaf(a5, w50.x, acc[r][0]); acc[r][1] = fmaf(a5, w50.y, acc[r][1]);
      acc[r][2] = fmaf(a5, w50.z, acc[r][2]); acc[r][3] = fmaf(a5, w50.w, acc[r][3]);
      acc[r][4] = fmaf(a5, w51.x, acc[r][4]); acc[r][5] = fmaf(a5, w51.y, acc[r][5]);
      acc[r][6] = fmaf(a5, w51.z, acc[r][6]); acc[r][7] = fmaf(a5, w51.w, acc[r][7]);
      acc[r][0] = fmaf(a6, w60.x, acc[r][0]); acc[r][1] = fmaf(a6, w60.y, acc[r][1]);
      acc[r][2] = fmaf(a6, w60.z, acc[r][2]); acc[r][3] = fmaf(a6, w60.w, acc[r][3]);
      acc[r][4] = fmaf(a6, w61.x, acc[r][4]); acc[r][5] = fmaf(a6, w61.y, acc[r][5]);
      acc[r][6] = fmaf(a6, w61.z, acc[r][6]); acc[r][7] = fmaf(a6, w61.w, acc[r][7]);
    }
  }
  int c0 = tc * 8;
  float sc[8], sh[8];
  #pragma unroll
  for (int c = 0; c < 8; ++c) {
    float inv = rsqrtf(bvar[c0 + c] + EPS_BN) * bgam[c0 + c];
    sc[c] = inv;
    sh[c] = (bias[c0 + c] - bmean[c0 + c]) * inv + bbet[c0 + c];
  }
  #pragma unroll
  for (int r = 0; r < 8; ++r) {
    unsigned int w[4];
    #pragma unroll
    for (int c = 0; c < 8; c += 2) {
      float v0 = fmaf(acc[r][c], sc[c], sh[c]);
      float v1 = fmaf(acc[r][c + 1], sc[c + 1], sh[c + 1]);
      v0 = v0 > 0.f ? v0 : expf(v0) - 1.f;   // ELU
      v1 = v1 > 0.f ? v1 : expf(v1) - 1.f;
      w[c >> 1] = (unsigned int)f2bf(v0) | ((unsigned int)f2bf(v1) << 16);
    }
    *(uint4*)&hB[(size_t)(row0 + r) * 128 + c0] = make_uint4(w[0], w[1], w[2], w[3]);
  }
}

// ---------- pooling (batch sorted -> contiguous ranges) ----------

__global__ void gcn_gb(const int* __restrict__ batch, int* __restrict__ gstart, int n, int G) {
  int g = blockIdx.x * 256 + threadIdx.x;
  if (g > G) return;
  if (g == G) { gstart[G] = n; return; }
  int lo = 0, hi = n;
  while (lo < hi) { int mid = (lo + hi) >> 1; if (batch[mid] < g) lo = mid + 1; else hi = mid; }
  gstart[g] = lo;
}

__global__ void gcn_pool2(const unsigned short* __restrict__ hB, const int* __restrict__ gstart,
                          float* __restrict__ pooled, int G) {
  int g = blockIdx.x * 4 + (threadIdx.x >> 6);
  int lane = threadIdx.x & 63;
  if (g >= G) return;
  int s = gstart[g], epos = gstart[g + 1];
  const unsigned int* h32 = (const unsigned int*)hB;
  float ax = 0.f, ay = 0.f;
  for (int i = s; i < epos; ++i) {
    unsigned int u = h32[(size_t)i * 64 + lane];
    ax += bflo(u);
    ay += bfhi(u);
  }
  float r = 1.0f / fmaxf((float)(epos - s), 1.0f);
  ((float2*)pooled)[(size_t)g * 64 + lane] = make_float2(ax * r, ay * r);
}

__global__ void gcn_head(const float* __restrict__ pooled,
                         const float* __restrict__ hw1, const float* __restrict__ hb1,
                         const float* __restrict__ hw2, const float* __restrict__ hb2,
                         float* __restrict__ out, int g) {
  int gi = blockIdx.x * 4 + (threadIdx.x >> 6);
  int j = threadIdx.x & 63;
  if (gi >= g) return;
  const float* p = pooled + (size_t)gi * 128;
  float acc = hb1[j];
  #pragma unroll 8
  for (int k = 0; k < 128; ++k) acc = fmaf(p[k], hw1[k * 64 + j], acc);
  float t = acc > 0.f ? acc : expf(acc) - 1.f;   // ELU
  t *= hw2[j];
  #pragma unroll
  for (int off = 32; off; off >>= 1) t += __shfl_down(t, off, 64);
  if (j == 0) out[gi] = t + hb2[0];
}

// ---------- launch ----------

extern "C" void kernel_launch(void* const* d_in, const int* in_sizes, int n_in,
                              void* d_out, int out_size, void* d_ws, size_t ws_size,
                              hipStream_t stream) {
  const float* x   = (const float*)d_in[0];
  const int*   ei  = (const int*)d_in[1];
  const int*   batch = (const int*)d_in[2];
  const float* w1  = (const float*)d_in[3];
  const float* b1  = (const float*)d_in[4];
  const float* w2  = (const float*)d_in[5];
  const float* cw0 = (const float*)d_in[6];
  const float* cb0 = (const float*)d_in[7];
  const float* cwr = (const float*)d_in[8];
  const float* cbr = (const float*)d_in[9];
  const float* bng = (const float*)d_in[10];
  const float* bnb = (const float*)d_in[11];
  const float* bnm = (const float*)d_in[12];
  const float* bnv = (const float*)d_in[13];
  const float* hw1 = (const float*)d_in[14];
  const float* hb1 = (const float*)d_in[15];
  const float* hw2 = (const float*)d_in[16];
  const float* hb2 = (const float*)d_in[17];
  float* out = (float*)d_out;
  (void)n_in; (void)ws_size;

  const int n = in_sizes[0] / 64;
  const int e = in_sizes[1] / 2;
  const int G = out_size;
  const int* row = ei;
  const int* col = ei + e;
  const int nb128 = (n + 127) / 128;
  const int n_pad = nb128 * 128;

  char* p = (char*)d_ws;
  auto take = [&](size_t bytes) { char* r = p; p += (bytes + 255) & ~(size_t)255; return r; };
  float* cnt    = (float*)take((size_t)SS * 4);
  float* sums   = (float*)take((size_t)SS * 64 * 4);
  float* attn   = (float*)take((size_t)SS * 4);
  float* deg    = (float*)take((size_t)n * 4);
  float* dinv   = (float*)take((size_t)n * 4);
  int*   rowst  = (int*)take(((size_t)n + 1) * 4);
  int*   fill   = (int*)take((size_t)n * 4);
  int*   bsum   = (int*)take(128 * 4);
  int*   gstart = (int*)take(((size_t)G + 1) * 4);
  int2*  sedge  = (int2*)take((size_t)e * 8);
  float* pooled = (float*)take((size_t)G * HH * 4);
  float2* np    = (float2*)take((size_t)n * 8);
  unsigned int* xh = (unsigned int*)take((size_t)n * 32 * 4);
  float* s0     = (float*)take((size_t)n_pad * 68 * 4);
  float* sB     = (float*)take((size_t)n_pad * HH * 4);
  unsigned short* hB = (unsigned short*)take((size_t)n_pad * HH * 2);

  hipMemsetAsync(cnt, 0, (size_t)SS * 4, stream);
  hipMemsetAsync(sums, 0, (size_t)SS * 64 * 4, stream);
  hipMemsetAsync(deg, 0, (size_t)n * 4, stream);
  hipMemsetAsync(fill, 0, (size_t)n * 4, stream);

  gcn_subst_accum<<<(n + 3) / 4, 256, 0, stream>>>(x, cnt, sums, n);
  gcn_scores<<<SS / 4, 256, 0, stream>>>(sums, cnt, w1, b1, w2, attn);
  gcn_softmax<<<1, 1024, 0, stream>>>(attn);

  gcn_deg<<<(e + 255) / 256, 256, 0, stream>>>(col, deg, e);
  gcn_dinv<<<(n + 255) / 256, 256, 0, stream>>>(deg, dinv, n);
  int nb = (n + 1023) / 1024;
  gcn_scan1<<<nb, 1024, 0, stream>>>(deg, rowst, bsum, n);
  gcn_scan2<<<1, 128, 0, stream>>>(bsum, nb);
  gcn_scan3<<<nb, 1024, 0, stream>>>(rowst, bsum, n, e);
  gcn_scatter<<<(e + 255) / 256, 256, 0, stream>>>(row, col, dinv, rowst, fill, sedge, e);
  gcn_gb<<<(G + 256) / 256, 256, 0, stream>>>(batch, gstart, n, G);

  // prep tables
  gcn_xb<<<(n * 32 + 255) / 256, 256, 0, stream>>>(x, xh, n);
  gcn_np<<<(n + 255) / 256, 256, 0, stream>>>(x, attn, np, n);

  // layer 0
  gcn_agg_x<<<(n + 3) / 4, 256, 0, stream>>>(xh, sedge, rowst, dinv, s0, n);
  gcn_agg_np<<<(n + 255) / 256, 256, 0, stream>>>(np, sedge, rowst, dinv, s0, n);
  gcn_mm_bn0<<<nb128, 256, 0, stream>>>(s0, cw0, cb0, bnm, bnv, bng, bnb, hB);

  // layers 1-3
  for (int l = 0; l < 3; ++l) {
    gcn_aggB<<<(n + 3) / 4, 256, 0, stream>>>(hB, sedge, rowst, dinv, sB, n);
    gcn_mm_bn<<<nb128, 256, 0, stream>>>(sB, cwr + (size_t)l * HH * HH, cbr + l * HH,
        bnm + (l + 1) * HH, bnv + (l + 1) * HH, bng + (l + 1) * HH, bnb + (l + 1) * HH,
        hB, l == 2 ? 1 : 0);
  }

  gcn_pool2<<<(G + 3) / 4, 256, 0, stream>>>(hB, gstart, pooled, G);
  gcn_head<<<(G + 3) / 4, 256, 0, stream>>>(pooled, hw1, hb1, hw2, hb2, out, G);
}

// Round 6
// 707.021 us; speedup vs baseline: 2.7455x; 1.5254x over previous
//
#include <hip/hip_runtime.h>
#include <math.h>

static constexpr int SS = 4096;   // substructures
static constexpr int HH = 128;    // hidden
static constexpr float EPS_BN = 1e-5f;

typedef __attribute__((ext_vector_type(8))) short bf16x8;
typedef __attribute__((ext_vector_type(4))) float f32x4;

__device__ inline unsigned short f2bf(float f) {       // RNE fp32 -> bf16
  unsigned int u = __float_as_uint(f);
  return (unsigned short)((u + 0x7fffu + ((u >> 16) & 1u)) >> 16);
}
__device__ inline float bflo(unsigned int u) { return __uint_as_float(u << 16); }
__device__ inline float bfhi(unsigned int u) { return __uint_as_float(u & 0xffff0000u); }

// ---------- substructure attention ----------

__global__ void gcn_subst_accum(const float* __restrict__ x, float* __restrict__ cnt,
                                float* __restrict__ sums, int n) {
  int node = blockIdx.x * 4 + (threadIdx.x >> 6);
  int lane = threadIdx.x & 63;
  if (node >= n) return;
  const float* xr = x + (size_t)node * 64;
  float v = xr[lane];
  int sid = (int)__shfl(v, 5, 64);
  if (lane == 0) atomicAdd(&cnt[sid], 1.0f);
  atomicAdd(&sums[(size_t)sid * 64 + lane], v);
}

__global__ void gcn_scores(const float* __restrict__ sums, const float* __restrict__ cnt,
                           const float* __restrict__ w1, const float* __restrict__ b1,
                           const float* __restrict__ w2, float* __restrict__ scores) {
  int s = blockIdx.x * 4 + (threadIdx.x >> 6);
  int j = threadIdx.x & 63;
  float r = 1.0f / fmaxf(cnt[s], 1.0f);
  const float* ss = sums + (size_t)s * 64;
  float acc = b1[j];
  #pragma unroll 8
  for (int d = 0; d < 64; ++d) acc = fmaf(ss[d] * r, w1[d * 64 + j], acc);
  float t = tanhf(acc) * w2[j];
  #pragma unroll
  for (int off = 32; off; off >>= 1) t += __shfl_down(t, off, 64);
  if (j == 0) scores[s] = t;
}

__global__ void gcn_softmax(float* __restrict__ sc) {
  int t = threadIdx.x;
  int wid = t >> 6;
  float v[4]; float m = -INFINITY;
  for (int i = 0; i < 4; ++i) { v[i] = sc[t + i * 1024]; m = fmaxf(m, v[i]); }
  for (int off = 32; off; off >>= 1) m = fmaxf(m, __shfl_xor(m, off, 64));
  __shared__ float wmax[16];
  if ((t & 63) == 0) wmax[wid] = m;
  __syncthreads();
  if (t == 0) { float mm = wmax[0]; for (int i = 1; i < 16; ++i) mm = fmaxf(mm, wmax[i]); wmax[0] = mm; }
  __syncthreads();
  float M = wmax[0];
  float s = 0.f;
  for (int i = 0; i < 4; ++i) { v[i] = expf(v[i] - M); s += v[i]; }
  for (int off = 32; off; off >>= 1) s += __shfl_xor(s, off, 64);
  __shared__ float wsum[16];
  if ((t & 63) == 0) wsum[wid] = s;
  __syncthreads();
  if (t == 0) { float ts = 0.f; for (int i = 0; i < 16; ++i) ts += wsum[i]; wsum[0] = ts; }
  __syncthreads();
  float inv = 1.0f / wsum[0];
  for (int i = 0; i < 4; ++i) sc[t + i * 1024] = v[i] * inv;
}

// ---------- degree / CSR build ----------

__global__ void gcn_deg(const int* __restrict__ col, float* __restrict__ deg, int e) {
  int i = blockIdx.x * 256 + threadIdx.x;
  if (i < e) atomicAdd(&deg[col[i]], 1.0f);
}

__global__ void gcn_dinv(const float* __restrict__ deg, float* __restrict__ dinv, int n) {
  int i = blockIdx.x * 256 + threadIdx.x;
  if (i < n) dinv[i] = rsqrtf(deg[i] + 1.0f);
}

__global__ void gcn_scan1(const float* __restrict__ deg, int* __restrict__ rowstart,
                          int* __restrict__ bsum, int n) {
  __shared__ int tmp[1024];
  int t = threadIdx.x; int g = blockIdx.x * 1024 + t;
  int v = (g < n) ? (int)(deg[g] + 0.5f) : 0;
  tmp[t] = v; __syncthreads();
  for (int off = 1; off < 1024; off <<= 1) {
    int a = (t >= off) ? tmp[t - off] : 0; __syncthreads();
    tmp[t] += a; __syncthreads();
  }
  if (g < n) rowstart[g] = tmp[t] - v;
  if (t == 1023) bsum[blockIdx.x] = tmp[t];
}

__global__ void gcn_scan2(int* __restrict__ bsum, int nb) {
  __shared__ int tmp[128];
  int t = threadIdx.x;
  int v = (t < nb) ? bsum[t] : 0;
  tmp[t] = v; __syncthreads();
  for (int off = 1; off < 128; off <<= 1) {
    int a = (t >= off) ? tmp[t - off] : 0; __syncthreads();
    tmp[t] += a; __syncthreads();
  }
  if (t < nb) bsum[t] = tmp[t] - v;
}

__global__ void gcn_scan3(int* __restrict__ rowstart, const int* __restrict__ bsum, int n, int e) {
  int g = blockIdx.x * 1024 + threadIdx.x;
  if (g < n) rowstart[g] += bsum[blockIdx.x];
  if (g == 0) rowstart[n] = e;
}

__global__ void gcn_scatter(const int* __restrict__ row, const int* __restrict__ col,
                            const float* __restrict__ dinv, const int* __restrict__ rowstart,
                            int* __restrict__ fill, int2* __restrict__ sedge, int e) {
  int i = blockIdx.x * 256 + threadIdx.x;
  if (i >= e) return;
  int c = col[i], r = row[i];
  int pos = rowstart[c] + atomicAdd(&fill[c], 1);
  sedge[pos] = make_int2(r, __float_as_int(dinv[r] * dinv[c]));
}

// ---------- prep ----------

__global__ void gcn_xb(const float* __restrict__ x, unsigned int* __restrict__ xh, int n) {
  int i = blockIdx.x * 256 + threadIdx.x;            // one uint = 2 features
  if (i >= n * 32) return;
  int pr = i & 31;
  float2 v = *(const float2*)&x[(size_t)(i >> 5) * 64 + pr * 2];
  if (pr == 2) v.y = 0.f;                            // feature 5 handled exactly elsewhere
  xh[i] = (unsigned int)f2bf(v.x) | ((unsigned int)f2bf(v.y) << 16);
}

__global__ void gcn_np(const float* __restrict__ x, const float* __restrict__ attn,
                       float2* __restrict__ np, int n) {
  int i = blockIdx.x * 256 + threadIdx.x;
  if (i >= n) return;
  int sid = (int)x[(size_t)i * 64 + 5];
  np[i] = make_float2((float)sid, attn[sid]);
}

// pack W[128-col matrices] to bf16 MFMA B-fragment layout: out[nt][kc][lane][8]
__global__ void gcn_wpack(const float* __restrict__ W, unsigned short* __restrict__ out, int nkc) {
  int idx = blockIdx.x * 256 + threadIdx.x;          // one per (nt,kc,lane)
  if (idx >= 8 * nkc * 64) return;
  int lane = idx & 63;
  int kc = (idx >> 6) % nkc;
  int nt = idx / (64 * nkc);
  int colc = nt * 16 + (lane & 15);
  int k0 = kc * 32 + (lane >> 4) * 8;
  unsigned int w[4];
  #pragma unroll
  for (int i = 0; i < 4; ++i) {
    unsigned short a = f2bf(W[(size_t)(k0 + 2 * i) * 128 + colc]);
    unsigned short b = f2bf(W[(size_t)(k0 + 2 * i + 1) * 128 + colc]);
    w[i] = (unsigned int)a | ((unsigned int)b << 16);
  }
  *(uint4*)&out[(size_t)idx * 8] = make_uint4(w[0], w[1], w[2], w[3]);
}

// fold BN: u = z*S + T per layer/col
__global__ void gcn_bnp(const float* __restrict__ cb0, const float* __restrict__ cbr,
                        const float* __restrict__ bng, const float* __restrict__ bnb,
                        const float* __restrict__ bnm, const float* __restrict__ bnv,
                        float* __restrict__ bnS, float* __restrict__ bnT) {
  int i = blockIdx.x * 128 + threadIdx.x;            // 0..511
  int l = i >> 7, c = i & 127;
  float S = rsqrtf(bnv[i] + EPS_BN) * bng[i];
  float bias = (l == 0) ? cb0[c] : cbr[(l - 1) * 128 + c];
  bnS[i] = S;
  bnT[i] = fmaf(bias - bnm[i], S, bnb[i]);
}

// ---------- layer-0 aggregation ----------

__global__ void gcn_agg_x(const unsigned int* __restrict__ xh, const int2* __restrict__ sedge,
                          const int* __restrict__ rowstart, const float* __restrict__ dinv,
                          unsigned int* __restrict__ s0b, int n) {
  int node = blockIdx.x * 4 + (threadIdx.x >> 6);
  int lane = threadIdx.x & 63;
  if (node >= n) return;
  float di = dinv[node], d2 = di * di;
  unsigned int us = xh[(size_t)node * 32 + (lane & 31)];
  float ax = (lane < 32) ? bflo(us) * d2 : 0.f;
  float ay = (lane < 32) ? bfhi(us) * d2 : 0.f;
  int s_ = rowstart[node], e_ = rowstart[node + 1];
  for (int b = s_; b < e_; b += 8) {
    int idx = b + (lane & 7);
    int2 se = (idx < e_) ? sedge[idx] : make_int2(node, 0);
    #pragma unroll
    for (int j = 0; j < 8; j += 2) {
      int sa = __shfl(se.x, j, 8), sb = __shfl(se.x, j + 1, 8);
      float wa = __int_as_float(__shfl(se.y, j, 8));
      float wb = __int_as_float(__shfl(se.y, j + 1, 8));
      int src = (lane < 32) ? sa : sb;
      float w = (lane < 32) ? wa : wb;
      unsigned int u = xh[(size_t)src * 32 + (lane & 31)];
      ax = fmaf(bflo(u), w, ax);
      ay = fmaf(bfhi(u), w, ay);
    }
  }
  ax += __shfl_xor(ax, 32, 64);
  ay += __shfl_xor(ay, 32, 64);
  if (lane < 32)
    s0b[(size_t)node * 32 + lane] = (unsigned int)f2bf(ax) | ((unsigned int)f2bf(ay) << 16);
}

// exact fp32 {sid, attn} aggregates. thread per node.
__global__ void gcn_agg_np(const float2* __restrict__ np, const int2* __restrict__ sedge,
                           const int* __restrict__ rowstart, const float* __restrict__ dinv,
                           float* __restrict__ s0x, int n) {
  int i = blockIdx.x * 256 + threadIdx.x;
  if (i >= n) return;
  float di = dinv[i], d2 = di * di;
  float2 self = np[i];
  float a5 = d2 * self.x, a64 = d2 * self.y;
  int s_ = rowstart[i], e_ = rowstart[i + 1];
  for (int ee = s_; ee < e_; ++ee) {
    int2 se = sedge[ee];
    float w = __int_as_float(se.y);
    float2 v = np[se.x];
    a5 = fmaf(v.x, w, a5);
    a64 = fmaf(v.y, w, a64);
  }
  s0x[(size_t)i * 2] = a5;
  s0x[(size_t)i * 2 + 1] = a64;
}

// ---------- layers 1-3 aggregation (bf16 h -> bf16 s, fp32 accumulate) ----------

__global__ void gcn_aggB(const unsigned short* __restrict__ hB, const int2* __restrict__ sedge,
                         const int* __restrict__ rowstart, const float* __restrict__ dinv,
                         unsigned int* __restrict__ sBb, int n) {
  int node = blockIdx.x * 4 + (threadIdx.x >> 6);
  int lane = threadIdx.x & 63;
  if (node >= n) return;
  float di = dinv[node], d2 = di * di;
  const unsigned int* h32 = (const unsigned int*)hB;
  unsigned int us = h32[(size_t)node * 64 + lane];
  float ax = bflo(us) * d2, ay = bfhi(us) * d2;
  int s_ = rowstart[node], e_ = rowstart[node + 1];
  for (int b = s_; b < e_; b += 8) {
    int idx = b + (lane & 7);
    int2 se = (idx < e_) ? sedge[idx] : make_int2(node, 0);
    #pragma unroll
    for (int j = 0; j < 8; ++j) {
      int src = __shfl(se.x, j, 8);
      float w = __int_as_float(__shfl(se.y, j, 8));
      unsigned int u = h32[(size_t)src * 64 + lane];
      ax = fmaf(bflo(u), w, ax);
      ay = fmaf(bfhi(u), w, ay);
    }
  }
  sBb[(size_t)node * 64 + lane] = (unsigned int)f2bf(ax) | ((unsigned int)f2bf(ay) << 16);
}

// ---------- MFMA GEMM + BN + activation -> bf16 h ----------
// 64 rows/block (4 waves x 16 rows), N=128 (8 tiles), K=128 (4 chunks of 32).
// A bf16 from global; B prepacked bf16 fragments (L1/L2-resident); no W in LDS.

__global__ __launch_bounds__(256)
void gcn_mm_mfma(const unsigned short* __restrict__ A, const unsigned short* __restrict__ Wpk,
                 const float* __restrict__ bnS, const float* __restrict__ bnT,
                 unsigned short* __restrict__ hB, int relu) {
  __shared__ unsigned short tile[4][16][136];
  int t = threadIdx.x;
  int wid = t >> 6, l = t & 63;
  int rowA = l & 15, kg = l >> 4;
  size_t row0w = (size_t)blockIdx.x * 64 + wid * 16;
  const unsigned short* Ar = A + (row0w + rowA) * 128 + kg * 8;
  bf16x8 af[4];
  #pragma unroll
  for (int kc = 0; kc < 4; ++kc) af[kc] = *(const bf16x8*)(Ar + kc * 32);
  f32x4 acc[8];
  #pragma unroll
  for (int nt = 0; nt < 8; ++nt) acc[nt] = (f32x4){0.f, 0.f, 0.f, 0.f};
  const unsigned short* wp = Wpk + (size_t)l * 8;
  #pragma unroll
  for (int kc = 0; kc < 4; ++kc) {
    bf16x8 bf[8];
    #pragma unroll
    for (int nt = 0; nt < 8; ++nt)
      bf[nt] = *(const bf16x8*)(wp + (size_t)(nt * 4 + kc) * 512);
    #pragma unroll
    for (int nt = 0; nt < 8; ++nt)
      acc[nt] = __builtin_amdgcn_mfma_f32_16x16x32_bf16(af[kc], bf[nt], acc[nt], 0, 0, 0);
  }
  int colb = l & 15, rb = kg * 4;
  #pragma unroll
  for (int nt = 0; nt < 8; ++nt) {
    int c = nt * 16 + colb;
    float S = bnS[c], T = bnT[c];
    #pragma unroll
    for (int j = 0; j < 4; ++j) {
      float v = fmaf(acc[nt][j], S, T);
      v = relu ? fmaxf(v, 0.f) : (v > 0.f ? v : expf(v) - 1.f);
      tile[wid][rb + j][c] = f2bf(v);
    }
  }
  __syncthreads();
  #pragma unroll
  for (int i = 0; i < 4; ++i) {
    int m = i * 64 + l;
    int row = m >> 4, chunk = m & 15;
    uint4 v = *(const uint4*)&tile[wid][row][chunk * 8];
    *(uint4*)&hB[(row0w + row) * 128 + chunk * 8] = v;
  }
}

// layer 0: A = s0b (n_pad x 64 bf16, col5 zeroed), + exact fp32 sid/attn features
__global__ __launch_bounds__(256)
void gcn_mm0_mfma(const unsigned short* __restrict__ A, const float* __restrict__ s0x,
                  const unsigned short* __restrict__ Wpk0, const float* __restrict__ cw0,
                  const float* __restrict__ bnS, const float* __restrict__ bnT,
                  unsigned short* __restrict__ hB) {
  __shared__ unsigned short tile[4][16][136];
  int t = threadIdx.x;
  int wid = t >> 6, l = t & 63;
  int rowA = l & 15, kg = l >> 4;
  size_t row0w = (size_t)blockIdx.x * 64 + wid * 16;
  const unsigned short* Ar = A + (row0w + rowA) * 64 + kg * 8;
  bf16x8 af[2];
  #pragma unroll
  for (int kc = 0; kc < 2; ++kc) af[kc] = *(const bf16x8*)(Ar + kc * 32);
  f32x4 acc[8];
  #pragma unroll
  for (int nt = 0; nt < 8; ++nt) acc[nt] = (f32x4){0.f, 0.f, 0.f, 0.f};
  const unsigned short* wp = Wpk0 + (size_t)l * 8;
  #pragma unroll
  for (int kc = 0; kc < 2; ++kc) {
    bf16x8 bf[8];
    #pragma unroll
    for (int nt = 0; nt < 8; ++nt)
      bf[nt] = *(const bf16x8*)(wp + (size_t)(nt * 2 + kc) * 512);
    #pragma unroll
    for (int nt = 0; nt < 8; ++nt)
      acc[nt] = __builtin_amdgcn_mfma_f32_16x16x32_bf16(af[kc], bf[nt], acc[nt], 0, 0, 0);
  }
  int colb = l & 15, rb = kg * 4;
  float2 ax[4];
  #pragma unroll
  for (int j = 0; j < 4; ++j) ax[j] = *(const float2*)&s0x[(row0w + rb + j) * 2];
  #pragma unroll
  for (int nt = 0; nt < 8; ++nt) {
    int c = nt * 16 + colb;
    float w5 = cw0[5 * 128 + c], w64 = cw0[64 * 128 + c];
    float S = bnS[c], T = bnT[c];
    #pragma unroll
    for (int j = 0; j < 4; ++j) {
      float z = acc[nt][j] + ax[j].x * w5 + ax[j].y * w64;
      float v = fmaf(z, S, T);
      v = v > 0.f ? v : expf(v) - 1.f;   // ELU
      tile[wid][rb + j][c] = f2bf(v);
    }
  }
  __syncthreads();
  #pragma unroll
  for (int i = 0; i < 4; ++i) {
    int m = i * 64 + l;
    int row = m >> 4, chunk = m & 15;
    uint4 v = *(const uint4*)&tile[wid][row][chunk * 8];
    *(uint4*)&hB[(row0w + row) * 128 + chunk * 8] = v;
  }
}

// ---------- pooling (batch sorted -> contiguous ranges) ----------

__global__ void gcn_gb(const int* __restrict__ batch, int* __restrict__ gstart, int n, int G) {
  int g = blockIdx.x * 256 + threadIdx.x;
  if (g > G) return;
  if (g == G) { gstart[G] = n; return; }
  int lo = 0, hi = n;
  while (lo < hi) { int mid = (lo + hi) >> 1; if (batch[mid] < g) lo = mid + 1; else hi = mid; }
  gstart[g] = lo;
}

__global__ void gcn_pool2(const unsigned short* __restrict__ hB, const int* __restrict__ gstart,
                          float* __restrict__ pooled, int G) {
  int g = blockIdx.x * 4 + (threadIdx.x >> 6);
  int lane = threadIdx.x & 63;
  if (g >= G) return;
  int s = gstart[g], epos = gstart[g + 1];
  const unsigned int* h32 = (const unsigned int*)hB;
  float ax = 0.f, ay = 0.f;
  for (int i = s; i < epos; ++i) {
    unsigned int u = h32[(size_t)i * 64 + lane];
    ax += bflo(u);
    ay += bfhi(u);
  }
  float r = 1.0f / fmaxf((float)(epos - s), 1.0f);
  ((float2*)pooled)[(size_t)g * 64 + lane] = make_float2(ax * r, ay * r);
}

__global__ void gcn_head(const float* __restrict__ pooled,
                         const float* __restrict__ hw1, const float* __restrict__ hb1,
                         const float* __restrict__ hw2, const float* __restrict__ hb2,
                         float* __restrict__ out, int g) {
  int gi = blockIdx.x * 4 + (threadIdx.x >> 6);
  int j = threadIdx.x & 63;
  if (gi >= g) return;
  const float* p = pooled + (size_t)gi * 128;
  float acc = hb1[j];
  #pragma unroll 8
  for (int k = 0; k < 128; ++k) acc = fmaf(p[k], hw1[k * 64 + j], acc);
  float t = acc > 0.f ? acc : expf(acc) - 1.f;   // ELU
  t *= hw2[j];
  #pragma unroll
  for (int off = 32; off; off >>= 1) t += __shfl_down(t, off, 64);
  if (j == 0) out[gi] = t + hb2[0];
}

// ---------- launch ----------

extern "C" void kernel_launch(void* const* d_in, const int* in_sizes, int n_in,
                              void* d_out, int out_size, void* d_ws, size_t ws_size,
                              hipStream_t stream) {
  const float* x   = (const float*)d_in[0];
  const int*   ei  = (const int*)d_in[1];
  const int*   batch = (const int*)d_in[2];
  const float* w1  = (const float*)d_in[3];
  const float* b1  = (const float*)d_in[4];
  const float* w2  = (const float*)d_in[5];
  const float* cw0 = (const float*)d_in[6];
  const float* cb0 = (const float*)d_in[7];
  const float* cwr = (const float*)d_in[8];
  const float* cbr = (const float*)d_in[9];
  const float* bng = (const float*)d_in[10];
  const float* bnb = (const float*)d_in[11];
  const float* bnm = (const float*)d_in[12];
  const float* bnv = (const float*)d_in[13];
  const float* hw1 = (const float*)d_in[14];
  const float* hb1 = (const float*)d_in[15];
  const float* hw2 = (const float*)d_in[16];
  const float* hb2 = (const float*)d_in[17];
  float* out = (float*)d_out;
  (void)n_in; (void)ws_size;

  const int n = in_sizes[0] / 64;
  const int e = in_sizes[1] / 2;
  const int G = out_size;
  const int* row = ei;
  const int* col = ei + e;
  const int nb128 = (n + 127) / 128;
  const int n_pad = nb128 * 128;

  char* p = (char*)d_ws;
  auto take = [&](size_t bytes) { char* r = p; p += (bytes + 255) & ~(size_t)255; return r; };
  float* cnt    = (float*)take((size_t)SS * 4);
  float* sums   = (float*)take((size_t)SS * 64 * 4);
  float* attn   = (float*)take((size_t)SS * 4);
  float* deg    = (float*)take((size_t)n * 4);
  float* dinv   = (float*)take((size_t)n * 4);
  int*   rowst  = (int*)take(((size_t)n + 1) * 4);
  int*   fill   = (int*)take((size_t)n * 4);
  int*   bsum   = (int*)take(128 * 4);
  int*   gstart = (int*)take(((size_t)G + 1) * 4);
  int2*  sedge  = (int2*)take((size_t)e * 8);
  float* pooled = (float*)take((size_t)G * HH * 4);
  float2* np    = (float2*)take((size_t)n * 8);
  unsigned int* xh = (unsigned int*)take((size_t)n * 32 * 4);
  unsigned int* s0b = (unsigned int*)take((size_t)n_pad * 32 * 4);   // n_pad x 64 bf16
  float* s0x    = (float*)take((size_t)n_pad * 2 * 4);
  unsigned int* sBb = (unsigned int*)take((size_t)n_pad * 64 * 4);   // n_pad x 128 bf16
  unsigned short* hB = (unsigned short*)take((size_t)n_pad * HH * 2);
  unsigned short* wpk0 = (unsigned short*)take((size_t)8 * 2 * 64 * 8 * 2);
  unsigned short* wpkr = (unsigned short*)take((size_t)3 * 8 * 4 * 64 * 8 * 2);
  float* bnS    = (float*)take(4 * 128 * 4);
  float* bnT    = (float*)take(4 * 128 * 4);

  hipMemsetAsync(cnt, 0, (size_t)SS * 4, stream);
  hipMemsetAsync(sums, 0, (size_t)SS * 64 * 4, stream);
  hipMemsetAsync(deg, 0, (size_t)n * 4, stream);
  hipMemsetAsync(fill, 0, (size_t)n * 4, stream);

  gcn_subst_accum<<<(n + 3) / 4, 256, 0, stream>>>(x, cnt, sums, n);
  gcn_scores<<<SS / 4, 256, 0, stream>>>(sums, cnt, w1, b1, w2, attn);
  gcn_softmax<<<1, 1024, 0, stream>>>(attn);

  gcn_deg<<<(e + 255) / 256, 256, 0, stream>>>(col, deg, e);
  gcn_dinv<<<(n + 255) / 256, 256, 0, stream>>>(deg, dinv, n);
  int nb = (n + 1023) / 1024;
  gcn_scan1<<<nb, 1024, 0, stream>>>(deg, rowst, bsum, n);
  gcn_scan2<<<1, 128, 0, stream>>>(bsum, nb);
  gcn_scan3<<<nb, 1024, 0, stream>>>(rowst, bsum, n, e);
  gcn_scatter<<<(e + 255) / 256, 256, 0, stream>>>(row, col, dinv, rowst, fill, sedge, e);
  gcn_gb<<<(G + 256) / 256, 256, 0, stream>>>(batch, gstart, n, G);

  // prep: bf16 x, node {sid,attn} pairs, packed weights, folded BN
  gcn_xb<<<(n * 32 + 255) / 256, 256, 0, stream>>>(x, xh, n);
  gcn_np<<<(n + 255) / 256, 256, 0, stream>>>(x, attn, np, n);
  gcn_wpack<<<(8 * 2 * 64 + 255) / 256, 256, 0, stream>>>(cw0, wpk0, 2);
  for (int l = 0; l < 3; ++l)
    gcn_wpack<<<(8 * 4 * 64 + 255) / 256, 256, 0, stream>>>(cwr + (size_t)l * HH * HH,
        wpkr + (size_t)l * 8 * 4 * 64 * 8, 4);
  gcn_bnp<<<4, 128, 0, stream>>>(cb0, cbr, bng, bnb, bnm, bnv, bnS, bnT);

  // layer 0
  gcn_agg_x<<<(n + 3) / 4, 256, 0, stream>>>(xh, sedge, rowst, dinv, s0b, n);
  gcn_agg_np<<<(n + 255) / 256, 256, 0, stream>>>(np, sedge, rowst, dinv, s0x, n);
  gcn_mm0_mfma<<<n_pad / 64, 256, 0, stream>>>((const unsigned short*)s0b, s0x, wpk0, cw0,
      bnS, bnT, hB);

  // layers 1-3
  for (int l = 0; l < 3; ++l) {
    gcn_aggB<<<(n + 3) / 4, 256, 0, stream>>>(hB, sedge, rowst, dinv, sBb, n);
    gcn_mm_mfma<<<n_pad / 64, 256, 0, stream>>>((const unsigned short*)sBb,
        wpkr + (size_t)l * 8 * 4 * 64 * 8, bnS + (l + 1) * 128, bnT + (l + 1) * 128,
        hB, l == 2 ? 1 : 0);
  }

  gcn_pool2<<<(G + 3) / 4, 256, 0, stream>>>(hB, gstart, pooled, G);
  gcn_head<<<(G + 3) / 4, 256, 0, stream>>>(pooled, hw1, hb1, hw2, hb2, out, G);
}

// Round 7
// 647.727 us; speedup vs baseline: 2.9968x; 1.0915x over previous
//
#include <hip/hip_runtime.h>
#include <math.h>

static constexpr int SS = 4096;   // substructures
static constexpr int HH = 128;    // hidden
static constexpr float EPS_BN = 1e-5f;

typedef __attribute__((ext_vector_type(8))) short bf16x8;
typedef __attribute__((ext_vector_type(4))) float f32x4;

__device__ inline unsigned short f2bf(float f) {       // RNE fp32 -> bf16
  unsigned int u = __float_as_uint(f);
  return (unsigned short)((u + 0x7fffu + ((u >> 16) & 1u)) >> 16);
}
__device__ inline float bflo(unsigned int u) { return __uint_as_float(u << 16); }
__device__ inline float bfhi(unsigned int u) { return __uint_as_float(u & 0xffff0000u); }

// ---------- substructure attention ----------

__global__ void gcn_subst_accum(const float* __restrict__ x, float* __restrict__ cnt,
                                float* __restrict__ sums, int n) {
  int node = blockIdx.x * 4 + (threadIdx.x >> 6);
  int lane = threadIdx.x & 63;
  if (node >= n) return;
  const float* xr = x + (size_t)node * 64;
  float v = xr[lane];
  int sid = (int)__shfl(v, 5, 64);
  if (lane == 0) atomicAdd(&cnt[sid], 1.0f);
  atomicAdd(&sums[(size_t)sid * 64 + lane], v);
}

__global__ void gcn_scores(const float* __restrict__ sums, const float* __restrict__ cnt,
                           const float* __restrict__ w1, const float* __restrict__ b1,
                           const float* __restrict__ w2, float* __restrict__ scores) {
  int s = blockIdx.x * 4 + (threadIdx.x >> 6);
  int j = threadIdx.x & 63;
  float r = 1.0f / fmaxf(cnt[s], 1.0f);
  const float* ss = sums + (size_t)s * 64;
  float acc = b1[j];
  #pragma unroll 8
  for (int d = 0; d < 64; ++d) acc = fmaf(ss[d] * r, w1[d * 64 + j], acc);
  float t = tanhf(acc) * w2[j];
  #pragma unroll
  for (int off = 32; off; off >>= 1) t += __shfl_down(t, off, 64);
  if (j == 0) scores[s] = t;
}

__global__ void gcn_softmax(float* __restrict__ sc) {
  int t = threadIdx.x;
  int wid = t >> 6;
  float v[4]; float m = -INFINITY;
  for (int i = 0; i < 4; ++i) { v[i] = sc[t + i * 1024]; m = fmaxf(m, v[i]); }
  for (int off = 32; off; off >>= 1) m = fmaxf(m, __shfl_xor(m, off, 64));
  __shared__ float wmax[16];
  if ((t & 63) == 0) wmax[wid] = m;
  __syncthreads();
  if (t == 0) { float mm = wmax[0]; for (int i = 1; i < 16; ++i) mm = fmaxf(mm, wmax[i]); wmax[0] = mm; }
  __syncthreads();
  float M = wmax[0];
  float s = 0.f;
  for (int i = 0; i < 4; ++i) { v[i] = expf(v[i] - M); s += v[i]; }
  for (int off = 32; off; off >>= 1) s += __shfl_xor(s, off, 64);
  __shared__ float wsum[16];
  if ((t & 63) == 0) wsum[wid] = s;
  __syncthreads();
  if (t == 0) { float ts = 0.f; for (int i = 0; i < 16; ++i) ts += wsum[i]; wsum[0] = ts; }
  __syncthreads();
  float inv = 1.0f / wsum[0];
  for (int i = 0; i < 4; ++i) sc[t + i * 1024] = v[i] * inv;
}

// ---------- CSR build (single atomic pass) ----------

// one atomic pass: per-edge slot within its col + (in fill) the degree
__global__ void gcn_pos(const int* __restrict__ col, int* __restrict__ fill,
                        int* __restrict__ pos, int e) {
  int i = blockIdx.x * 256 + threadIdx.x;
  if (i < e) pos[i] = atomicAdd(&fill[col[i]], 1);
}

__global__ void gcn_dinv(const int* __restrict__ fill, float* __restrict__ dinv, int n) {
  int i = blockIdx.x * 256 + threadIdx.x;
  if (i < n) dinv[i] = rsqrtf((float)fill[i] + 1.0f);  // +1 = self loop
}

__global__ void gcn_scan1(const int* __restrict__ fill, int* __restrict__ rowstart,
                          int* __restrict__ bsum, int n) {
  __shared__ int tmp[1024];
  int t = threadIdx.x; int g = blockIdx.x * 1024 + t;
  int v = (g < n) ? fill[g] : 0;
  tmp[t] = v; __syncthreads();
  for (int off = 1; off < 1024; off <<= 1) {
    int a = (t >= off) ? tmp[t - off] : 0; __syncthreads();
    tmp[t] += a; __syncthreads();
  }
  if (g < n) rowstart[g] = tmp[t] - v;
  if (t == 1023) bsum[blockIdx.x] = tmp[t];
}

__global__ void gcn_scan2(int* __restrict__ bsum, int nb) {
  __shared__ int tmp[128];
  int t = threadIdx.x;
  int v = (t < nb) ? bsum[t] : 0;
  tmp[t] = v; __syncthreads();
  for (int off = 1; off < 128; off <<= 1) {
    int a = (t >= off) ? tmp[t - off] : 0; __syncthreads();
    tmp[t] += a; __syncthreads();
  }
  if (t < nb) bsum[t] = tmp[t] - v;
}

__global__ void gcn_scan3(int* __restrict__ rowstart, const int* __restrict__ bsum, int n, int e) {
  int g = blockIdx.x * 1024 + threadIdx.x;
  if (g < n) rowstart[g] += bsum[blockIdx.x];
  if (g == 0) rowstart[n] = e;
}

// atomic-free scatter using precomputed slots
__global__ void gcn_scatter2(const int* __restrict__ row, const int* __restrict__ col,
                             const int* __restrict__ pos, const int* __restrict__ rowstart,
                             const float* __restrict__ dinv, int2* __restrict__ sedge, int e) {
  int i = blockIdx.x * 256 + threadIdx.x;
  if (i >= e) return;
  int c = col[i], r = row[i];
  sedge[rowstart[c] + pos[i]] = make_int2(r, __float_as_int(dinv[r] * dinv[c]));
}

// ---------- prep ----------

__global__ void gcn_xb(const float* __restrict__ x, unsigned int* __restrict__ xh, int n) {
  int i = blockIdx.x * 256 + threadIdx.x;            // one uint = 2 features
  if (i >= n * 32) return;
  int pr = i & 31;
  float2 v = *(const float2*)&x[(size_t)(i >> 5) * 64 + pr * 2];
  if (pr == 2) v.y = 0.f;                            // feature 5 handled exactly elsewhere
  xh[i] = (unsigned int)f2bf(v.x) | ((unsigned int)f2bf(v.y) << 16);
}

__global__ void gcn_np(const float* __restrict__ x, const float* __restrict__ attn,
                       float2* __restrict__ np, int n) {
  int i = blockIdx.x * 256 + threadIdx.x;
  if (i >= n) return;
  int sid = (int)x[(size_t)i * 64 + 5];
  np[i] = make_float2((float)sid, attn[sid]);
}

// pack W[128-col matrices] to bf16 MFMA B-fragment layout: out[nt][kc][lane][8]
__global__ void gcn_wpack(const float* __restrict__ W, unsigned short* __restrict__ out, int nkc) {
  int idx = blockIdx.x * 256 + threadIdx.x;          // one per (nt,kc,lane)
  if (idx >= 8 * nkc * 64) return;
  int lane = idx & 63;
  int kc = (idx >> 6) % nkc;
  int nt = idx / (64 * nkc);
  int colc = nt * 16 + (lane & 15);
  int k0 = kc * 32 + (lane >> 4) * 8;
  unsigned int w[4];
  #pragma unroll
  for (int i = 0; i < 4; ++i) {
    unsigned short a = f2bf(W[(size_t)(k0 + 2 * i) * 128 + colc]);
    unsigned short b = f2bf(W[(size_t)(k0 + 2 * i + 1) * 128 + colc]);
    w[i] = (unsigned int)a | ((unsigned int)b << 16);
  }
  *(uint4*)&out[(size_t)idx * 8] = make_uint4(w[0], w[1], w[2], w[3]);
}

// fold BN: u = z*S + T per layer/col
__global__ void gcn_bnp(const float* __restrict__ cb0, const float* __restrict__ cbr,
                        const float* __restrict__ bng, const float* __restrict__ bnb,
                        const float* __restrict__ bnm, const float* __restrict__ bnv,
                        float* __restrict__ bnS, float* __restrict__ bnT) {
  int i = blockIdx.x * 128 + threadIdx.x;            // 0..511
  int l = i >> 7, c = i & 127;
  float S = rsqrtf(bnv[i] + EPS_BN) * bng[i];
  float bias = (l == 0) ? cb0[c] : cbr[(l - 1) * 128 + c];
  bnS[i] = S;
  bnT[i] = fmaf(bias - bnm[i], S, bnb[i]);
}

// ---------- layer-0 aggregation ----------

__global__ void gcn_agg_x(const unsigned int* __restrict__ xh, const int2* __restrict__ sedge,
                          const int* __restrict__ rowstart, const float* __restrict__ dinv,
                          unsigned int* __restrict__ s0b, int n) {
  int node = blockIdx.x * 4 + (threadIdx.x >> 6);
  int lane = threadIdx.x & 63;
  if (node >= n) return;
  float di = dinv[node], d2 = di * di;
  unsigned int us = xh[(size_t)node * 32 + (lane & 31)];
  float ax = (lane < 32) ? bflo(us) * d2 : 0.f;
  float ay = (lane < 32) ? bfhi(us) * d2 : 0.f;
  int s_ = rowstart[node], e_ = rowstart[node + 1];
  for (int b = s_; b < e_; b += 8) {
    int idx = b + (lane & 7);
    int2 se = (idx < e_) ? sedge[idx] : make_int2(node, 0);
    #pragma unroll
    for (int j = 0; j < 8; j += 2) {
      int sa = __shfl(se.x, j, 8), sb = __shfl(se.x, j + 1, 8);
      float wa = __int_as_float(__shfl(se.y, j, 8));
      float wb = __int_as_float(__shfl(se.y, j + 1, 8));
      int src = (lane < 32) ? sa : sb;
      float w = (lane < 32) ? wa : wb;
      unsigned int u = xh[(size_t)src * 32 + (lane & 31)];
      ax = fmaf(bflo(u), w, ax);
      ay = fmaf(bfhi(u), w, ay);
    }
  }
  ax += __shfl_xor(ax, 32, 64);
  ay += __shfl_xor(ay, 32, 64);
  if (lane < 32)
    s0b[(size_t)node * 32 + lane] = (unsigned int)f2bf(ax) | ((unsigned int)f2bf(ay) << 16);
}

// exact fp32 {sid, attn} aggregates. thread per node.
__global__ void gcn_agg_np(const float2* __restrict__ np, const int2* __restrict__ sedge,
                           const int* __restrict__ rowstart, const float* __restrict__ dinv,
                           float* __restrict__ s0x, int n) {
  int i = blockIdx.x * 256 + threadIdx.x;
  if (i >= n) return;
  float di = dinv[i], d2 = di * di;
  float2 self = np[i];
  float a5 = d2 * self.x, a64 = d2 * self.y;
  int s_ = rowstart[i], e_ = rowstart[i + 1];
  for (int ee = s_; ee < e_; ++ee) {
    int2 se = sedge[ee];
    float w = __int_as_float(se.y);
    float2 v = np[se.x];
    a5 = fmaf(v.x, w, a5);
    a64 = fmaf(v.y, w, a64);
  }
  s0x[(size_t)i * 2] = a5;
  s0x[(size_t)i * 2 + 1] = a64;
}

// ---------- layers 1-3 aggregation (bf16 h -> bf16 s, fp32 accumulate) ----------

__global__ void gcn_aggB(const unsigned short* __restrict__ hB, const int2* __restrict__ sedge,
                         const int* __restrict__ rowstart, const float* __restrict__ dinv,
                         unsigned int* __restrict__ sBb, int n) {
  int node = blockIdx.x * 4 + (threadIdx.x >> 6);
  int lane = threadIdx.x & 63;
  if (node >= n) return;
  float di = dinv[node], d2 = di * di;
  const unsigned int* h32 = (const unsigned int*)hB;
  unsigned int us = h32[(size_t)node * 64 + lane];
  float ax = bflo(us) * d2, ay = bfhi(us) * d2;
  int s_ = rowstart[node], e_ = rowstart[node + 1];
  for (int b = s_; b < e_; b += 8) {
    int idx = b + (lane & 7);
    int2 se = (idx < e_) ? sedge[idx] : make_int2(node, 0);
    #pragma unroll
    for (int j = 0; j < 8; ++j) {
      int src = __shfl(se.x, j, 8);
      float w = __int_as_float(__shfl(se.y, j, 8));
      unsigned int u = h32[(size_t)src * 64 + lane];
      ax = fmaf(bflo(u), w, ax);
      ay = fmaf(bfhi(u), w, ay);
    }
  }
  sBb[(size_t)node * 64 + lane] = (unsigned int)f2bf(ax) | ((unsigned int)f2bf(ay) << 16);
}

// ---------- MFMA GEMM + BN + activation -> bf16 h ----------

__global__ __launch_bounds__(256)
void gcn_mm_mfma(const unsigned short* __restrict__ A, const unsigned short* __restrict__ Wpk,
                 const float* __restrict__ bnS, const float* __restrict__ bnT,
                 unsigned short* __restrict__ hB, int relu) {
  __shared__ unsigned short tile[4][16][136];
  int t = threadIdx.x;
  int wid = t >> 6, l = t & 63;
  int rowA = l & 15, kg = l >> 4;
  size_t row0w = (size_t)blockIdx.x * 64 + wid * 16;
  const unsigned short* Ar = A + (row0w + rowA) * 128 + kg * 8;
  bf16x8 af[4];
  #pragma unroll
  for (int kc = 0; kc < 4; ++kc) af[kc] = *(const bf16x8*)(Ar + kc * 32);
  f32x4 acc[8];
  #pragma unroll
  for (int nt = 0; nt < 8; ++nt) acc[nt] = (f32x4){0.f, 0.f, 0.f, 0.f};
  const unsigned short* wp = Wpk + (size_t)l * 8;
  #pragma unroll
  for (int kc = 0; kc < 4; ++kc) {
    bf16x8 bf[8];
    #pragma unroll
    for (int nt = 0; nt < 8; ++nt)
      bf[nt] = *(const bf16x8*)(wp + (size_t)(nt * 4 + kc) * 512);
    #pragma unroll
    for (int nt = 0; nt < 8; ++nt)
      acc[nt] = __builtin_amdgcn_mfma_f32_16x16x32_bf16(af[kc], bf[nt], acc[nt], 0, 0, 0);
  }
  int colb = l & 15, rb = kg * 4;
  #pragma unroll
  for (int nt = 0; nt < 8; ++nt) {
    int c = nt * 16 + colb;
    float S = bnS[c], T = bnT[c];
    #pragma unroll
    for (int j = 0; j < 4; ++j) {
      float v = fmaf(acc[nt][j], S, T);
      v = relu ? fmaxf(v, 0.f) : (v > 0.f ? v : expf(v) - 1.f);
      tile[wid][rb + j][c] = f2bf(v);
    }
  }
  __syncthreads();
  #pragma unroll
  for (int i = 0; i < 4; ++i) {
    int m = i * 64 + l;
    int row = m >> 4, chunk = m & 15;
    uint4 v = *(const uint4*)&tile[wid][row][chunk * 8];
    *(uint4*)&hB[(row0w + row) * 128 + chunk * 8] = v;
  }
}

// layer 0: A = s0b (n_pad x 64 bf16, col5 zeroed), + exact fp32 sid/attn features
__global__ __launch_bounds__(256)
void gcn_mm0_mfma(const unsigned short* __restrict__ A, const float* __restrict__ s0x,
                  const unsigned short* __restrict__ Wpk0, const float* __restrict__ cw0,
                  const float* __restrict__ bnS, const float* __restrict__ bnT,
                  unsigned short* __restrict__ hB) {
  __shared__ unsigned short tile[4][16][136];
  int t = threadIdx.x;
  int wid = t >> 6, l = t & 63;
  int rowA = l & 15, kg = l >> 4;
  size_t row0w = (size_t)blockIdx.x * 64 + wid * 16;
  const unsigned short* Ar = A + (row0w + rowA) * 64 + kg * 8;
  bf16x8 af[2];
  #pragma unroll
  for (int kc = 0; kc < 2; ++kc) af[kc] = *(const bf16x8*)(Ar + kc * 32);
  f32x4 acc[8];
  #pragma unroll
  for (int nt = 0; nt < 8; ++nt) acc[nt] = (f32x4){0.f, 0.f, 0.f, 0.f};
  const unsigned short* wp = Wpk0 + (size_t)l * 8;
  #pragma unroll
  for (int kc = 0; kc < 2; ++kc) {
    bf16x8 bf[8];
    #pragma unroll
    for (int nt = 0; nt < 8; ++nt)
      bf[nt] = *(const bf16x8*)(wp + (size_t)(nt * 2 + kc) * 512);
    #pragma unroll
    for (int nt = 0; nt < 8; ++nt)
      acc[nt] = __builtin_amdgcn_mfma_f32_16x16x32_bf16(af[kc], bf[nt], acc[nt], 0, 0, 0);
  }
  int colb = l & 15, rb = kg * 4;
  float2 ax[4];
  #pragma unroll
  for (int j = 0; j < 4; ++j) ax[j] = *(const float2*)&s0x[(row0w + rb + j) * 2];
  #pragma unroll
  for (int nt = 0; nt < 8; ++nt) {
    int c = nt * 16 + colb;
    float w5 = cw0[5 * 128 + c], w64 = cw0[64 * 128 + c];
    float S = bnS[c], T = bnT[c];
    #pragma unroll
    for (int j = 0; j < 4; ++j) {
      float z = acc[nt][j] + ax[j].x * w5 + ax[j].y * w64;
      float v = fmaf(z, S, T);
      v = v > 0.f ? v : expf(v) - 1.f;   // ELU
      tile[wid][rb + j][c] = f2bf(v);
    }
  }
  __syncthreads();
  #pragma unroll
  for (int i = 0; i < 4; ++i) {
    int m = i * 64 + l;
    int row = m >> 4, chunk = m & 15;
    uint4 v = *(const uint4*)&tile[wid][row][chunk * 8];
    *(uint4*)&hB[(row0w + row) * 128 + chunk * 8] = v;
  }
}

// ---------- pooling (batch sorted -> contiguous ranges) ----------

__global__ void gcn_gb(const int* __restrict__ batch, int* __restrict__ gstart, int n, int G) {
  int g = blockIdx.x * 256 + threadIdx.x;
  if (g > G) return;
  if (g == G) { gstart[G] = n; return; }
  int lo = 0, hi = n;
  while (lo < hi) { int mid = (lo + hi) >> 1; if (batch[mid] < g) lo = mid + 1; else hi = mid; }
  gstart[g] = lo;
}

__global__ void gcn_pool2(const unsigned short* __restrict__ hB, const int* __restrict__ gstart,
                          float* __restrict__ pooled, int G) {
  int g = blockIdx.x * 4 + (threadIdx.x >> 6);
  int lane = threadIdx.x & 63;
  if (g >= G) return;
  int s = gstart[g], epos = gstart[g + 1];
  const unsigned int* h32 = (const unsigned int*)hB;
  float ax = 0.f, ay = 0.f;
  for (int i = s; i < epos; ++i) {
    unsigned int u = h32[(size_t)i * 64 + lane];
    ax += bflo(u);
    ay += bfhi(u);
  }
  float r = 1.0f / fmaxf((float)(epos - s), 1.0f);
  ((float2*)pooled)[(size_t)g * 64 + lane] = make_float2(ax * r, ay * r);
}

__global__ void gcn_head(const float* __restrict__ pooled,
                         const float* __restrict__ hw1, const float* __restrict__ hb1,
                         const float* __restrict__ hw2, const float* __restrict__ hb2,
                         float* __restrict__ out, int g) {
  int gi = blockIdx.x * 4 + (threadIdx.x >> 6);
  int j = threadIdx.x & 63;
  if (gi >= g) return;
  const float* p = pooled + (size_t)gi * 128;
  float acc = hb1[j];
  #pragma unroll 8
  for (int k = 0; k < 128; ++k) acc = fmaf(p[k], hw1[k * 64 + j], acc);
  float t = acc > 0.f ? acc : expf(acc) - 1.f;   // ELU
  t *= hw2[j];
  #pragma unroll
  for (int off = 32; off; off >>= 1) t += __shfl_down(t, off, 64);
  if (j == 0) out[gi] = t + hb2[0];
}

// ---------- launch ----------

extern "C" void kernel_launch(void* const* d_in, const int* in_sizes, int n_in,
                              void* d_out, int out_size, void* d_ws, size_t ws_size,
                              hipStream_t stream) {
  const float* x   = (const float*)d_in[0];
  const int*   ei  = (const int*)d_in[1];
  const int*   batch = (const int*)d_in[2];
  const float* w1  = (const float*)d_in[3];
  const float* b1  = (const float*)d_in[4];
  const float* w2  = (const float*)d_in[5];
  const float* cw0 = (const float*)d_in[6];
  const float* cb0 = (const float*)d_in[7];
  const float* cwr = (const float*)d_in[8];
  const float* cbr = (const float*)d_in[9];
  const float* bng = (const float*)d_in[10];
  const float* bnb = (const float*)d_in[11];
  const float* bnm = (const float*)d_in[12];
  const float* bnv = (const float*)d_in[13];
  const float* hw1 = (const float*)d_in[14];
  const float* hb1 = (const float*)d_in[15];
  const float* hw2 = (const float*)d_in[16];
  const float* hb2 = (const float*)d_in[17];
  float* out = (float*)d_out;
  (void)n_in; (void)ws_size;

  const int n = in_sizes[0] / 64;
  const int e = in_sizes[1] / 2;
  const int G = out_size;
  const int* row = ei;
  const int* col = ei + e;
  const int nb128 = (n + 127) / 128;
  const int n_pad = nb128 * 128;

  char* p = (char*)d_ws;
  auto take = [&](size_t bytes) { char* r = p; p += (bytes + 255) & ~(size_t)255; return r; };
  float* cnt    = (float*)take((size_t)SS * 4);
  float* sums   = (float*)take((size_t)SS * 64 * 4);
  float* attn   = (float*)take((size_t)SS * 4);
  float* dinv   = (float*)take((size_t)n * 4);
  int*   rowst  = (int*)take(((size_t)n + 1) * 4);
  int*   fill   = (int*)take((size_t)n * 4);
  int*   pos    = (int*)take((size_t)e * 4);
  int*   bsum   = (int*)take(128 * 4);
  int*   gstart = (int*)take(((size_t)G + 1) * 4);
  int2*  sedge  = (int2*)take((size_t)e * 8);
  float* pooled = (float*)take((size_t)G * HH * 4);
  float2* np    = (float2*)take((size_t)n * 8);
  unsigned int* xh = (unsigned int*)take((size_t)n * 32 * 4);
  unsigned int* s0b = (unsigned int*)take((size_t)n_pad * 32 * 4);   // n_pad x 64 bf16
  float* s0x    = (float*)take((size_t)n_pad * 2 * 4);
  unsigned int* sBb = (unsigned int*)take((size_t)n_pad * 64 * 4);   // n_pad x 128 bf16
  unsigned short* hB = (unsigned short*)take((size_t)n_pad * HH * 2);
  unsigned short* wpk0 = (unsigned short*)take((size_t)8 * 2 * 64 * 8 * 2);
  unsigned short* wpkr = (unsigned short*)take((size_t)3 * 8 * 4 * 64 * 8 * 2);
  float* bnS    = (float*)take(4 * 128 * 4);
  float* bnT    = (float*)take(4 * 128 * 4);

  hipMemsetAsync(cnt, 0, (size_t)SS * 4, stream);
  hipMemsetAsync(sums, 0, (size_t)SS * 64 * 4, stream);
  hipMemsetAsync(fill, 0, (size_t)n * 4, stream);

  gcn_subst_accum<<<(n + 3) / 4, 256, 0, stream>>>(x, cnt, sums, n);
  gcn_scores<<<SS / 4, 256, 0, stream>>>(sums, cnt, w1, b1, w2, attn);
  gcn_softmax<<<1, 1024, 0, stream>>>(attn);

  // CSR build: one atomic pass (pos+degree), then scan, then atomic-free scatter
  gcn_pos<<<(e + 255) / 256, 256, 0, stream>>>(col, fill, pos, e);
  gcn_dinv<<<(n + 255) / 256, 256, 0, stream>>>(fill, dinv, n);
  int nb = (n + 1023) / 1024;
  gcn_scan1<<<nb, 1024, 0, stream>>>(fill, rowst, bsum, n);
  gcn_scan2<<<1, 128, 0, stream>>>(bsum, nb);
  gcn_scan3<<<nb, 1024, 0, stream>>>(rowst, bsum, n, e);
  gcn_scatter2<<<(e + 255) / 256, 256, 0, stream>>>(row, col, pos, rowst, dinv, sedge, e);
  gcn_gb<<<(G + 256) / 256, 256, 0, stream>>>(batch, gstart, n, G);

  // prep: bf16 x, node {sid,attn} pairs, packed weights, folded BN
  gcn_xb<<<(n * 32 + 255) / 256, 256, 0, stream>>>(x, xh, n);
  gcn_np<<<(n + 255) / 256, 256, 0, stream>>>(x, attn, np, n);
  gcn_wpack<<<(8 * 2 * 64 + 255) / 256, 256, 0, stream>>>(cw0, wpk0, 2);
  for (int l = 0; l < 3; ++l)
    gcn_wpack<<<(8 * 4 * 64 + 255) / 256, 256, 0, stream>>>(cwr + (size_t)l * HH * HH,
        wpkr + (size_t)l * 8 * 4 * 64 * 8, 4);
  gcn_bnp<<<4, 128, 0, stream>>>(cb0, cbr, bng, bnb, bnm, bnv, bnS, bnT);

  // layer 0
  gcn_agg_x<<<(n + 3) / 4, 256, 0, stream>>>(xh, sedge, rowst, dinv, s0b, n);
  gcn_agg_np<<<(n + 255) / 256, 256, 0, stream>>>(np, sedge, rowst, dinv, s0x, n);
  gcn_mm0_mfma<<<n_pad / 64, 256, 0, stream>>>((const unsigned short*)s0b, s0x, wpk0, cw0,
      bnS, bnT, hB);

  // layers 1-3
  for (int l = 0; l < 3; ++l) {
    gcn_aggB<<<(n + 3) / 4, 256, 0, stream>>>(hB, sedge, rowst, dinv, sBb, n);
    gcn_mm_mfma<<<n_pad / 64, 256, 0, stream>>>((const unsigned short*)sBb,
        wpkr + (size_t)l * 8 * 4 * 64 * 8, bnS + (l + 1) * 128, bnT + (l + 1) * 128,
        hB, l == 2 ? 1 : 0);
  }

  gcn_pool2<<<(G + 3) / 4, 256, 0, stream>>>(hB, gstart, pooled, G);
  gcn_head<<<(G + 3) / 4, 256, 0, stream>>>(pooled, hw1, hb1, hw2, hb2, out, G);
}

// Round 8
// 634.605 us; speedup vs baseline: 3.0587x; 1.0207x over previous
//
#include <hip/hip_runtime.h>
#include <math.h>

static constexpr int SS = 4096;   // substructures
static constexpr int HH = 128;    // hidden
static constexpr float EPS_BN = 1e-5f;

typedef __attribute__((ext_vector_type(8))) short bf16x8;
typedef __attribute__((ext_vector_type(4))) float f32x4;

__device__ inline unsigned short f2bf(float f) {       // RNE fp32 -> bf16
  unsigned int u = __float_as_uint(f);
  return (unsigned short)((u + 0x7fffu + ((u >> 16) & 1u)) >> 16);
}
__device__ inline float bflo(unsigned int u) { return __uint_as_float(u << 16); }
__device__ inline float bfhi(unsigned int u) { return __uint_as_float(u & 0xffff0000u); }

// ---------- FRONT1: pos-atomics || subst-accum || xb || gb || wpack x4 || bnp ----------

__device__ void wpack_body(const float* __restrict__ W, unsigned short* __restrict__ out,
                           int nkc, int idx) {
  if (idx >= 8 * nkc * 64) return;
  int lane = idx & 63;
  int kc = (idx >> 6) % nkc;
  int nt = idx / (64 * nkc);
  int colc = nt * 16 + (lane & 15);
  int k0 = kc * 32 + (lane >> 4) * 8;
  unsigned int w[4];
  #pragma unroll
  for (int i = 0; i < 4; ++i) {
    unsigned short a = f2bf(W[(size_t)(k0 + 2 * i) * 128 + colc]);
    unsigned short b = f2bf(W[(size_t)(k0 + 2 * i + 1) * 128 + colc]);
    w[i] = (unsigned int)a | ((unsigned int)b << 16);
  }
  *(uint4*)&out[(size_t)idx * 8] = make_uint4(w[0], w[1], w[2], w[3]);
}

__global__ __launch_bounds__(256)
void gcn_front1(const int* __restrict__ col, int* __restrict__ fill, int* __restrict__ pos,
                const float* __restrict__ x, float* __restrict__ cnt, float* __restrict__ sums,
                unsigned int* __restrict__ xh, const int* __restrict__ batch,
                int* __restrict__ gstart,
                const float* __restrict__ cw0, const float* __restrict__ cwr,
                unsigned short* __restrict__ wpk0, unsigned short* __restrict__ wpkr,
                const float* __restrict__ cb0, const float* __restrict__ cbr,
                const float* __restrict__ bng, const float* __restrict__ bnb,
                const float* __restrict__ bnm, const float* __restrict__ bnv,
                float* __restrict__ bnS, float* __restrict__ bnT,
                int n, int e, int G,
                int nbPos, int nbSub, int nbXb, int nbGb, int nbW0, int nbWr) {
  int b = blockIdx.x;
  int t = threadIdx.x;
  if (b < nbPos) {                       // one atomic pass: slot + degree
    int i = b * 256 + t;
    if (i < e) pos[i] = atomicAdd(&fill[col[i]], 1);
    return;
  }
  b -= nbPos;
  if (b < nbSub) {                       // substructure sums (coalesced atomics)
    int node = b * 4 + (t >> 6);
    int lane = t & 63;
    if (node >= n) return;
    const float* xr = x + (size_t)node * 64;
    float v = xr[lane];
    int sid = (int)__shfl(v, 5, 64);
    if (lane == 0) atomicAdd(&cnt[sid], 1.0f);
    atomicAdd(&sums[(size_t)sid * 64 + lane], v);
    return;
  }
  b -= nbSub;
  if (b < nbXb) {                        // bf16 x with col5 zeroed
    int i = b * 256 + t;
    if (i >= n * 32) return;
    int pr = i & 31;
    float2 v = *(const float2*)&x[(size_t)(i >> 5) * 64 + pr * 2];
    if (pr == 2) v.y = 0.f;
    xh[i] = (unsigned int)f2bf(v.x) | ((unsigned int)f2bf(v.y) << 16);
    return;
  }
  b -= nbXb;
  if (b < nbGb) {                        // graph starts (batch sorted)
    int g = b * 256 + t;
    if (g > G) return;
    if (g == G) { gstart[G] = n; return; }
    int lo = 0, hi = n;
    while (lo < hi) { int mid = (lo + hi) >> 1; if (batch[mid] < g) lo = mid + 1; else hi = mid; }
    gstart[g] = lo;
    return;
  }
  b -= nbGb;
  if (b < nbW0) { wpack_body(cw0, wpk0, 2, b * 256 + t); return; }
  b -= nbW0;
  if (b < 3 * nbWr) {
    int l = b / nbWr, bb = b % nbWr;
    wpack_body(cwr + (size_t)l * HH * HH, wpkr + (size_t)l * 8 * 4 * 64 * 8, 4, bb * 256 + t);
    return;
  }
  b -= 3 * nbWr;
  {                                      // fold BN
    int i = b * 256 + t;
    if (i >= 512) return;
    int l = i >> 7, c = i & 127;
    float S = rsqrtf(bnv[i] + EPS_BN) * bng[i];
    float bias = (l == 0) ? cb0[c] : cbr[(l - 1) * 128 + c];
    bnS[i] = S;
    bnT[i] = fmaf(bias - bnm[i], S, bnb[i]);
  }
}

// ---------- substructure attention (scores + softmax) ----------

__global__ void gcn_scores(const float* __restrict__ sums, const float* __restrict__ cnt,
                           const float* __restrict__ w1, const float* __restrict__ b1,
                           const float* __restrict__ w2, float* __restrict__ scores) {
  int s = blockIdx.x * 4 + (threadIdx.x >> 6);
  int j = threadIdx.x & 63;
  float r = 1.0f / fmaxf(cnt[s], 1.0f);
  const float* ss = sums + (size_t)s * 64;
  float acc = b1[j];
  #pragma unroll 8
  for (int d = 0; d < 64; ++d) acc = fmaf(ss[d] * r, w1[d * 64 + j], acc);
  float t = tanhf(acc) * w2[j];
  #pragma unroll
  for (int off = 32; off; off >>= 1) t += __shfl_down(t, off, 64);
  if (j == 0) scores[s] = t;
}

__global__ void gcn_softmax(float* __restrict__ sc) {
  int t = threadIdx.x;
  int wid = t >> 6;
  float v[4]; float m = -INFINITY;
  for (int i = 0; i < 4; ++i) { v[i] = sc[t + i * 1024]; m = fmaxf(m, v[i]); }
  for (int off = 32; off; off >>= 1) m = fmaxf(m, __shfl_xor(m, off, 64));
  __shared__ float wmax[16];
  if ((t & 63) == 0) wmax[wid] = m;
  __syncthreads();
  if (t == 0) { float mm = wmax[0]; for (int i = 1; i < 16; ++i) mm = fmaxf(mm, wmax[i]); wmax[0] = mm; }
  __syncthreads();
  float M = wmax[0];
  float s = 0.f;
  for (int i = 0; i < 4; ++i) { v[i] = expf(v[i] - M); s += v[i]; }
  for (int off = 32; off; off >>= 1) s += __shfl_xor(s, off, 64);
  __shared__ float wsum[16];
  if ((t & 63) == 0) wsum[wid] = s;
  __syncthreads();
  if (t == 0) { float ts = 0.f; for (int i = 0; i < 16; ++i) ts += wsum[i]; wsum[0] = ts; }
  __syncthreads();
  float inv = 1.0f / wsum[0];
  for (int i = 0; i < 4; ++i) sc[t + i * 1024] = v[i] * inv;
}

// ---------- scan (dinv fused into pass 1) ----------

__global__ void gcn_scan1(const int* __restrict__ fill, int* __restrict__ rowstart,
                          int* __restrict__ bsum, float* __restrict__ dinv, int n) {
  __shared__ int tmp[1024];
  int t = threadIdx.x; int g = blockIdx.x * 1024 + t;
  int v = (g < n) ? fill[g] : 0;
  if (g < n) dinv[g] = rsqrtf((float)v + 1.0f);   // +1 = self loop
  tmp[t] = v; __syncthreads();
  for (int off = 1; off < 1024; off <<= 1) {
    int a = (t >= off) ? tmp[t - off] : 0; __syncthreads();
    tmp[t] += a; __syncthreads();
  }
  if (g < n) rowstart[g] = tmp[t] - v;
  if (t == 1023) bsum[blockIdx.x] = tmp[t];
}

__global__ void gcn_scan2(int* __restrict__ bsum, int nb) {
  __shared__ int tmp[128];
  int t = threadIdx.x;
  int v = (t < nb) ? bsum[t] : 0;
  tmp[t] = v; __syncthreads();
  for (int off = 1; off < 128; off <<= 1) {
    int a = (t >= off) ? tmp[t - off] : 0; __syncthreads();
    tmp[t] += a; __syncthreads();
  }
  if (t < nb) bsum[t] = tmp[t] - v;
}

__global__ void gcn_scan3(int* __restrict__ rowstart, const int* __restrict__ bsum, int n, int e) {
  int g = blockIdx.x * 1024 + threadIdx.x;
  if (g < n) rowstart[g] += bsum[blockIdx.x];
  if (g == 0) rowstart[n] = e;
}

// ---------- FRONT3: np table || atomic-free scatter ----------

__global__ __launch_bounds__(256)
void gcn_front3(const float* __restrict__ x, const float* __restrict__ attn,
                float2* __restrict__ np,
                const int* __restrict__ row, const int* __restrict__ col,
                const int* __restrict__ pos, const int* __restrict__ rowstart,
                const float* __restrict__ dinv, int2* __restrict__ sedge,
                int n, int e, int nbNp) {
  int b = blockIdx.x;
  int t = threadIdx.x;
  if (b < nbNp) {
    int i = b * 256 + t;
    if (i >= n) return;
    int sid = (int)x[(size_t)i * 64 + 5];
    np[i] = make_float2((float)sid, attn[sid]);
    return;
  }
  b -= nbNp;
  int i = b * 256 + t;
  if (i >= e) return;
  int c = col[i], r = row[i];
  sedge[rowstart[c] + pos[i]] = make_int2(r, __float_as_int(dinv[r] * dinv[c]));
}

// ---------- FRONT4: layer-0 aggregation (x bf16, 8 edges in flight) || exact sid/attn agg ----------

__global__ __launch_bounds__(256)
void gcn_front4(const unsigned int* __restrict__ xh, const float2* __restrict__ np,
                const int2* __restrict__ sedge, const int* __restrict__ rowstart,
                const float* __restrict__ dinv,
                unsigned int* __restrict__ s0b, float* __restrict__ s0x,
                int n, int nbAx) {
  int blk = blockIdx.x;
  int t = threadIdx.x;
  if (blk < nbAx) {
    // eighth-wave: 8 groups x 8 lanes; group g handles edge b+g; lane covers 8 feats
    int node = blk * 4 + (t >> 6);
    int lane = t & 63;
    if (node >= n) return;
    int g = lane >> 3, sl = lane & 7;
    float di = dinv[node], d2 = di * di;
    const uint4* x4 = (const uint4*)xh;
    float a[8];
    if (g == 0) {
      uint4 u = x4[(size_t)node * 8 + sl];
      a[0] = bflo(u.x) * d2; a[1] = bfhi(u.x) * d2;
      a[2] = bflo(u.y) * d2; a[3] = bfhi(u.y) * d2;
      a[4] = bflo(u.z) * d2; a[5] = bfhi(u.z) * d2;
      a[6] = bflo(u.w) * d2; a[7] = bfhi(u.w) * d2;
    } else {
      #pragma unroll
      for (int i = 0; i < 8; ++i) a[i] = 0.f;
    }
    int s_ = rowstart[node], e_ = rowstart[node + 1];
    for (int b = s_; b < e_; b += 8) {
      int idx = b + (lane & 7);
      int2 se = (idx < e_) ? sedge[idx] : make_int2(node, 0);
      int src = __shfl(se.x, g, 8);
      float w = __int_as_float(__shfl(se.y, g, 8));
      uint4 u = x4[(size_t)src * 8 + sl];
      a[0] = fmaf(bflo(u.x), w, a[0]); a[1] = fmaf(bfhi(u.x), w, a[1]);
      a[2] = fmaf(bflo(u.y), w, a[2]); a[3] = fmaf(bfhi(u.y), w, a[3]);
      a[4] = fmaf(bflo(u.z), w, a[4]); a[5] = fmaf(bfhi(u.z), w, a[5]);
      a[6] = fmaf(bflo(u.w), w, a[6]); a[7] = fmaf(bfhi(u.w), w, a[7]);
    }
    #pragma unroll
    for (int i = 0; i < 8; ++i) {
      a[i] += __shfl_xor(a[i], 8, 64);
      a[i] += __shfl_xor(a[i], 16, 64);
      a[i] += __shfl_xor(a[i], 32, 64);
    }
    if (g == 0) {
      uint4 o;
      o.x = (unsigned)f2bf(a[0]) | ((unsigned)f2bf(a[1]) << 16);
      o.y = (unsigned)f2bf(a[2]) | ((unsigned)f2bf(a[3]) << 16);
      o.z = (unsigned)f2bf(a[4]) | ((unsigned)f2bf(a[5]) << 16);
      o.w = (unsigned)f2bf(a[6]) | ((unsigned)f2bf(a[7]) << 16);
      ((uint4*)s0b)[(size_t)node * 8 + sl] = o;
    }
    return;
  }
  // exact fp32 {sid, attn} aggregates, thread per node
  int i = (blk - nbAx) * 256 + t;
  if (i >= n) return;
  float di = dinv[i], d2 = di * di;
  float2 self = np[i];
  float a5 = d2 * self.x, a64 = d2 * self.y;
  int s_ = rowstart[i], e_ = rowstart[i + 1];
  for (int ee = s_; ee < e_; ++ee) {
    int2 se = sedge[ee];
    float w = __int_as_float(se.y);
    float2 v = np[se.x];
    a5 = fmaf(v.x, w, a5);
    a64 = fmaf(v.y, w, a64);
  }
  s0x[(size_t)i * 2] = a5;
  s0x[(size_t)i * 2 + 1] = a64;
}

// ---------- layers 1-3 aggregation: quarter-wave, 4 edges in flight ----------

__global__ __launch_bounds__(256)
void gcn_aggB(const unsigned short* __restrict__ hB, const int2* __restrict__ sedge,
              const int* __restrict__ rowstart, const float* __restrict__ dinv,
              unsigned int* __restrict__ sBb, int n) {
  int node = blockIdx.x * 4 + (threadIdx.x >> 6);
  int lane = threadIdx.x & 63;
  if (node >= n) return;
  int g = lane >> 4, sl = lane & 15;
  float di = dinv[node], d2 = di * di;
  const uint4* h4 = (const uint4*)hB;
  float a[8];
  if (g == 0) {
    uint4 u = h4[(size_t)node * 16 + sl];
    a[0] = bflo(u.x) * d2; a[1] = bfhi(u.x) * d2;
    a[2] = bflo(u.y) * d2; a[3] = bfhi(u.y) * d2;
    a[4] = bflo(u.z) * d2; a[5] = bfhi(u.z) * d2;
    a[6] = bflo(u.w) * d2; a[7] = bfhi(u.w) * d2;
  } else {
    #pragma unroll
    for (int i = 0; i < 8; ++i) a[i] = 0.f;
  }
  int s_ = rowstart[node], e_ = rowstart[node + 1];
  for (int b = s_; b < e_; b += 8) {
    int idx = b + (lane & 7);
    int2 se = (idx < e_) ? sedge[idx] : make_int2(node, 0);
    #pragma unroll
    for (int j = 0; j < 2; ++j) {
      int src = __shfl(se.x, j * 4 + g, 8);
      float w = __int_as_float(__shfl(se.y, j * 4 + g, 8));
      uint4 u = h4[(size_t)src * 16 + sl];
      a[0] = fmaf(bflo(u.x), w, a[0]); a[1] = fmaf(bfhi(u.x), w, a[1]);
      a[2] = fmaf(bflo(u.y), w, a[2]); a[3] = fmaf(bfhi(u.y), w, a[3]);
      a[4] = fmaf(bflo(u.z), w, a[4]); a[5] = fmaf(bfhi(u.z), w, a[5]);
      a[6] = fmaf(bflo(u.w), w, a[6]); a[7] = fmaf(bfhi(u.w), w, a[7]);
    }
  }
  #pragma unroll
  for (int i = 0; i < 8; ++i) {
    a[i] += __shfl_xor(a[i], 16, 64);
    a[i] += __shfl_xor(a[i], 32, 64);
  }
  if (g == 0) {
    uint4 o;
    o.x = (unsigned)f2bf(a[0]) | ((unsigned)f2bf(a[1]) << 16);
    o.y = (unsigned)f2bf(a[2]) | ((unsigned)f2bf(a[3]) << 16);
    o.z = (unsigned)f2bf(a[4]) | ((unsigned)f2bf(a[5]) << 16);
    o.w = (unsigned)f2bf(a[6]) | ((unsigned)f2bf(a[7]) << 16);
    ((uint4*)sBb)[(size_t)node * 16 + sl] = o;
  }
}

// ---------- MFMA GEMM + BN + activation -> bf16 h ----------

__global__ __launch_bounds__(256)
void gcn_mm_mfma(const unsigned short* __restrict__ A, const unsigned short* __restrict__ Wpk,
                 const float* __restrict__ bnS, const float* __restrict__ bnT,
                 unsigned short* __restrict__ hB, int relu) {
  __shared__ unsigned short tile[4][16][136];
  int t = threadIdx.x;
  int wid = t >> 6, l = t & 63;
  int rowA = l & 15, kg = l >> 4;
  size_t row0w = (size_t)blockIdx.x * 64 + wid * 16;
  const unsigned short* Ar = A + (row0w + rowA) * 128 + kg * 8;
  bf16x8 af[4];
  #pragma unroll
  for (int kc = 0; kc < 4; ++kc) af[kc] = *(const bf16x8*)(Ar + kc * 32);
  f32x4 acc[8];
  #pragma unroll
  for (int nt = 0; nt < 8; ++nt) acc[nt] = (f32x4){0.f, 0.f, 0.f, 0.f};
  const unsigned short* wp = Wpk + (size_t)l * 8;
  #pragma unroll
  for (int kc = 0; kc < 4; ++kc) {
    bf16x8 bf[8];
    #pragma unroll
    for (int nt = 0; nt < 8; ++nt)
      bf[nt] = *(const bf16x8*)(wp + (size_t)(nt * 4 + kc) * 512);
    #pragma unroll
    for (int nt = 0; nt < 8; ++nt)
      acc[nt] = __builtin_amdgcn_mfma_f32_16x16x32_bf16(af[kc], bf[nt], acc[nt], 0, 0, 0);
  }
  int colb = l & 15, rb = kg * 4;
  #pragma unroll
  for (int nt = 0; nt < 8; ++nt) {
    int c = nt * 16 + colb;
    float S = bnS[c], T = bnT[c];
    #pragma unroll
    for (int j = 0; j < 4; ++j) {
      float v = fmaf(acc[nt][j], S, T);
      v = relu ? fmaxf(v, 0.f) : (v > 0.f ? v : expf(v) - 1.f);
      tile[wid][rb + j][c] = f2bf(v);
    }
  }
  __syncthreads();
  #pragma unroll
  for (int i = 0; i < 4; ++i) {
    int m = i * 64 + l;
    int row = m >> 4, chunk = m & 15;
    uint4 v = *(const uint4*)&tile[wid][row][chunk * 8];
    *(uint4*)&hB[(row0w + row) * 128 + chunk * 8] = v;
  }
}

// layer 0: A = s0b (n_pad x 64 bf16, col5 zeroed), + exact fp32 sid/attn features
__global__ __launch_bounds__(256)
void gcn_mm0_mfma(const unsigned short* __restrict__ A, const float* __restrict__ s0x,
                  const unsigned short* __restrict__ Wpk0, const float* __restrict__ cw0,
                  const float* __restrict__ bnS, const float* __restrict__ bnT,
                  unsigned short* __restrict__ hB) {
  __shared__ unsigned short tile[4][16][136];
  int t = threadIdx.x;
  int wid = t >> 6, l = t & 63;
  int rowA = l & 15, kg = l >> 4;
  size_t row0w = (size_t)blockIdx.x * 64 + wid * 16;
  const unsigned short* Ar = A + (row0w + rowA) * 64 + kg * 8;
  bf16x8 af[2];
  #pragma unroll
  for (int kc = 0; kc < 2; ++kc) af[kc] = *(const bf16x8*)(Ar + kc * 32);
  f32x4 acc[8];
  #pragma unroll
  for (int nt = 0; nt < 8; ++nt) acc[nt] = (f32x4){0.f, 0.f, 0.f, 0.f};
  const unsigned short* wp = Wpk0 + (size_t)l * 8;
  #pragma unroll
  for (int kc = 0; kc < 2; ++kc) {
    bf16x8 bf[8];
    #pragma unroll
    for (int nt = 0; nt < 8; ++nt)
      bf[nt] = *(const bf16x8*)(wp + (size_t)(nt * 2 + kc) * 512);
    #pragma unroll
    for (int nt = 0; nt < 8; ++nt)
      acc[nt] = __builtin_amdgcn_mfma_f32_16x16x32_bf16(af[kc], bf[nt], acc[nt], 0, 0, 0);
  }
  int colb = l & 15, rb = kg * 4;
  float2 ax[4];
  #pragma unroll
  for (int j = 0; j < 4; ++j) ax[j] = *(const float2*)&s0x[(row0w + rb + j) * 2];
  #pragma unroll
  for (int nt = 0; nt < 8; ++nt) {
    int c = nt * 16 + colb;
    float w5 = cw0[5 * 128 + c], w64 = cw0[64 * 128 + c];
    float S = bnS[c], T = bnT[c];
    #pragma unroll
    for (int j = 0; j < 4; ++j) {
      float z = acc[nt][j] + ax[j].x * w5 + ax[j].y * w64;
      float v = fmaf(z, S, T);
      v = v > 0.f ? v : expf(v) - 1.f;   // ELU
      tile[wid][rb + j][c] = f2bf(v);
    }
  }
  __syncthreads();
  #pragma unroll
  for (int i = 0; i < 4; ++i) {
    int m = i * 64 + l;
    int row = m >> 4, chunk = m & 15;
    uint4 v = *(const uint4*)&tile[wid][row][chunk * 8];
    *(uint4*)&hB[(row0w + row) * 128 + chunk * 8] = v;
  }
}

// ---------- pooling + head ----------

__global__ void gcn_pool2(const unsigned short* __restrict__ hB, const int* __restrict__ gstart,
                          float* __restrict__ pooled, int G) {
  int g = blockIdx.x * 4 + (threadIdx.x >> 6);
  int lane = threadIdx.x & 63;
  if (g >= G) return;
  int s = gstart[g], epos = gstart[g + 1];
  const unsigned int* h32 = (const unsigned int*)hB;
  float ax = 0.f, ay = 0.f;
  for (int i = s; i < epos; ++i) {
    unsigned int u = h32[(size_t)i * 64 + lane];
    ax += bflo(u);
    ay += bfhi(u);
  }
  float r = 1.0f / fmaxf((float)(epos - s), 1.0f);
  ((float2*)pooled)[(size_t)g * 64 + lane] = make_float2(ax * r, ay * r);
}

__global__ void gcn_head(const float* __restrict__ pooled,
                         const float* __restrict__ hw1, const float* __restrict__ hb1,
                         const float* __restrict__ hw2, const float* __restrict__ hb2,
                         float* __restrict__ out, int g) {
  int gi = blockIdx.x * 4 + (threadIdx.x >> 6);
  int j = threadIdx.x & 63;
  if (gi >= g) return;
  const float* p = pooled + (size_t)gi * 128;
  float acc = hb1[j];
  #pragma unroll 8
  for (int k = 0; k < 128; ++k) acc = fmaf(p[k], hw1[k * 64 + j], acc);
  float t = acc > 0.f ? acc : expf(acc) - 1.f;   // ELU
  t *= hw2[j];
  #pragma unroll
  for (int off = 32; off; off >>= 1) t += __shfl_down(t, off, 64);
  if (j == 0) out[gi] = t + hb2[0];
}

// ---------- launch ----------

extern "C" void kernel_launch(void* const* d_in, const int* in_sizes, int n_in,
                              void* d_out, int out_size, void* d_ws, size_t ws_size,
                              hipStream_t stream) {
  const float* x   = (const float*)d_in[0];
  const int*   ei  = (const int*)d_in[1];
  const int*   batch = (const int*)d_in[2];
  const float* w1  = (const float*)d_in[3];
  const float* b1  = (const float*)d_in[4];
  const float* w2  = (const float*)d_in[5];
  const float* cw0 = (const float*)d_in[6];
  const float* cb0 = (const float*)d_in[7];
  const float* cwr = (const float*)d_in[8];
  const float* cbr = (const float*)d_in[9];
  const float* bng = (const float*)d_in[10];
  const float* bnb = (const float*)d_in[11];
  const float* bnm = (const float*)d_in[12];
  const float* bnv = (const float*)d_in[13];
  const float* hw1 = (const float*)d_in[14];
  const float* hb1 = (const float*)d_in[15];
  const float* hw2 = (const float*)d_in[16];
  const float* hb2 = (const float*)d_in[17];
  float* out = (float*)d_out;
  (void)n_in; (void)ws_size;

  const int n = in_sizes[0] / 64;
  const int e = in_sizes[1] / 2;
  const int G = out_size;
  const int* row = ei;
  const int* col = ei + e;
  const int nb128 = (n + 127) / 128;
  const int n_pad = nb128 * 128;

  char* p = (char*)d_ws;
  auto take = [&](size_t bytes) { char* r = p; p += (bytes + 255) & ~(size_t)255; return r; };
  float* cnt    = (float*)take((size_t)SS * 4);
  float* sums   = (float*)take((size_t)SS * 64 * 4);
  float* attn   = (float*)take((size_t)SS * 4);
  float* dinv   = (float*)take((size_t)n * 4);
  int*   rowst  = (int*)take(((size_t)n + 1) * 4);
  int*   fill   = (int*)take((size_t)n * 4);
  int*   pos    = (int*)take((size_t)e * 4);
  int*   bsum   = (int*)take(128 * 4);
  int*   gstart = (int*)take(((size_t)G + 1) * 4);
  int2*  sedge  = (int2*)take((size_t)e * 8);
  float* pooled = (float*)take((size_t)G * HH * 4);
  float2* np    = (float2*)take((size_t)n * 8);
  unsigned int* xh = (unsigned int*)take((size_t)n * 32 * 4);
  unsigned int* s0b = (unsigned int*)take((size_t)n_pad * 32 * 4);   // n_pad x 64 bf16
  float* s0x    = (float*)take((size_t)n_pad * 2 * 4);
  unsigned int* sBb = (unsigned int*)take((size_t)n_pad * 64 * 4);   // n_pad x 128 bf16
  unsigned short* hB = (unsigned short*)take((size_t)n_pad * HH * 2);
  unsigned short* wpk0 = (unsigned short*)take((size_t)8 * 2 * 64 * 8 * 2);
  unsigned short* wpkr = (unsigned short*)take((size_t)3 * 8 * 4 * 64 * 8 * 2);
  float* bnS    = (float*)take(4 * 128 * 4);
  float* bnT    = (float*)take(4 * 128 * 4);

  hipMemsetAsync(cnt, 0, (size_t)SS * 4, stream);
  hipMemsetAsync(sums, 0, (size_t)SS * 64 * 4, stream);
  hipMemsetAsync(fill, 0, (size_t)n * 4, stream);

  // FRONT1: pos atomics overlapped with all independent prep
  int nbPos = (e + 255) / 256;
  int nbSub = (n + 3) / 4;
  int nbXb  = (n * 32 + 255) / 256;
  int nbGb  = (G + 1 + 255) / 256;
  int nbW0 = 4, nbWr = 8, nbBnp = 2;
  int front1 = nbPos + nbSub + nbXb + nbGb + nbW0 + 3 * nbWr + nbBnp;
  gcn_front1<<<front1, 256, 0, stream>>>(col, fill, pos, x, cnt, sums, xh, batch, gstart,
      cw0, cwr, wpk0, wpkr, cb0, cbr, bng, bnb, bnm, bnv, bnS, bnT,
      n, e, G, nbPos, nbSub, nbXb, nbGb, nbW0, nbWr);

  gcn_scores<<<SS / 4, 256, 0, stream>>>(sums, cnt, w1, b1, w2, attn);
  gcn_softmax<<<1, 1024, 0, stream>>>(attn);

  int nb = (n + 1023) / 1024;
  gcn_scan1<<<nb, 1024, 0, stream>>>(fill, rowst, bsum, dinv, n);
  gcn_scan2<<<1, 128, 0, stream>>>(bsum, nb);
  gcn_scan3<<<nb, 1024, 0, stream>>>(rowst, bsum, n, e);

  int nbNp = (n + 255) / 256, nbSc = (e + 255) / 256;
  gcn_front3<<<nbNp + nbSc, 256, 0, stream>>>(x, attn, np, row, col, pos, rowst, dinv,
      sedge, n, e, nbNp);

  int nbAx = (n + 3) / 4, nbAnp = (n + 255) / 256;
  gcn_front4<<<nbAx + nbAnp, 256, 0, stream>>>(xh, np, sedge, rowst, dinv, s0b, s0x, n, nbAx);
  gcn_mm0_mfma<<<n_pad / 64, 256, 0, stream>>>((const unsigned short*)s0b, s0x, wpk0, cw0,
      bnS, bnT, hB);

  for (int l = 0; l < 3; ++l) {
    gcn_aggB<<<(n + 3) / 4, 256, 0, stream>>>(hB, sedge, rowst, dinv, sBb, n);
    gcn_mm_mfma<<<n_pad / 64, 256, 0, stream>>>((const unsigned short*)sBb,
        wpkr + (size_t)l * 8 * 4 * 64 * 8, bnS + (l + 1) * 128, bnT + (l + 1) * 128,
        hB, l == 2 ? 1 : 0);
  }

  gcn_pool2<<<(G + 3) / 4, 256, 0, stream>>>(hB, gstart, pooled, G);
  gcn_head<<<(G + 3) / 4, 256, 0, stream>>>(pooled, hw1, hb1, hw2, hb2, out, G);
}

// Round 9
// 625.397 us; speedup vs baseline: 3.1038x; 1.0147x over previous
//
#include <hip/hip_runtime.h>
#include <math.h>

static constexpr int SS = 4096;   // substructures
static constexpr int HH = 128;    // hidden
static constexpr float EPS_BN = 1e-5f;

typedef __attribute__((ext_vector_type(8))) short bf16x8;
typedef __attribute__((ext_vector_type(4))) float f32x4;

__device__ inline unsigned short f2bf(float f) {       // RNE fp32 -> bf16
  unsigned int u = __float_as_uint(f);
  return (unsigned short)((u + 0x7fffu + ((u >> 16) & 1u)) >> 16);
}
__device__ inline float bflo(unsigned int u) { return __uint_as_float(u << 16); }
__device__ inline float bfhi(unsigned int u) { return __uint_as_float(u & 0xffff0000u); }

// ---------- FRONT1: pos-atomics || subst-accum || xb || gb || wpack x4 || bnp ----------

__device__ void wpack_body(const float* __restrict__ W, unsigned short* __restrict__ out,
                           int nkc, int idx) {
  if (idx >= 8 * nkc * 64) return;
  int lane = idx & 63;
  int kc = (idx >> 6) % nkc;
  int nt = idx / (64 * nkc);
  int colc = nt * 16 + (lane & 15);
  int k0 = kc * 32 + (lane >> 4) * 8;
  unsigned int w[4];
  #pragma unroll
  for (int i = 0; i < 4; ++i) {
    unsigned short a = f2bf(W[(size_t)(k0 + 2 * i) * 128 + colc]);
    unsigned short b = f2bf(W[(size_t)(k0 + 2 * i + 1) * 128 + colc]);
    w[i] = (unsigned int)a | ((unsigned int)b << 16);
  }
  *(uint4*)&out[(size_t)idx * 8] = make_uint4(w[0], w[1], w[2], w[3]);
}

__global__ __launch_bounds__(256)
void gcn_front1(const int* __restrict__ col, int* __restrict__ fill, int* __restrict__ pos,
                const float* __restrict__ x, float* __restrict__ cnt, float* __restrict__ sums,
                unsigned int* __restrict__ xh, const int* __restrict__ batch,
                int* __restrict__ gstart,
                const float* __restrict__ cw0, const float* __restrict__ cwr,
                unsigned short* __restrict__ wpk0, unsigned short* __restrict__ wpkr,
                const float* __restrict__ cb0, const float* __restrict__ cbr,
                const float* __restrict__ bng, const float* __restrict__ bnb,
                const float* __restrict__ bnm, const float* __restrict__ bnv,
                float* __restrict__ bnS, float* __restrict__ bnT,
                int n, int e, int G,
                int nbPos, int nbSub, int nbXb, int nbGb, int nbW0, int nbWr) {
  int b = blockIdx.x;
  int t = threadIdx.x;
  if (b < nbPos) {                       // one atomic pass: slot + degree
    int i = b * 256 + t;
    if (i < e) pos[i] = atomicAdd(&fill[col[i]], 1);
    return;
  }
  b -= nbPos;
  if (b < nbSub) {                       // substructure sums (coalesced atomics)
    int node = b * 4 + (t >> 6);
    int lane = t & 63;
    if (node >= n) return;
    const float* xr = x + (size_t)node * 64;
    float v = xr[lane];
    int sid = (int)__shfl(v, 5, 64);
    if (lane == 0) atomicAdd(&cnt[sid], 1.0f);
    atomicAdd(&sums[(size_t)sid * 64 + lane], v);
    return;
  }
  b -= nbSub;
  if (b < nbXb) {                        // bf16 x with col5 zeroed
    int i = b * 256 + t;
    if (i >= n * 32) return;
    int pr = i & 31;
    float2 v = *(const float2*)&x[(size_t)(i >> 5) * 64 + pr * 2];
    if (pr == 2) v.y = 0.f;
    xh[i] = (unsigned int)f2bf(v.x) | ((unsigned int)f2bf(v.y) << 16);
    return;
  }
  b -= nbXb;
  if (b < nbGb) {                        // graph starts (batch sorted)
    int g = b * 256 + t;
    if (g > G) return;
    if (g == G) { gstart[G] = n; return; }
    int lo = 0, hi = n;
    while (lo < hi) { int mid = (lo + hi) >> 1; if (batch[mid] < g) lo = mid + 1; else hi = mid; }
    gstart[g] = lo;
    return;
  }
  b -= nbGb;
  if (b < nbW0) { wpack_body(cw0, wpk0, 2, b * 256 + t); return; }
  b -= nbW0;
  if (b < 3 * nbWr) {
    int l = b / nbWr, bb = b % nbWr;
    wpack_body(cwr + (size_t)l * HH * HH, wpkr + (size_t)l * 8 * 4 * 64 * 8, 4, bb * 256 + t);
    return;
  }
  b -= 3 * nbWr;
  {                                      // fold BN
    int i = b * 256 + t;
    if (i >= 512) return;
    int l = i >> 7, c = i & 127;
    float S = rsqrtf(bnv[i] + EPS_BN) * bng[i];
    float bias = (l == 0) ? cb0[c] : cbr[(l - 1) * 128 + c];
    bnS[i] = S;
    bnT[i] = fmaf(bias - bnm[i], S, bnb[i]);
  }
}

// ---------- substructure attention (scores + softmax) ----------

__global__ void gcn_scores(const float* __restrict__ sums, const float* __restrict__ cnt,
                           const float* __restrict__ w1, const float* __restrict__ b1,
                           const float* __restrict__ w2, float* __restrict__ scores) {
  int s = blockIdx.x * 4 + (threadIdx.x >> 6);
  int j = threadIdx.x & 63;
  float r = 1.0f / fmaxf(cnt[s], 1.0f);
  const float* ss = sums + (size_t)s * 64;
  float acc = b1[j];
  #pragma unroll 8
  for (int d = 0; d < 64; ++d) acc = fmaf(ss[d] * r, w1[d * 64 + j], acc);
  float t = tanhf(acc) * w2[j];
  #pragma unroll
  for (int off = 32; off; off >>= 1) t += __shfl_down(t, off, 64);
  if (j == 0) scores[s] = t;
}

__global__ void gcn_softmax(float* __restrict__ sc) {
  int t = threadIdx.x;
  int wid = t >> 6;
  float v[4]; float m = -INFINITY;
  for (int i = 0; i < 4; ++i) { v[i] = sc[t + i * 1024]; m = fmaxf(m, v[i]); }
  for (int off = 32; off; off >>= 1) m = fmaxf(m, __shfl_xor(m, off, 64));
  __shared__ float wmax[16];
  if ((t & 63) == 0) wmax[wid] = m;
  __syncthreads();
  if (t == 0) { float mm = wmax[0]; for (int i = 1; i < 16; ++i) mm = fmaxf(mm, wmax[i]); wmax[0] = mm; }
  __syncthreads();
  float M = wmax[0];
  float s = 0.f;
  for (int i = 0; i < 4; ++i) { v[i] = expf(v[i] - M); s += v[i]; }
  for (int off = 32; off; off >>= 1) s += __shfl_xor(s, off, 64);
  __shared__ float wsum[16];
  if ((t & 63) == 0) wsum[wid] = s;
  __syncthreads();
  if (t == 0) { float ts = 0.f; for (int i = 0; i < 16; ++i) ts += wsum[i]; wsum[0] = ts; }
  __syncthreads();
  float inv = 1.0f / wsum[0];
  for (int i = 0; i < 4; ++i) sc[t + i * 1024] = v[i] * inv;
}

// ---------- scan (dinv fused into pass 1) ----------

__global__ void gcn_scan1(const int* __restrict__ fill, int* __restrict__ rowstart,
                          int* __restrict__ bsum, float* __restrict__ dinv, int n) {
  __shared__ int tmp[1024];
  int t = threadIdx.x; int g = blockIdx.x * 1024 + t;
  int v = (g < n) ? fill[g] : 0;
  if (g < n) dinv[g] = rsqrtf((float)v + 1.0f);   // +1 = self loop
  tmp[t] = v; __syncthreads();
  for (int off = 1; off < 1024; off <<= 1) {
    int a = (t >= off) ? tmp[t - off] : 0; __syncthreads();
    tmp[t] += a; __syncthreads();
  }
  if (g < n) rowstart[g] = tmp[t] - v;
  if (t == 1023) bsum[blockIdx.x] = tmp[t];
}

__global__ void gcn_scan2(int* __restrict__ bsum, int nb) {
  __shared__ int tmp[128];
  int t = threadIdx.x;
  int v = (t < nb) ? bsum[t] : 0;
  tmp[t] = v; __syncthreads();
  for (int off = 1; off < 128; off <<= 1) {
    int a = (t >= off) ? tmp[t - off] : 0; __syncthreads();
    tmp[t] += a; __syncthreads();
  }
  if (t < nb) bsum[t] = tmp[t] - v;
}

__global__ void gcn_scan3(int* __restrict__ rowstart, const int* __restrict__ bsum, int n, int e) {
  int g = blockIdx.x * 1024 + threadIdx.x;
  if (g < n) rowstart[g] += bsum[blockIdx.x];
  if (g == 0) rowstart[n] = e;
}

// ---------- FRONT3: np table || atomic-free scatter ----------

__global__ __launch_bounds__(256)
void gcn_front3(const float* __restrict__ x, const float* __restrict__ attn,
                float2* __restrict__ np,
                const int* __restrict__ row, const int* __restrict__ col,
                const int* __restrict__ pos, const int* __restrict__ rowstart,
                const float* __restrict__ dinv, int2* __restrict__ sedge,
                int n, int e, int nbNp) {
  int b = blockIdx.x;
  int t = threadIdx.x;
  if (b < nbNp) {
    int i = b * 256 + t;
    if (i >= n) return;
    int sid = (int)x[(size_t)i * 64 + 5];
    np[i] = make_float2((float)sid, attn[sid]);
    return;
  }
  b -= nbNp;
  int i = b * 256 + t;
  if (i >= e) return;
  int c = col[i], r = row[i];
  sedge[rowstart[c] + pos[i]] = make_int2(r, __float_as_int(dinv[r] * dinv[c]));
}

// ---------- fused layer 1-3: CSR gather (into A fragments) + MFMA + BN + act ----------
// 64 rows/block, 4 waves x 16 rows. Lane l: node = base + (l&15), feature chunk
// kg = l>>4 (8 feats per kc). Per-kc gather loads are line-coalesced (16 nodes x
// 4 quarters of a 64B line). Gather accumulates fp32, rounds to bf16 A-frag,
// then 8 MFMA tiles; B prepacked, L1/L2-resident.

__global__ __launch_bounds__(256)
void gcn_layer_f(const unsigned short* __restrict__ hIn, const int2* __restrict__ sedge,
                 const int* __restrict__ rowstart, const float* __restrict__ dinv,
                 const unsigned short* __restrict__ Wpk,
                 const float* __restrict__ bnS, const float* __restrict__ bnT,
                 unsigned short* __restrict__ hOut, int relu, int n) {
  __shared__ unsigned short tile[4][16][136];
  int t = threadIdx.x;
  int wid = t >> 6, l = t & 63;
  int r = l & 15, kg = l >> 4;
  size_t row0w = (size_t)blockIdx.x * 64 + wid * 16;
  int noderaw = (int)row0w + r;
  bool valid = noderaw < n;
  int node = valid ? noderaw : n - 1;
  float di = dinv[node], d2 = di * di;
  const uint4* h4 = (const uint4*)hIn;
  float a[4][8];
  #pragma unroll
  for (int kc = 0; kc < 4; ++kc) {
    uint4 u = h4[(size_t)node * 16 + kc * 4 + kg];
    a[kc][0] = bflo(u.x) * d2; a[kc][1] = bfhi(u.x) * d2;
    a[kc][2] = bflo(u.y) * d2; a[kc][3] = bfhi(u.y) * d2;
    a[kc][4] = bflo(u.z) * d2; a[kc][5] = bfhi(u.z) * d2;
    a[kc][6] = bflo(u.w) * d2; a[kc][7] = bfhi(u.w) * d2;
  }
  int s_ = valid ? rowstart[node] : 0;
  int e_ = valid ? rowstart[node + 1] : 0;
  int2 se = (s_ < e_) ? sedge[s_] : make_int2(0, 0);
  for (int j = s_; j < e_; ++j) {
    int2 cur = se;
    if (j + 1 < e_) se = sedge[j + 1];
    float w = __int_as_float(cur.y);
    #pragma unroll
    for (int kc = 0; kc < 4; ++kc) {
      uint4 u = h4[(size_t)cur.x * 16 + kc * 4 + kg];
      a[kc][0] = fmaf(bflo(u.x), w, a[kc][0]); a[kc][1] = fmaf(bfhi(u.x), w, a[kc][1]);
      a[kc][2] = fmaf(bflo(u.y), w, a[kc][2]); a[kc][3] = fmaf(bfhi(u.y), w, a[kc][3]);
      a[kc][4] = fmaf(bflo(u.z), w, a[kc][4]); a[kc][5] = fmaf(bfhi(u.z), w, a[kc][5]);
      a[kc][6] = fmaf(bflo(u.w), w, a[kc][6]); a[kc][7] = fmaf(bfhi(u.w), w, a[kc][7]);
    }
  }
  bf16x8 af[4];
  #pragma unroll
  for (int kc = 0; kc < 4; ++kc) {
    uint4 pk;
    pk.x = (unsigned)f2bf(a[kc][0]) | ((unsigned)f2bf(a[kc][1]) << 16);
    pk.y = (unsigned)f2bf(a[kc][2]) | ((unsigned)f2bf(a[kc][3]) << 16);
    pk.z = (unsigned)f2bf(a[kc][4]) | ((unsigned)f2bf(a[kc][5]) << 16);
    pk.w = (unsigned)f2bf(a[kc][6]) | ((unsigned)f2bf(a[kc][7]) << 16);
    af[kc] = *(bf16x8*)&pk;
  }
  f32x4 acc[8];
  #pragma unroll
  for (int nt = 0; nt < 8; ++nt) acc[nt] = (f32x4){0.f, 0.f, 0.f, 0.f};
  const unsigned short* wp = Wpk + (size_t)l * 8;
  #pragma unroll
  for (int kc = 0; kc < 4; ++kc) {
    bf16x8 bf[8];
    #pragma unroll
    for (int nt = 0; nt < 8; ++nt)
      bf[nt] = *(const bf16x8*)(wp + (size_t)(nt * 4 + kc) * 512);
    #pragma unroll
    for (int nt = 0; nt < 8; ++nt)
      acc[nt] = __builtin_amdgcn_mfma_f32_16x16x32_bf16(af[kc], bf[nt], acc[nt], 0, 0, 0);
  }
  int colb = l & 15, rb = kg * 4;
  #pragma unroll
  for (int nt = 0; nt < 8; ++nt) {
    int c = nt * 16 + colb;
    float S = bnS[c], T = bnT[c];
    #pragma unroll
    for (int j = 0; j < 4; ++j) {
      float v = fmaf(acc[nt][j], S, T);
      v = relu ? fmaxf(v, 0.f) : (v > 0.f ? v : expf(v) - 1.f);
      tile[wid][rb + j][c] = f2bf(v);
    }
  }
  __syncthreads();
  #pragma unroll
  for (int i = 0; i < 4; ++i) {
    int m = i * 64 + l;
    int rr = m >> 4, chunk = m & 15;
    uint4 v = *(const uint4*)&tile[wid][rr][chunk * 8];
    *(uint4*)&hOut[(row0w + rr) * 128 + chunk * 8] = v;
  }
}

// ---------- fused layer 0: gather x(bf16,col5=0)+np + MFMA(K=64) + exact feats + BN + ELU ----------

__global__ __launch_bounds__(256)
void gcn_layer0_f(const unsigned int* __restrict__ xh, const float2* __restrict__ np,
                  const int2* __restrict__ sedge, const int* __restrict__ rowstart,
                  const float* __restrict__ dinv, const unsigned short* __restrict__ Wpk0,
                  const float* __restrict__ cw0,
                  const float* __restrict__ bnS, const float* __restrict__ bnT,
                  unsigned short* __restrict__ hOut, int n) {
  __shared__ unsigned short tile[4][16][136];
  int t = threadIdx.x;
  int wid = t >> 6, l = t & 63;
  int r = l & 15, kg = l >> 4;
  size_t row0w = (size_t)blockIdx.x * 64 + wid * 16;
  int noderaw = (int)row0w + r;
  bool valid = noderaw < n;
  int node = valid ? noderaw : n - 1;
  float di = dinv[node], d2 = di * di;
  const uint4* x4 = (const uint4*)xh;
  float a[2][8];
  #pragma unroll
  for (int kc = 0; kc < 2; ++kc) {
    uint4 u = x4[(size_t)node * 8 + kc * 4 + kg];
    a[kc][0] = bflo(u.x) * d2; a[kc][1] = bfhi(u.x) * d2;
    a[kc][2] = bflo(u.y) * d2; a[kc][3] = bfhi(u.y) * d2;
    a[kc][4] = bflo(u.z) * d2; a[kc][5] = bfhi(u.z) * d2;
    a[kc][6] = bflo(u.w) * d2; a[kc][7] = bfhi(u.w) * d2;
  }
  float a5 = 0.f, a64 = 0.f;
  if (kg == 0) { float2 v = np[node]; a5 = d2 * v.x; a64 = d2 * v.y; }
  int s_ = valid ? rowstart[node] : 0;
  int e_ = valid ? rowstart[node + 1] : 0;
  int2 se = (s_ < e_) ? sedge[s_] : make_int2(0, 0);
  for (int j = s_; j < e_; ++j) {
    int2 cur = se;
    if (j + 1 < e_) se = sedge[j + 1];
    float w = __int_as_float(cur.y);
    #pragma unroll
    for (int kc = 0; kc < 2; ++kc) {
      uint4 u = x4[(size_t)cur.x * 8 + kc * 4 + kg];
      a[kc][0] = fmaf(bflo(u.x), w, a[kc][0]); a[kc][1] = fmaf(bfhi(u.x), w, a[kc][1]);
      a[kc][2] = fmaf(bflo(u.y), w, a[kc][2]); a[kc][3] = fmaf(bfhi(u.y), w, a[kc][3]);
      a[kc][4] = fmaf(bflo(u.z), w, a[kc][4]); a[kc][5] = fmaf(bfhi(u.z), w, a[kc][5]);
      a[kc][6] = fmaf(bflo(u.w), w, a[kc][6]); a[kc][7] = fmaf(bfhi(u.w), w, a[kc][7]);
    }
    if (kg == 0) {
      float2 v = np[cur.x];
      a5 = fmaf(v.x, w, a5);
      a64 = fmaf(v.y, w, a64);
    }
  }
  bf16x8 af[2];
  #pragma unroll
  for (int kc = 0; kc < 2; ++kc) {
    uint4 pk;
    pk.x = (unsigned)f2bf(a[kc][0]) | ((unsigned)f2bf(a[kc][1]) << 16);
    pk.y = (unsigned)f2bf(a[kc][2]) | ((unsigned)f2bf(a[kc][3]) << 16);
    pk.z = (unsigned)f2bf(a[kc][4]) | ((unsigned)f2bf(a[kc][5]) << 16);
    pk.w = (unsigned)f2bf(a[kc][6]) | ((unsigned)f2bf(a[kc][7]) << 16);
    af[kc] = *(bf16x8*)&pk;
  }
  f32x4 acc[8];
  #pragma unroll
  for (int nt = 0; nt < 8; ++nt) acc[nt] = (f32x4){0.f, 0.f, 0.f, 0.f};
  const unsigned short* wp = Wpk0 + (size_t)l * 8;
  #pragma unroll
  for (int kc = 0; kc < 2; ++kc) {
    bf16x8 bf[8];
    #pragma unroll
    for (int nt = 0; nt < 8; ++nt)
      bf[nt] = *(const bf16x8*)(wp + (size_t)(nt * 2 + kc) * 512);
    #pragma unroll
    for (int nt = 0; nt < 8; ++nt)
      acc[nt] = __builtin_amdgcn_mfma_f32_16x16x32_bf16(af[kc], bf[nt], acc[nt], 0, 0, 0);
  }
  int colb = l & 15, rb = kg * 4;
  float2 ax[4];
  #pragma unroll
  for (int j = 0; j < 4; ++j) {
    ax[j].x = __shfl(a5, rb + j, 64);    // exact fp32 sid aggregate of row rb+j
    ax[j].y = __shfl(a64, rb + j, 64);   // exact fp32 attn aggregate
  }
  #pragma unroll
  for (int nt = 0; nt < 8; ++nt) {
    int c = nt * 16 + colb;
    float w5 = cw0[5 * 128 + c], w64 = cw0[64 * 128 + c];
    float S = bnS[c], T = bnT[c];
    #pragma unroll
    for (int j = 0; j < 4; ++j) {
      float z = acc[nt][j] + ax[j].x * w5 + ax[j].y * w64;
      float v = fmaf(z, S, T);
      v = v > 0.f ? v : expf(v) - 1.f;   // ELU
      tile[wid][rb + j][c] = f2bf(v);
    }
  }
  __syncthreads();
  #pragma unroll
  for (int i = 0; i < 4; ++i) {
    int m = i * 64 + l;
    int rr = m >> 4, chunk = m & 15;
    uint4 v = *(const uint4*)&tile[wid][rr][chunk * 8];
    *(uint4*)&hOut[(row0w + rr) * 128 + chunk * 8] = v;
  }
}

// ---------- pooling + head ----------

__global__ void gcn_pool2(const unsigned short* __restrict__ hB, const int* __restrict__ gstart,
                          float* __restrict__ pooled, int G) {
  int g = blockIdx.x * 4 + (threadIdx.x >> 6);
  int lane = threadIdx.x & 63;
  if (g >= G) return;
  int s = gstart[g], epos = gstart[g + 1];
  const unsigned int* h32 = (const unsigned int*)hB;
  float ax = 0.f, ay = 0.f;
  for (int i = s; i < epos; ++i) {
    unsigned int u = h32[(size_t)i * 64 + lane];
    ax += bflo(u);
    ay += bfhi(u);
  }
  float r = 1.0f / fmaxf((float)(epos - s), 1.0f);
  ((float2*)pooled)[(size_t)g * 64 + lane] = make_float2(ax * r, ay * r);
}

__global__ void gcn_head(const float* __restrict__ pooled,
                         const float* __restrict__ hw1, const float* __restrict__ hb1,
                         const float* __restrict__ hw2, const float* __restrict__ hb2,
                         float* __restrict__ out, int g) {
  int gi = blockIdx.x * 4 + (threadIdx.x >> 6);
  int j = threadIdx.x & 63;
  if (gi >= g) return;
  const float* p = pooled + (size_t)gi * 128;
  float acc = hb1[j];
  #pragma unroll 8
  for (int k = 0; k < 128; ++k) acc = fmaf(p[k], hw1[k * 64 + j], acc);
  float t = acc > 0.f ? acc : expf(acc) - 1.f;   // ELU
  t *= hw2[j];
  #pragma unroll
  for (int off = 32; off; off >>= 1) t += __shfl_down(t, off, 64);
  if (j == 0) out[gi] = t + hb2[0];
}

// ---------- launch ----------

extern "C" void kernel_launch(void* const* d_in, const int* in_sizes, int n_in,
                              void* d_out, int out_size, void* d_ws, size_t ws_size,
                              hipStream_t stream) {
  const float* x   = (const float*)d_in[0];
  const int*   ei  = (const int*)d_in[1];
  const int*   batch = (const int*)d_in[2];
  const float* w1  = (const float*)d_in[3];
  const float* b1  = (const float*)d_in[4];
  const float* w2  = (const float*)d_in[5];
  const float* cw0 = (const float*)d_in[6];
  const float* cb0 = (const float*)d_in[7];
  const float* cwr = (const float*)d_in[8];
  const float* cbr = (const float*)d_in[9];
  const float* bng = (const float*)d_in[10];
  const float* bnb = (const float*)d_in[11];
  const float* bnm = (const float*)d_in[12];
  const float* bnv = (const float*)d_in[13];
  const float* hw1 = (const float*)d_in[14];
  const float* hb1 = (const float*)d_in[15];
  const float* hw2 = (const float*)d_in[16];
  const float* hb2 = (const float*)d_in[17];
  float* out = (float*)d_out;
  (void)n_in; (void)ws_size;

  const int n = in_sizes[0] / 64;
  const int e = in_sizes[1] / 2;
  const int G = out_size;
  const int* row = ei;
  const int* col = ei + e;
  const int nb128 = (n + 127) / 128;
  const int n_pad = nb128 * 128;

  char* p = (char*)d_ws;
  auto take = [&](size_t bytes) { char* r = p; p += (bytes + 255) & ~(size_t)255; return r; };
  float* cnt    = (float*)take((size_t)SS * 4);
  float* sums   = (float*)take((size_t)SS * 64 * 4);
  float* attn   = (float*)take((size_t)SS * 4);
  float* dinv   = (float*)take((size_t)n * 4);
  int*   rowst  = (int*)take(((size_t)n + 1) * 4);
  int*   fill   = (int*)take((size_t)n * 4);
  int*   pos    = (int*)take((size_t)e * 4);
  int*   bsum   = (int*)take(128 * 4);
  int*   gstart = (int*)take(((size_t)G + 1) * 4);
  int2*  sedge  = (int2*)take((size_t)e * 8);
  float* pooled = (float*)take((size_t)G * HH * 4);
  float2* np    = (float2*)take((size_t)n * 8);
  unsigned int* xh = (unsigned int*)take((size_t)n * 32 * 4);
  unsigned short* hP0 = (unsigned short*)take((size_t)n_pad * HH * 2);
  unsigned short* hP1 = (unsigned short*)take((size_t)n_pad * HH * 2);
  unsigned short* wpk0 = (unsigned short*)take((size_t)8 * 2 * 64 * 8 * 2);
  unsigned short* wpkr = (unsigned short*)take((size_t)3 * 8 * 4 * 64 * 8 * 2);
  float* bnS    = (float*)take(4 * 128 * 4);
  float* bnT    = (float*)take(4 * 128 * 4);

  hipMemsetAsync(cnt, 0, (size_t)SS * 4, stream);
  hipMemsetAsync(sums, 0, (size_t)SS * 64 * 4, stream);
  hipMemsetAsync(fill, 0, (size_t)n * 4, stream);

  // FRONT1: pos atomics overlapped with all independent prep
  int nbPos = (e + 255) / 256;
  int nbSub = (n + 3) / 4;
  int nbXb  = (n * 32 + 255) / 256;
  int nbGb  = (G + 1 + 255) / 256;
  int nbW0 = 4, nbWr = 8, nbBnp = 2;
  int front1 = nbPos + nbSub + nbXb + nbGb + nbW0 + 3 * nbWr + nbBnp;
  gcn_front1<<<front1, 256, 0, stream>>>(col, fill, pos, x, cnt, sums, xh, batch, gstart,
      cw0, cwr, wpk0, wpkr, cb0, cbr, bng, bnb, bnm, bnv, bnS, bnT,
      n, e, G, nbPos, nbSub, nbXb, nbGb, nbW0, nbWr);

  gcn_scores<<<SS / 4, 256, 0, stream>>>(sums, cnt, w1, b1, w2, attn);
  gcn_softmax<<<1, 1024, 0, stream>>>(attn);

  int nb = (n + 1023) / 1024;
  gcn_scan1<<<nb, 1024, 0, stream>>>(fill, rowst, bsum, dinv, n);
  gcn_scan2<<<1, 128, 0, stream>>>(bsum, nb);
  gcn_scan3<<<nb, 1024, 0, stream>>>(rowst, bsum, n, e);

  int nbNp = (n + 255) / 256, nbSc = (e + 255) / 256;
  gcn_front3<<<nbNp + nbSc, 256, 0, stream>>>(x, attn, np, row, col, pos, rowst, dinv,
      sedge, n, e, nbNp);

  // fused layers (ping-pong hP0/hP1)
  gcn_layer0_f<<<n_pad / 64, 256, 0, stream>>>(xh, np, sedge, rowst, dinv, wpk0, cw0,
      bnS, bnT, hP0, n);
  gcn_layer_f<<<n_pad / 64, 256, 0, stream>>>(hP0, sedge, rowst, dinv, wpkr,
      bnS + 128, bnT + 128, hP1, 0, n);
  gcn_layer_f<<<n_pad / 64, 256, 0, stream>>>(hP1, sedge, rowst, dinv,
      wpkr + (size_t)8 * 4 * 64 * 8, bnS + 256, bnT + 256, hP0, 0, n);
  gcn_layer_f<<<n_pad / 64, 256, 0, stream>>>(hP0, sedge, rowst, dinv,
      wpkr + (size_t)2 * 8 * 4 * 64 * 8, bnS + 384, bnT + 384, hP1, 1, n);

  gcn_pool2<<<(G + 3) / 4, 256, 0, stream>>>(hP1, gstart, pooled, G);
  gcn_head<<<(G + 3) / 4, 256, 0, stream>>>(pooled, hw1, hb1, hw2, hb2, out, G);
}

// Round 10
// 608.948 us; speedup vs baseline: 3.1876x; 1.0270x over previous
//
#include <hip/hip_runtime.h>
#include <math.h>

static constexpr int SS = 4096;   // substructures
static constexpr int HH = 128;    // hidden
static constexpr float EPS_BN = 1e-5f;

typedef __attribute__((ext_vector_type(8))) short bf16x8;
typedef __attribute__((ext_vector_type(4))) float f32x4;

__device__ inline unsigned short f2bf(float f) {       // RNE fp32 -> bf16
  unsigned int u = __float_as_uint(f);
  return (unsigned short)((u + 0x7fffu + ((u >> 16) & 1u)) >> 16);
}
__device__ inline float bflo(unsigned int u) { return __uint_as_float(u << 16); }
__device__ inline float bfhi(unsigned int u) { return __uint_as_float(u & 0xffff0000u); }

// ---------- FRONT1: the two atomic passes only ----------

__global__ __launch_bounds__(256)
void gcn_front1(const int* __restrict__ col, int* __restrict__ fill, int* __restrict__ pos,
                const float* __restrict__ x, float* __restrict__ cnt, float* __restrict__ sums,
                int n, int e, int nbPos) {
  int b = blockIdx.x;
  int t = threadIdx.x;
  if (b < nbPos) {                       // one atomic pass: slot + degree
    int i = b * 256 + t;
    if (i < e) pos[i] = atomicAdd(&fill[col[i]], 1);
    return;
  }
  b -= nbPos;
  {                                      // substructure sums (coalesced atomics)
    int node = b * 4 + (t >> 6);
    int lane = t & 63;
    if (node >= n) return;
    const float* xr = x + (size_t)node * 64;
    float v = xr[lane];
    int sid = (int)__shfl(v, 5, 64);
    if (lane == 0) atomicAdd(&cnt[sid], 1.0f);
    atomicAdd(&sums[(size_t)sid * 64 + lane], v);
  }
}

// ---------- substructure attention (scores + softmax) ----------

__global__ void gcn_scores(const float* __restrict__ sums, const float* __restrict__ cnt,
                           const float* __restrict__ w1, const float* __restrict__ b1,
                           const float* __restrict__ w2, float* __restrict__ scores) {
  int s = blockIdx.x * 4 + (threadIdx.x >> 6);
  int j = threadIdx.x & 63;
  float r = 1.0f / fmaxf(cnt[s], 1.0f);
  const float* ss = sums + (size_t)s * 64;
  float acc = b1[j];
  #pragma unroll 8
  for (int d = 0; d < 64; ++d) acc = fmaf(ss[d] * r, w1[d * 64 + j], acc);
  float t = tanhf(acc) * w2[j];
  #pragma unroll
  for (int off = 32; off; off >>= 1) t += __shfl_down(t, off, 64);
  if (j == 0) scores[s] = t;
}

__global__ void gcn_softmax(float* __restrict__ sc) {
  int t = threadIdx.x;
  int wid = t >> 6;
  float v[4]; float m = -INFINITY;
  for (int i = 0; i < 4; ++i) { v[i] = sc[t + i * 1024]; m = fmaxf(m, v[i]); }
  for (int off = 32; off; off >>= 1) m = fmaxf(m, __shfl_xor(m, off, 64));
  __shared__ float wmax[16];
  if ((t & 63) == 0) wmax[wid] = m;
  __syncthreads();
  if (t == 0) { float mm = wmax[0]; for (int i = 1; i < 16; ++i) mm = fmaxf(mm, wmax[i]); wmax[0] = mm; }
  __syncthreads();
  float M = wmax[0];
  float s = 0.f;
  for (int i = 0; i < 4; ++i) { v[i] = expf(v[i] - M); s += v[i]; }
  for (int off = 32; off; off >>= 1) s += __shfl_xor(s, off, 64);
  __shared__ float wsum[16];
  if ((t & 63) == 0) wsum[wid] = s;
  __syncthreads();
  if (t == 0) { float ts = 0.f; for (int i = 0; i < 16; ++i) ts += wsum[i]; wsum[0] = ts; }
  __syncthreads();
  float inv = 1.0f / wsum[0];
  for (int i = 0; i < 4; ++i) sc[t + i * 1024] = v[i] * inv;
}

// ---------- scan (dinv fused into pass 1) ----------

__global__ void gcn_scan1(const int* __restrict__ fill, int* __restrict__ rowstart,
                          int* __restrict__ bsum, float* __restrict__ dinv, int n) {
  __shared__ int tmp[1024];
  int t = threadIdx.x; int g = blockIdx.x * 1024 + t;
  int v = (g < n) ? fill[g] : 0;
  if (g < n) dinv[g] = rsqrtf((float)v + 1.0f);   // +1 = self loop
  tmp[t] = v; __syncthreads();
  for (int off = 1; off < 1024; off <<= 1) {
    int a = (t >= off) ? tmp[t - off] : 0; __syncthreads();
    tmp[t] += a; __syncthreads();
  }
  if (g < n) rowstart[g] = tmp[t] - v;
  if (t == 1023) bsum[blockIdx.x] = tmp[t];
}

__global__ void gcn_scan2(int* __restrict__ bsum, int nb) {
  __shared__ int tmp[128];
  int t = threadIdx.x;
  int v = (t < nb) ? bsum[t] : 0;
  tmp[t] = v; __syncthreads();
  for (int off = 1; off < 128; off <<= 1) {
    int a = (t >= off) ? tmp[t - off] : 0; __syncthreads();
    tmp[t] += a; __syncthreads();
  }
  if (t < nb) bsum[t] = tmp[t] - v;
}

__global__ void gcn_scan3(int* __restrict__ rowstart, const int* __restrict__ bsum, int n, int e) {
  int g = blockIdx.x * 1024 + threadIdx.x;
  if (g < n) rowstart[g] += bsum[blockIdx.x];
  if (g == 0) rowstart[n] = e;
}

// ---------- FRONT3: scatter || np || xb || gb || wpack x4 || bnp ----------

__device__ void wpack_body(const float* __restrict__ W, unsigned short* __restrict__ out,
                           int nkc, int idx) {
  if (idx >= 8 * nkc * 64) return;
  int lane = idx & 63;
  int kc = (idx >> 6) % nkc;
  int nt = idx / (64 * nkc);
  int colc = nt * 16 + (lane & 15);
  int k0 = kc * 32 + (lane >> 4) * 8;
  unsigned int w[4];
  #pragma unroll
  for (int i = 0; i < 4; ++i) {
    unsigned short a = f2bf(W[(size_t)(k0 + 2 * i) * 128 + colc]);
    unsigned short b = f2bf(W[(size_t)(k0 + 2 * i + 1) * 128 + colc]);
    w[i] = (unsigned int)a | ((unsigned int)b << 16);
  }
  *(uint4*)&out[(size_t)idx * 8] = make_uint4(w[0], w[1], w[2], w[3]);
}

__global__ __launch_bounds__(256)
void gcn_front3(const float* __restrict__ x, const float* __restrict__ attn,
                float2* __restrict__ np,
                const int* __restrict__ row, const int* __restrict__ col,
                const int* __restrict__ pos, const int* __restrict__ rowstart,
                const float* __restrict__ dinv, int2* __restrict__ sedge,
                unsigned int* __restrict__ xh, const int* __restrict__ batch,
                int* __restrict__ gstart,
                const float* __restrict__ cw0, const float* __restrict__ cwr,
                unsigned short* __restrict__ wpk0, unsigned short* __restrict__ wpkr,
                const float* __restrict__ cb0, const float* __restrict__ cbr,
                const float* __restrict__ bng, const float* __restrict__ bnb,
                const float* __restrict__ bnm, const float* __restrict__ bnv,
                float* __restrict__ bnS, float* __restrict__ bnT,
                int n, int e, int G,
                int nbSc, int nbNp, int nbXb, int nbGb, int nbW0, int nbWr) {
  int b = blockIdx.x;
  int t = threadIdx.x;
  if (b < nbSc) {                        // atomic-free CSR scatter
    int i = b * 256 + t;
    if (i >= e) return;
    int c = col[i], r = row[i];
    sedge[rowstart[c] + pos[i]] = make_int2(r, __float_as_int(dinv[r] * dinv[c]));
    return;
  }
  b -= nbSc;
  if (b < nbNp) {                        // per-node {sid, attn}
    int i = b * 256 + t;
    if (i >= n) return;
    int sid = (int)x[(size_t)i * 64 + 5];
    np[i] = make_float2((float)sid, attn[sid]);
    return;
  }
  b -= nbNp;
  if (b < nbXb) {                        // bf16 x with col5 zeroed
    int i = b * 256 + t;
    if (i >= n * 32) return;
    int pr = i & 31;
    float2 v = *(const float2*)&x[(size_t)(i >> 5) * 64 + pr * 2];
    if (pr == 2) v.y = 0.f;
    xh[i] = (unsigned int)f2bf(v.x) | ((unsigned int)f2bf(v.y) << 16);
    return;
  }
  b -= nbXb;
  if (b < nbGb) {                        // graph starts (batch sorted)
    int g = b * 256 + t;
    if (g > G) return;
    if (g == G) { gstart[G] = n; return; }
    int lo = 0, hi = n;
    while (lo < hi) { int mid = (lo + hi) >> 1; if (batch[mid] < g) lo = mid + 1; else hi = mid; }
    gstart[g] = lo;
    return;
  }
  b -= nbGb;
  if (b < nbW0) { wpack_body(cw0, wpk0, 2, b * 256 + t); return; }
  b -= nbW0;
  if (b < 3 * nbWr) {
    int l = b / nbWr, bb = b % nbWr;
    wpack_body(cwr + (size_t)l * HH * HH, wpkr + (size_t)l * 8 * 4 * 64 * 8, 4, bb * 256 + t);
    return;
  }
  b -= 3 * nbWr;
  {                                      // fold BN
    int i = b * 256 + t;
    if (i >= 512) return;
    int l = i >> 7, c = i & 127;
    float S = rsqrtf(bnv[i] + EPS_BN) * bng[i];
    float bias = (l == 0) ? cb0[c] : cbr[(l - 1) * 128 + c];
    bnS[i] = S;
    bnT[i] = fmaf(bias - bnm[i], S, bnb[i]);
  }
}

// ---------- fused layer 1-3: CSR gather (2-edge unrolled) + MFMA + BN + act ----------

__global__ __launch_bounds__(256)
void gcn_layer_f(const unsigned short* __restrict__ hIn, const int2* __restrict__ sedge,
                 const int* __restrict__ rowstart, const float* __restrict__ dinv,
                 const unsigned short* __restrict__ Wpk,
                 const float* __restrict__ bnS, const float* __restrict__ bnT,
                 unsigned short* __restrict__ hOut, int relu, int n) {
  __shared__ unsigned short tile[4][16][136];
  int t = threadIdx.x;
  int wid = t >> 6, l = t & 63;
  int r = l & 15, kg = l >> 4;
  size_t row0w = (size_t)blockIdx.x * 64 + wid * 16;
  int noderaw = (int)row0w + r;
  bool valid = noderaw < n;
  int node = valid ? noderaw : n - 1;
  float di = dinv[node], d2 = di * di;
  const uint4* h4 = (const uint4*)hIn;
  float a[4][8];
  #pragma unroll
  for (int kc = 0; kc < 4; ++kc) {
    uint4 u = h4[(size_t)node * 16 + kc * 4 + kg];
    a[kc][0] = bflo(u.x) * d2; a[kc][1] = bfhi(u.x) * d2;
    a[kc][2] = bflo(u.y) * d2; a[kc][3] = bfhi(u.y) * d2;
    a[kc][4] = bflo(u.z) * d2; a[kc][5] = bfhi(u.z) * d2;
    a[kc][6] = bflo(u.w) * d2; a[kc][7] = bfhi(u.w) * d2;
  }
  int s_ = valid ? rowstart[node] : 0;
  int e_ = valid ? rowstart[node + 1] : 0;
  int j = s_;
  for (; j + 2 <= e_; j += 2) {          // 8 row-loads in flight
    int2 sA = sedge[j], sB = sedge[j + 1];
    float wA = __int_as_float(sA.y), wB = __int_as_float(sB.y);
    uint4 uA[4], uB[4];
    #pragma unroll
    for (int kc = 0; kc < 4; ++kc) uA[kc] = h4[(size_t)sA.x * 16 + kc * 4 + kg];
    #pragma unroll
    for (int kc = 0; kc < 4; ++kc) uB[kc] = h4[(size_t)sB.x * 16 + kc * 4 + kg];
    #pragma unroll
    for (int kc = 0; kc < 4; ++kc) {
      a[kc][0] = fmaf(bflo(uA[kc].x), wA, a[kc][0]); a[kc][1] = fmaf(bfhi(uA[kc].x), wA, a[kc][1]);
      a[kc][2] = fmaf(bflo(uA[kc].y), wA, a[kc][2]); a[kc][3] = fmaf(bfhi(uA[kc].y), wA, a[kc][3]);
      a[kc][4] = fmaf(bflo(uA[kc].z), wA, a[kc][4]); a[kc][5] = fmaf(bfhi(uA[kc].z), wA, a[kc][5]);
      a[kc][6] = fmaf(bflo(uA[kc].w), wA, a[kc][6]); a[kc][7] = fmaf(bfhi(uA[kc].w), wA, a[kc][7]);
    }
    #pragma unroll
    for (int kc = 0; kc < 4; ++kc) {
      a[kc][0] = fmaf(bflo(uB[kc].x), wB, a[kc][0]); a[kc][1] = fmaf(bfhi(uB[kc].x), wB, a[kc][1]);
      a[kc][2] = fmaf(bflo(uB[kc].y), wB, a[kc][2]); a[kc][3] = fmaf(bfhi(uB[kc].y), wB, a[kc][3]);
      a[kc][4] = fmaf(bflo(uB[kc].z), wB, a[kc][4]); a[kc][5] = fmaf(bfhi(uB[kc].z), wB, a[kc][5]);
      a[kc][6] = fmaf(bflo(uB[kc].w), wB, a[kc][6]); a[kc][7] = fmaf(bfhi(uB[kc].w), wB, a[kc][7]);
    }
  }
  if (j < e_) {
    int2 sA = sedge[j];
    float wA = __int_as_float(sA.y);
    #pragma unroll
    for (int kc = 0; kc < 4; ++kc) {
      uint4 u = h4[(size_t)sA.x * 16 + kc * 4 + kg];
      a[kc][0] = fmaf(bflo(u.x), wA, a[kc][0]); a[kc][1] = fmaf(bfhi(u.x), wA, a[kc][1]);
      a[kc][2] = fmaf(bflo(u.y), wA, a[kc][2]); a[kc][3] = fmaf(bfhi(u.y), wA, a[kc][3]);
      a[kc][4] = fmaf(bflo(u.z), wA, a[kc][4]); a[kc][5] = fmaf(bfhi(u.z), wA, a[kc][5]);
      a[kc][6] = fmaf(bflo(u.w), wA, a[kc][6]); a[kc][7] = fmaf(bfhi(u.w), wA, a[kc][7]);
    }
  }
  bf16x8 af[4];
  #pragma unroll
  for (int kc = 0; kc < 4; ++kc) {
    uint4 pk;
    pk.x = (unsigned)f2bf(a[kc][0]) | ((unsigned)f2bf(a[kc][1]) << 16);
    pk.y = (unsigned)f2bf(a[kc][2]) | ((unsigned)f2bf(a[kc][3]) << 16);
    pk.z = (unsigned)f2bf(a[kc][4]) | ((unsigned)f2bf(a[kc][5]) << 16);
    pk.w = (unsigned)f2bf(a[kc][6]) | ((unsigned)f2bf(a[kc][7]) << 16);
    af[kc] = *(bf16x8*)&pk;
  }
  f32x4 acc[8];
  #pragma unroll
  for (int nt = 0; nt < 8; ++nt) acc[nt] = (f32x4){0.f, 0.f, 0.f, 0.f};
  const unsigned short* wp = Wpk + (size_t)l * 8;
  #pragma unroll
  for (int kc = 0; kc < 4; ++kc) {
    bf16x8 bf[8];
    #pragma unroll
    for (int nt = 0; nt < 8; ++nt)
      bf[nt] = *(const bf16x8*)(wp + (size_t)(nt * 4 + kc) * 512);
    #pragma unroll
    for (int nt = 0; nt < 8; ++nt)
      acc[nt] = __builtin_amdgcn_mfma_f32_16x16x32_bf16(af[kc], bf[nt], acc[nt], 0, 0, 0);
  }
  int colb = l & 15, rb = kg * 4;
  #pragma unroll
  for (int nt = 0; nt < 8; ++nt) {
    int c = nt * 16 + colb;
    float S = bnS[c], T = bnT[c];
    #pragma unroll
    for (int jj = 0; jj < 4; ++jj) {
      float v = fmaf(acc[nt][jj], S, T);
      v = relu ? fmaxf(v, 0.f) : (v > 0.f ? v : expf(v) - 1.f);
      tile[wid][rb + jj][c] = f2bf(v);
    }
  }
  __syncthreads();
  #pragma unroll
  for (int i = 0; i < 4; ++i) {
    int m = i * 64 + l;
    int rr = m >> 4, chunk = m & 15;
    uint4 v = *(const uint4*)&tile[wid][rr][chunk * 8];
    *(uint4*)&hOut[(row0w + rr) * 128 + chunk * 8] = v;
  }
}

// ---------- fused layer 0 (K=64 + exact fp32 sid/attn), 2-edge unrolled ----------

__global__ __launch_bounds__(256)
void gcn_layer0_f(const unsigned int* __restrict__ xh, const float2* __restrict__ np,
                  const int2* __restrict__ sedge, const int* __restrict__ rowstart,
                  const float* __restrict__ dinv, const unsigned short* __restrict__ Wpk0,
                  const float* __restrict__ cw0,
                  const float* __restrict__ bnS, const float* __restrict__ bnT,
                  unsigned short* __restrict__ hOut, int n) {
  __shared__ unsigned short tile[4][16][136];
  int t = threadIdx.x;
  int wid = t >> 6, l = t & 63;
  int r = l & 15, kg = l >> 4;
  size_t row0w = (size_t)blockIdx.x * 64 + wid * 16;
  int noderaw = (int)row0w + r;
  bool valid = noderaw < n;
  int node = valid ? noderaw : n - 1;
  float di = dinv[node], d2 = di * di;
  const uint4* x4 = (const uint4*)xh;
  float a[2][8];
  #pragma unroll
  for (int kc = 0; kc < 2; ++kc) {
    uint4 u = x4[(size_t)node * 8 + kc * 4 + kg];
    a[kc][0] = bflo(u.x) * d2; a[kc][1] = bfhi(u.x) * d2;
    a[kc][2] = bflo(u.y) * d2; a[kc][3] = bfhi(u.y) * d2;
    a[kc][4] = bflo(u.z) * d2; a[kc][5] = bfhi(u.z) * d2;
    a[kc][6] = bflo(u.w) * d2; a[kc][7] = bfhi(u.w) * d2;
  }
  float a5 = 0.f, a64 = 0.f;
  if (kg == 0) { float2 v = np[node]; a5 = d2 * v.x; a64 = d2 * v.y; }
  int s_ = valid ? rowstart[node] : 0;
  int e_ = valid ? rowstart[node + 1] : 0;
  int j = s_;
  for (; j + 2 <= e_; j += 2) {
    int2 sA = sedge[j], sB = sedge[j + 1];
    float wA = __int_as_float(sA.y), wB = __int_as_float(sB.y);
    uint4 uA[2], uB[2];
    #pragma unroll
    for (int kc = 0; kc < 2; ++kc) uA[kc] = x4[(size_t)sA.x * 8 + kc * 4 + kg];
    #pragma unroll
    for (int kc = 0; kc < 2; ++kc) uB[kc] = x4[(size_t)sB.x * 8 + kc * 4 + kg];
    float2 vA, vB;
    if (kg == 0) { vA = np[sA.x]; vB = np[sB.x]; }
    #pragma unroll
    for (int kc = 0; kc < 2; ++kc) {
      a[kc][0] = fmaf(bflo(uA[kc].x), wA, a[kc][0]); a[kc][1] = fmaf(bfhi(uA[kc].x), wA, a[kc][1]);
      a[kc][2] = fmaf(bflo(uA[kc].y), wA, a[kc][2]); a[kc][3] = fmaf(bfhi(uA[kc].y), wA, a[kc][3]);
      a[kc][4] = fmaf(bflo(uA[kc].z), wA, a[kc][4]); a[kc][5] = fmaf(bfhi(uA[kc].z), wA, a[kc][5]);
      a[kc][6] = fmaf(bflo(uA[kc].w), wA, a[kc][6]); a[kc][7] = fmaf(bfhi(uA[kc].w), wA, a[kc][7]);
      a[kc][0] = fmaf(bflo(uB[kc].x), wB, a[kc][0]); a[kc][1] = fmaf(bfhi(uB[kc].x), wB, a[kc][1]);
      a[kc][2] = fmaf(bflo(uB[kc].y), wB, a[kc][2]); a[kc][3] = fmaf(bfhi(uB[kc].y), wB, a[kc][3]);
      a[kc][4] = fmaf(bflo(uB[kc].z), wB, a[kc][4]); a[kc][5] = fmaf(bfhi(uB[kc].z), wB, a[kc][5]);
      a[kc][6] = fmaf(bflo(uB[kc].w), wB, a[kc][6]); a[kc][7] = fmaf(bfhi(uB[kc].w), wB, a[kc][7]);
    }
    if (kg == 0) {
      a5 = fmaf(vA.x, wA, a5); a64 = fmaf(vA.y, wA, a64);
      a5 = fmaf(vB.x, wB, a5); a64 = fmaf(vB.y, wB, a64);
    }
  }
  if (j < e_) {
    int2 sA = sedge[j];
    float wA = __int_as_float(sA.y);
    #pragma unroll
    for (int kc = 0; kc < 2; ++kc) {
      uint4 u = x4[(size_t)sA.x * 8 + kc * 4 + kg];
      a[kc][0] = fmaf(bflo(u.x), wA, a[kc][0]); a[kc][1] = fmaf(bfhi(u.x), wA, a[kc][1]);
      a[kc][2] = fmaf(bflo(u.y), wA, a[kc][2]); a[kc][3] = fmaf(bfhi(u.y), wA, a[kc][3]);
      a[kc][4] = fmaf(bflo(u.z), wA, a[kc][4]); a[kc][5] = fmaf(bfhi(u.z), wA, a[kc][5]);
      a[kc][6] = fmaf(bflo(u.w), wA, a[kc][6]); a[kc][7] = fmaf(bfhi(u.w), wA, a[kc][7]);
    }
    if (kg == 0) {
      float2 v = np[sA.x];
      a5 = fmaf(v.x, wA, a5); a64 = fmaf(v.y, wA, a64);
    }
  }
  bf16x8 af[2];
  #pragma unroll
  for (int kc = 0; kc < 2; ++kc) {
    uint4 pk;
    pk.x = (unsigned)f2bf(a[kc][0]) | ((unsigned)f2bf(a[kc][1]) << 16);
    pk.y = (unsigned)f2bf(a[kc][2]) | ((unsigned)f2bf(a[kc][3]) << 16);
    pk.z = (unsigned)f2bf(a[kc][4]) | ((unsigned)f2bf(a[kc][5]) << 16);
    pk.w = (unsigned)f2bf(a[kc][6]) | ((unsigned)f2bf(a[kc][7]) << 16);
    af[kc] = *(bf16x8*)&pk;
  }
  f32x4 acc[8];
  #pragma unroll
  for (int nt = 0; nt < 8; ++nt) acc[nt] = (f32x4){0.f, 0.f, 0.f, 0.f};
  const unsigned short* wp = Wpk0 + (size_t)l * 8;
  #pragma unroll
  for (int kc = 0; kc < 2; ++kc) {
    bf16x8 bf[8];
    #pragma unroll
    for (int nt = 0; nt < 8; ++nt)
      bf[nt] = *(const bf16x8*)(wp + (size_t)(nt * 2 + kc) * 512);
    #pragma unroll
    for (int nt = 0; nt < 8; ++nt)
      acc[nt] = __builtin_amdgcn_mfma_f32_16x16x32_bf16(af[kc], bf[nt], acc[nt], 0, 0, 0);
  }
  int colb = l & 15, rb = kg * 4;
  float2 ax[4];
  #pragma unroll
  for (int jj = 0; jj < 4; ++jj) {
    ax[jj].x = __shfl(a5, rb + jj, 64);
    ax[jj].y = __shfl(a64, rb + jj, 64);
  }
  #pragma unroll
  for (int nt = 0; nt < 8; ++nt) {
    int c = nt * 16 + colb;
    float w5 = cw0[5 * 128 + c], w64 = cw0[64 * 128 + c];
    float S = bnS[c], T = bnT[c];
    #pragma unroll
    for (int jj = 0; jj < 4; ++jj) {
      float z = acc[nt][jj] + ax[jj].x * w5 + ax[jj].y * w64;
      float v = fmaf(z, S, T);
      v = v > 0.f ? v : expf(v) - 1.f;   // ELU
      tile[wid][rb + jj][c] = f2bf(v);
    }
  }
  __syncthreads();
  #pragma unroll
  for (int i = 0; i < 4; ++i) {
    int m = i * 64 + l;
    int rr = m >> 4, chunk = m & 15;
    uint4 v = *(const uint4*)&tile[wid][rr][chunk * 8];
    *(uint4*)&hOut[(row0w + rr) * 128 + chunk * 8] = v;
  }
}

// ---------- fused pooling + head (per-wave LDS pooled vector) ----------

__global__ __launch_bounds__(256)
void gcn_poolhead(const unsigned short* __restrict__ hB, const int* __restrict__ gstart,
                  const float* __restrict__ hw1, const float* __restrict__ hb1,
                  const float* __restrict__ hw2, const float* __restrict__ hb2,
                  float* __restrict__ out, int G) {
  __shared__ float pl[4][128];
  int wid = threadIdx.x >> 6, lane = threadIdx.x & 63;
  int g = blockIdx.x * 4 + wid;
  if (g >= G) return;
  int s = gstart[g], e = gstart[g + 1];
  const unsigned int* h32 = (const unsigned int*)hB;
  float ax = 0.f, ay = 0.f;
  int i = s;
  for (; i + 2 <= e; i += 2) {
    unsigned int u0 = h32[(size_t)i * 64 + lane];
    unsigned int u1 = h32[(size_t)(i + 1) * 64 + lane];
    ax += bflo(u0) + bflo(u1);
    ay += bfhi(u0) + bfhi(u1);
  }
  if (i < e) {
    unsigned int u = h32[(size_t)i * 64 + lane];
    ax += bflo(u); ay += bfhi(u);
  }
  float r = 1.0f / fmaxf((float)(e - s), 1.0f);
  pl[wid][lane * 2] = ax * r;
  pl[wid][lane * 2 + 1] = ay * r;
  // same-wave LDS write->read: compiler-inserted lgkmcnt suffices, no barrier
  float acc = hb1[lane];
  #pragma unroll 8
  for (int k = 0; k < 128; ++k) acc = fmaf(pl[wid][k], hw1[k * 64 + lane], acc);
  float t2 = acc > 0.f ? acc : expf(acc) - 1.f;   // ELU
  t2 *= hw2[lane];
  #pragma unroll
  for (int off = 32; off; off >>= 1) t2 += __shfl_down(t2, off, 64);
  if (lane == 0) out[g] = t2 + hb2[0];
}

// ---------- launch ----------

extern "C" void kernel_launch(void* const* d_in, const int* in_sizes, int n_in,
                              void* d_out, int out_size, void* d_ws, size_t ws_size,
                              hipStream_t stream) {
  const float* x   = (const float*)d_in[0];
  const int*   ei  = (const int*)d_in[1];
  const int*   batch = (const int*)d_in[2];
  const float* w1  = (const float*)d_in[3];
  const float* b1  = (const float*)d_in[4];
  const float* w2  = (const float*)d_in[5];
  const float* cw0 = (const float*)d_in[6];
  const float* cb0 = (const float*)d_in[7];
  const float* cwr = (const float*)d_in[8];
  const float* cbr = (const float*)d_in[9];
  const float* bng = (const float*)d_in[10];
  const float* bnb = (const float*)d_in[11];
  const float* bnm = (const float*)d_in[12];
  const float* bnv = (const float*)d_in[13];
  const float* hw1 = (const float*)d_in[14];
  const float* hb1 = (const float*)d_in[15];
  const float* hw2 = (const float*)d_in[16];
  const float* hb2 = (const float*)d_in[17];
  float* out = (float*)d_out;
  (void)n_in; (void)ws_size;

  const int n = in_sizes[0] / 64;
  const int e = in_sizes[1] / 2;
  const int G = out_size;
  const int* row = ei;
  const int* col = ei + e;
  const int nb128 = (n + 127) / 128;
  const int n_pad = nb128 * 128;

  char* p = (char*)d_ws;
  auto take = [&](size_t bytes) { char* r = p; p += (bytes + 255) & ~(size_t)255; return r; };
  float* cnt    = (float*)take((size_t)SS * 4);
  float* sums   = (float*)take((size_t)SS * 64 * 4);
  float* attn   = (float*)take((size_t)SS * 4);
  float* dinv   = (float*)take((size_t)n * 4);
  int*   rowst  = (int*)take(((size_t)n + 1) * 4);
  int*   fill   = (int*)take((size_t)n * 4);
  int*   pos    = (int*)take((size_t)e * 4);
  int*   bsum   = (int*)take(128 * 4);
  int*   gstart = (int*)take(((size_t)G + 1) * 4);
  int2*  sedge  = (int2*)take((size_t)e * 8);
  float2* np    = (float2*)take((size_t)n * 8);
  unsigned int* xh = (unsigned int*)take((size_t)n * 32 * 4);
  unsigned short* hP0 = (unsigned short*)take((size_t)n_pad * HH * 2);
  unsigned short* hP1 = (unsigned short*)take((size_t)n_pad * HH * 2);
  unsigned short* wpk0 = (unsigned short*)take((size_t)8 * 2 * 64 * 8 * 2);
  unsigned short* wpkr = (unsigned short*)take((size_t)3 * 8 * 4 * 64 * 8 * 2);
  float* bnS    = (float*)take(4 * 128 * 4);
  float* bnT    = (float*)take(4 * 128 * 4);

  hipMemsetAsync(cnt, 0, (size_t)SS * 4, stream);
  hipMemsetAsync(sums, 0, (size_t)SS * 64 * 4, stream);
  hipMemsetAsync(fill, 0, (size_t)n * 4, stream);

  // FRONT1: the two atomic passes
  int nbPos = (e + 255) / 256;
  int nbSub = (n + 3) / 4;
  gcn_front1<<<nbPos + nbSub, 256, 0, stream>>>(col, fill, pos, x, cnt, sums, n, e, nbPos);

  gcn_scores<<<SS / 4, 256, 0, stream>>>(sums, cnt, w1, b1, w2, attn);
  gcn_softmax<<<1, 1024, 0, stream>>>(attn);

  int nb = (n + 1023) / 1024;
  gcn_scan1<<<nb, 1024, 0, stream>>>(fill, rowst, bsum, dinv, n);
  gcn_scan2<<<1, 128, 0, stream>>>(bsum, nb);
  gcn_scan3<<<nb, 1024, 0, stream>>>(rowst, bsum, n, e);

  // FRONT3: scatter + all remaining prep
  int nbSc = (e + 255) / 256;
  int nbNp = (n + 255) / 256;
  int nbXb = (n * 32 + 255) / 256;
  int nbGb = (G + 1 + 255) / 256;
  int nbW0 = 4, nbWr = 8, nbBnp = 2;
  int front3 = nbSc + nbNp + nbXb + nbGb + nbW0 + 3 * nbWr + nbBnp;
  gcn_front3<<<front3, 256, 0, stream>>>(x, attn, np, row, col, pos, rowst, dinv, sedge,
      xh, batch, gstart, cw0, cwr, wpk0, wpkr, cb0, cbr, bng, bnb, bnm, bnv, bnS, bnT,
      n, e, G, nbSc, nbNp, nbXb, nbGb, nbW0, nbWr);

  // fused layers (ping-pong hP0/hP1)
  gcn_layer0_f<<<n_pad / 64, 256, 0, stream>>>(xh, np, sedge, rowst, dinv, wpk0, cw0,
      bnS, bnT, hP0, n);
  gcn_layer_f<<<n_pad / 64, 256, 0, stream>>>(hP0, sedge, rowst, dinv, wpkr,
      bnS + 128, bnT + 128, hP1, 0, n);
  gcn_layer_f<<<n_pad / 64, 256, 0, stream>>>(hP1, sedge, rowst, dinv,
      wpkr + (size_t)8 * 4 * 64 * 8, bnS + 256, bnT + 256, hP0, 0, n);
  gcn_layer_f<<<n_pad / 64, 256, 0, stream>>>(hP0, sedge, rowst, dinv,
      wpkr + (size_t)2 * 8 * 4 * 64 * 8, bnS + 384, bnT + 384, hP1, 1, n);

  gcn_poolhead<<<(G + 3) / 4, 256, 0, stream>>>(hP1, gstart, hw1, hb1, hw2, hb2, out, G);
}

// Round 12
// 606.551 us; speedup vs baseline: 3.2002x; 1.0040x over previous
//
#include <hip/hip_runtime.h>
#include <math.h>

static constexpr int SS = 4096;   // substructures
static constexpr int HH = 128;    // hidden
static constexpr float EPS_BN = 1e-5f;

typedef __attribute__((ext_vector_type(8))) short bf16x8;
typedef __attribute__((ext_vector_type(4))) float f32x4;

__device__ inline unsigned short f2bf(float f) {       // RNE fp32 -> bf16
  unsigned int u = __float_as_uint(f);
  return (unsigned short)((u + 0x7fffu + ((u >> 16) & 1u)) >> 16);
}
__device__ inline float bflo(unsigned int u) { return __uint_as_float(u << 16); }
__device__ inline float bfhi(unsigned int u) { return __uint_as_float(u & 0xffff0000u); }

// ---------- FRONT1: the two atomic passes only ----------

__global__ __launch_bounds__(256)
void gcn_front1(const int* __restrict__ col, int* __restrict__ fill, int* __restrict__ pos,
                const float* __restrict__ x, float* __restrict__ cnt, float* __restrict__ sums,
                int n, int e, int nbPos) {
  int b = blockIdx.x;
  int t = threadIdx.x;
  if (b < nbPos) {                       // one atomic pass: slot + degree
    int i = b * 256 + t;
    if (i < e) pos[i] = atomicAdd(&fill[col[i]], 1);
    return;
  }
  b -= nbPos;
  {                                      // substructure sums (coalesced atomics)
    int node = b * 4 + (t >> 6);
    int lane = t & 63;
    if (node >= n) return;
    const float* xr = x + (size_t)node * 64;
    float v = xr[lane];
    int sid = (int)__shfl(v, 5, 64);
    if (lane == 0) atomicAdd(&cnt[sid], 1.0f);
    atomicAdd(&sums[(size_t)sid * 64 + lane], v);
  }
}

// ---------- substructure attention (scores + softmax) ----------

__global__ void gcn_scores(const float* __restrict__ sums, const float* __restrict__ cnt,
                           const float* __restrict__ w1, const float* __restrict__ b1,
                           const float* __restrict__ w2, float* __restrict__ scores) {
  int s = blockIdx.x * 4 + (threadIdx.x >> 6);
  int j = threadIdx.x & 63;
  float r = 1.0f / fmaxf(cnt[s], 1.0f);
  const float* ss = sums + (size_t)s * 64;
  float acc = b1[j];
  #pragma unroll 8
  for (int d = 0; d < 64; ++d) acc = fmaf(ss[d] * r, w1[d * 64 + j], acc);
  float t = tanhf(acc) * w2[j];
  #pragma unroll
  for (int off = 32; off; off >>= 1) t += __shfl_down(t, off, 64);
  if (j == 0) scores[s] = t;
}

__global__ void gcn_softmax(float* __restrict__ sc) {
  int t = threadIdx.x;
  int wid = t >> 6;
  float v[4]; float m = -INFINITY;
  for (int i = 0; i < 4; ++i) { v[i] = sc[t + i * 1024]; m = fmaxf(m, v[i]); }
  for (int off = 32; off; off >>= 1) m = fmaxf(m, __shfl_xor(m, off, 64));
  __shared__ float wmax[16];
  if ((t & 63) == 0) wmax[wid] = m;
  __syncthreads();
  if (t == 0) { float mm = wmax[0]; for (int i = 1; i < 16; ++i) mm = fmaxf(mm, wmax[i]); wmax[0] = mm; }
  __syncthreads();
  float M = wmax[0];
  float s = 0.f;
  for (int i = 0; i < 4; ++i) { v[i] = expf(v[i] - M); s += v[i]; }
  for (int off = 32; off; off >>= 1) s += __shfl_xor(s, off, 64);
  __shared__ float wsum[16];
  if ((t & 63) == 0) wsum[wid] = s;
  __syncthreads();
  if (t == 0) { float ts = 0.f; for (int i = 0; i < 16; ++i) ts += wsum[i]; wsum[0] = ts; }
  __syncthreads();
  float inv = 1.0f / wsum[0];
  for (int i = 0; i < 4; ++i) sc[t + i * 1024] = v[i] * inv;
}

// ---------- scan (dinv + degree histogram fused into pass 1) ----------

__global__ void gcn_scan1(const int* __restrict__ fill, int* __restrict__ rowstart,
                          int* __restrict__ bsum, float* __restrict__ dinv,
                          int* __restrict__ bh, int n) {
  __shared__ int tmp[1024];
  __shared__ int hist[64];
  int t = threadIdx.x; int g = blockIdx.x * 1024 + t;
  if (t < 64) hist[t] = 0;
  int v = (g < n) ? fill[g] : 0;
  if (g < n) dinv[g] = rsqrtf((float)v + 1.0f);   // +1 = self loop
  tmp[t] = v; __syncthreads();
  if (g < n) atomicAdd(&hist[v > 63 ? 63 : v], 1);
  for (int off = 1; off < 1024; off <<= 1) {
    int a = (t >= off) ? tmp[t - off] : 0; __syncthreads();
    tmp[t] += a; __syncthreads();
  }
  if (g < n) rowstart[g] = tmp[t] - v;
  if (t == 1023) bsum[blockIdx.x] = tmp[t];
  if (t < 64) bh[blockIdx.x * 64 + t] = hist[t];
}

__global__ void gcn_scan2(int* __restrict__ bsum, int nb) {
  __shared__ int tmp[128];
  int t = threadIdx.x;
  int v = (t < nb) ? bsum[t] : 0;
  tmp[t] = v; __syncthreads();
  for (int off = 1; off < 128; off <<= 1) {
    int a = (t >= off) ? tmp[t - off] : 0; __syncthreads();
    tmp[t] += a; __syncthreads();
  }
  if (t < nb) bsum[t] = tmp[t] - v;
}

__global__ void gcn_scan3(int* __restrict__ rowstart, const int* __restrict__ bsum, int n, int e) {
  int g = blockIdx.x * 1024 + threadIdx.x;
  if (g < n) rowstart[g] += bsum[blockIdx.x];
  if (g == 0) rowstart[n] = e;
}

// ---------- degree sort: bin offsets + scatter to perm (descending degree) ----------

__global__ void gcn_dscan(int* __restrict__ bh, int* __restrict__ binbase, int nbh) {
  int t = threadIdx.x;                   // bin, 64 threads = 1 wave
  int tot = 0;
  for (int b = 0; b < nbh; ++b) {
    int v = bh[b * 64 + t];
    bh[b * 64 + t] = tot;                // per-block exclusive within bin
    tot += v;
  }
  int s = tot;
  #pragma unroll
  for (int off = 1; off < 64; off <<= 1) {
    int u = __shfl_up(s, off, 64);
    if (t >= off) s += u;
  }
  binbase[t] = s - tot;                  // cross-bin exclusive base
}

__global__ void gcn_dscatter(const int* __restrict__ fill, const int* __restrict__ bh,
                             const int* __restrict__ binbase, int* __restrict__ perm, int n) {
  __shared__ int h[64];
  int t = threadIdx.x;                   // 1024 threads, 1024 nodes/block
  if (t < 64) h[t] = bh[blockIdx.x * 64 + t] + binbase[t];
  __syncthreads();
  int i = blockIdx.x * 1024 + t;
  if (i < n) {
    int d = fill[i]; if (d > 63) d = 63;
    int p = atomicAdd(&h[d], 1);
    perm[n - 1 - p] = i;                 // descending: heavy blocks dispatch first
  }
}

// ---------- FRONT3: scatter || np || xb || gb || wpack x4 || bnp ----------

__device__ void wpack_body(const float* __restrict__ W, unsigned short* __restrict__ out,
                           int nkc, int idx) {
  if (idx >= 8 * nkc * 64) return;
  int lane = idx & 63;
  int kc = (idx >> 6) % nkc;
  int nt = idx / (64 * nkc);
  int colc = nt * 16 + (lane & 15);
  int k0 = kc * 32 + (lane >> 4) * 8;
  unsigned int w[4];
  #pragma unroll
  for (int i = 0; i < 4; ++i) {
    unsigned short a = f2bf(W[(size_t)(k0 + 2 * i) * 128 + colc]);
    unsigned short b = f2bf(W[(size_t)(k0 + 2 * i + 1) * 128 + colc]);
    w[i] = (unsigned int)a | ((unsigned int)b << 16);
  }
  *(uint4*)&out[(size_t)idx * 8] = make_uint4(w[0], w[1], w[2], w[3]);
}

__global__ __launch_bounds__(256)
void gcn_front3(const float* __restrict__ x, const float* __restrict__ attn,
                float2* __restrict__ np,
                const int* __restrict__ row, const int* __restrict__ col,
                const int* __restrict__ pos, const int* __restrict__ rowstart,
                const float* __restrict__ dinv, int2* __restrict__ sedge,
                unsigned int* __restrict__ xh, const int* __restrict__ batch,
                int* __restrict__ gstart,
                const float* __restrict__ cw0, const float* __restrict__ cwr,
                unsigned short* __restrict__ wpk0, unsigned short* __restrict__ wpkr,
                const float* __restrict__ cb0, const float* __restrict__ cbr,
                const float* __restrict__ bng, const float* __restrict__ bnb,
                const float* __restrict__ bnm, const float* __restrict__ bnv,
                float* __restrict__ bnS, float* __restrict__ bnT,
                int n, int e, int G,
                int nbSc, int nbNp, int nbXb, int nbGb, int nbW0, int nbWr) {
  int b = blockIdx.x;
  int t = threadIdx.x;
  if (b < nbSc) {                        // atomic-free CSR scatter
    int i = b * 256 + t;
    if (i >= e) return;
    int c = col[i], r = row[i];
    sedge[rowstart[c] + pos[i]] = make_int2(r, __float_as_int(dinv[r] * dinv[c]));
    return;
  }
  b -= nbSc;
  if (b < nbNp) {                        // per-node {sid, attn}
    int i = b * 256 + t;
    if (i >= n) return;
    int sid = (int)x[(size_t)i * 64 + 5];
    np[i] = make_float2((float)sid, attn[sid]);
    return;
  }
  b -= nbNp;
  if (b < nbXb) {                        // bf16 x with col5 zeroed
    int i = b * 256 + t;
    if (i >= n * 32) return;
    int pr = i & 31;
    float2 v = *(const float2*)&x[(size_t)(i >> 5) * 64 + pr * 2];
    if (pr == 2) v.y = 0.f;
    xh[i] = (unsigned int)f2bf(v.x) | ((unsigned int)f2bf(v.y) << 16);
    return;
  }
  b -= nbXb;
  if (b < nbGb) {                        // graph starts (batch sorted)
    int g = b * 256 + t;
    if (g > G) return;
    if (g == G) { gstart[G] = n; return; }
    int lo = 0, hi = n;
    while (lo < hi) { int mid = (lo + hi) >> 1; if (batch[mid] < g) lo = mid + 1; else hi = mid; }
    gstart[g] = lo;
    return;
  }
  b -= nbGb;
  if (b < nbW0) { wpack_body(cw0, wpk0, 2, b * 256 + t); return; }
  b -= nbW0;
  if (b < 3 * nbWr) {
    int l = b / nbWr, bb = b % nbWr;
    wpack_body(cwr + (size_t)l * HH * HH, wpkr + (size_t)l * 8 * 4 * 64 * 8, 4, bb * 256 + t);
    return;
  }
  b -= 3 * nbWr;
  {                                      // fold BN
    int i = b * 256 + t;
    if (i >= 512) return;
    int l = i >> 7, c = i & 127;
    float S = rsqrtf(bnv[i] + EPS_BN) * bng[i];
    float bias = (l == 0) ? cb0[c] : cbr[(l - 1) * 128 + c];
    bnS[i] = S;
    bnT[i] = fmaf(bias - bnm[i], S, bnb[i]);
  }
}

// ---------- fused layer 1-3: degree-sorted gather (2-edge unrolled) + MFMA + BN + act ----------

__global__ __launch_bounds__(256)
void gcn_layer_f(const unsigned short* __restrict__ hIn, const int2* __restrict__ sedge,
                 const int* __restrict__ rowstart, const float* __restrict__ dinv,
                 const int* __restrict__ perm,
                 const unsigned short* __restrict__ Wpk,
                 const float* __restrict__ bnS, const float* __restrict__ bnT,
                 unsigned short* __restrict__ hOut, int relu, int n) {
  __shared__ unsigned short tile[4][16][136];
  int t = threadIdx.x;
  int wid = t >> 6, l = t & 63;
  int r = l & 15, kg = l >> 4;
  size_t row0w = (size_t)blockIdx.x * 64 + wid * 16;
  int tileRow = (int)row0w + r;
  bool valid = tileRow < n;
  int pidx = valid ? tileRow : 0;
  int node = valid ? perm[pidx] : tileRow;   // same-degree nodes share the wave
  int nrd = valid ? node : 0;
  float di = dinv[nrd], d2 = di * di;
  const uint4* h4 = (const uint4*)hIn;
  float a[4][8];
  #pragma unroll
  for (int kc = 0; kc < 4; ++kc) {
    uint4 u = h4[(size_t)nrd * 16 + kc * 4 + kg];
    a[kc][0] = bflo(u.x) * d2; a[kc][1] = bfhi(u.x) * d2;
    a[kc][2] = bflo(u.y) * d2; a[kc][3] = bfhi(u.y) * d2;
    a[kc][4] = bflo(u.z) * d2; a[kc][5] = bfhi(u.z) * d2;
    a[kc][6] = bflo(u.w) * d2; a[kc][7] = bfhi(u.w) * d2;
  }
  int s_ = valid ? rowstart[nrd] : 0;
  int e_ = valid ? rowstart[nrd + 1] : 0;
  int j = s_;
  for (; j + 2 <= e_; j += 2) {          // 8 row-loads in flight
    int2 sA = sedge[j], sB = sedge[j + 1];
    float wA = __int_as_float(sA.y), wB = __int_as_float(sB.y);
    uint4 uA[4], uB[4];
    #pragma unroll
    for (int kc = 0; kc < 4; ++kc) uA[kc] = h4[(size_t)sA.x * 16 + kc * 4 + kg];
    #pragma unroll
    for (int kc = 0; kc < 4; ++kc) uB[kc] = h4[(size_t)sB.x * 16 + kc * 4 + kg];
    #pragma unroll
    for (int kc = 0; kc < 4; ++kc) {
      a[kc][0] = fmaf(bflo(uA[kc].x), wA, a[kc][0]); a[kc][1] = fmaf(bfhi(uA[kc].x), wA, a[kc][1]);
      a[kc][2] = fmaf(bflo(uA[kc].y), wA, a[kc][2]); a[kc][3] = fmaf(bfhi(uA[kc].y), wA, a[kc][3]);
      a[kc][4] = fmaf(bflo(uA[kc].z), wA, a[kc][4]); a[kc][5] = fmaf(bfhi(uA[kc].z), wA, a[kc][5]);
      a[kc][6] = fmaf(bflo(uA[kc].w), wA, a[kc][6]); a[kc][7] = fmaf(bfhi(uA[kc].w), wA, a[kc][7]);
    }
    #pragma unroll
    for (int kc = 0; kc < 4; ++kc) {
      a[kc][0] = fmaf(bflo(uB[kc].x), wB, a[kc][0]); a[kc][1] = fmaf(bfhi(uB[kc].x), wB, a[kc][1]);
      a[kc][2] = fmaf(bflo(uB[kc].y), wB, a[kc][2]); a[kc][3] = fmaf(bfhi(uB[kc].y), wB, a[kc][3]);
      a[kc][4] = fmaf(bflo(uB[kc].z), wB, a[kc][4]); a[kc][5] = fmaf(bfhi(uB[kc].z), wB, a[kc][5]);
      a[kc][6] = fmaf(bflo(uB[kc].w), wB, a[kc][6]); a[kc][7] = fmaf(bfhi(uB[kc].w), wB, a[kc][7]);
    }
  }
  if (j < e_) {
    int2 sA = sedge[j];
    float wA = __int_as_float(sA.y);
    #pragma unroll
    for (int kc = 0; kc < 4; ++kc) {
      uint4 u = h4[(size_t)sA.x * 16 + kc * 4 + kg];
      a[kc][0] = fmaf(bflo(u.x), wA, a[kc][0]); a[kc][1] = fmaf(bfhi(u.x), wA, a[kc][1]);
      a[kc][2] = fmaf(bflo(u.y), wA, a[kc][2]); a[kc][3] = fmaf(bfhi(u.y), wA, a[kc][3]);
      a[kc][4] = fmaf(bflo(u.z), wA, a[kc][4]); a[kc][5] = fmaf(bfhi(u.z), wA, a[kc][5]);
      a[kc][6] = fmaf(bflo(u.w), wA, a[kc][6]); a[kc][7] = fmaf(bfhi(u.w), wA, a[kc][7]);
    }
  }
  bf16x8 af[4];
  #pragma unroll
  for (int kc = 0; kc < 4; ++kc) {
    uint4 pk;
    pk.x = (unsigned)f2bf(a[kc][0]) | ((unsigned)f2bf(a[kc][1]) << 16);
    pk.y = (unsigned)f2bf(a[kc][2]) | ((unsigned)f2bf(a[kc][3]) << 16);
    pk.z = (unsigned)f2bf(a[kc][4]) | ((unsigned)f2bf(a[kc][5]) << 16);
    pk.w = (unsigned)f2bf(a[kc][6]) | ((unsigned)f2bf(a[kc][7]) << 16);
    af[kc] = *(bf16x8*)&pk;
  }
  f32x4 acc[8];
  #pragma unroll
  for (int nt = 0; nt < 8; ++nt) acc[nt] = (f32x4){0.f, 0.f, 0.f, 0.f};
  const unsigned short* wp = Wpk + (size_t)l * 8;
  #pragma unroll
  for (int kc = 0; kc < 4; ++kc) {
    bf16x8 bf[8];
    #pragma unroll
    for (int nt = 0; nt < 8; ++nt)
      bf[nt] = *(const bf16x8*)(wp + (size_t)(nt * 4 + kc) * 512);
    #pragma unroll
    for (int nt = 0; nt < 8; ++nt)
      acc[nt] = __builtin_amdgcn_mfma_f32_16x16x32_bf16(af[kc], bf[nt], acc[nt], 0, 0, 0);
  }
  int colb = l & 15, rb = kg * 4;
  #pragma unroll
  for (int nt = 0; nt < 8; ++nt) {
    int c = nt * 16 + colb;
    float S = bnS[c], T = bnT[c];
    #pragma unroll
    for (int jj = 0; jj < 4; ++jj) {
      float v = fmaf(acc[nt][jj], S, T);
      v = relu ? fmaxf(v, 0.f) : (v > 0.f ? v : expf(v) - 1.f);
      tile[wid][rb + jj][c] = f2bf(v);
    }
  }
  // per-row store target: valid rows -> their node's row; pad rows -> own pad slot
  __shared__ int srow[4][16];
  if (kg == 0) srow[wid][r] = valid ? node : tileRow;
  __syncthreads();
  #pragma unroll
  for (int i = 0; i < 4; ++i) {
    int m = i * 64 + l;
    int rr = m >> 4, chunk = m & 15;
    uint4 v = *(const uint4*)&tile[wid][rr][chunk * 8];
    *(uint4*)&hOut[(size_t)srow[wid][rr] * 128 + chunk * 8] = v;
  }
}

// ---------- fused layer 0 (K=64 + exact fp32 sid/attn), degree-sorted ----------

__global__ __launch_bounds__(256)
void gcn_layer0_f(const unsigned int* __restrict__ xh, const float2* __restrict__ np,
                  const int2* __restrict__ sedge, const int* __restrict__ rowstart,
                  const float* __restrict__ dinv, const int* __restrict__ perm,
                  const unsigned short* __restrict__ Wpk0,
                  const float* __restrict__ cw0,
                  const float* __restrict__ bnS, const float* __restrict__ bnT,
                  unsigned short* __restrict__ hOut, int n) {
  __shared__ unsigned short tile[4][16][136];
  int t = threadIdx.x;
  int wid = t >> 6, l = t & 63;
  int r = l & 15, kg = l >> 4;
  size_t row0w = (size_t)blockIdx.x * 64 + wid * 16;
  int tileRow = (int)row0w + r;
  bool valid = tileRow < n;
  int pidx = valid ? tileRow : 0;
  int node = valid ? perm[pidx] : tileRow;
  int nrd = valid ? node : 0;
  float di = dinv[nrd], d2 = di * di;
  const uint4* x4 = (const uint4*)xh;
  float a[2][8];
  #pragma unroll
  for (int kc = 0; kc < 2; ++kc) {
    uint4 u = x4[(size_t)nrd * 8 + kc * 4 + kg];
    a[kc][0] = bflo(u.x) * d2; a[kc][1] = bfhi(u.x) * d2;
    a[kc][2] = bflo(u.y) * d2; a[kc][3] = bfhi(u.y) * d2;
    a[kc][4] = bflo(u.z) * d2; a[kc][5] = bfhi(u.z) * d2;
    a[kc][6] = bflo(u.w) * d2; a[kc][7] = bfhi(u.w) * d2;
  }
  float a5 = 0.f, a64 = 0.f;
  if (kg == 0) { float2 v = np[nrd]; a5 = d2 * v.x; a64 = d2 * v.y; }
  int s_ = valid ? rowstart[nrd] : 0;
  int e_ = valid ? rowstart[nrd + 1] : 0;
  int j = s_;
  for (; j + 2 <= e_; j += 2) {
    int2 sA = sedge[j], sB = sedge[j + 1];
    float wA = __int_as_float(sA.y), wB = __int_as_float(sB.y);
    uint4 uA[2], uB[2];
    #pragma unroll
    for (int kc = 0; kc < 2; ++kc) uA[kc] = x4[(size_t)sA.x * 8 + kc * 4 + kg];
    #pragma unroll
    for (int kc = 0; kc < 2; ++kc) uB[kc] = x4[(size_t)sB.x * 8 + kc * 4 + kg];
    float2 vA, vB;
    if (kg == 0) { vA = np[sA.x]; vB = np[sB.x]; }
    #pragma unroll
    for (int kc = 0; kc < 2; ++kc) {
      a[kc][0] = fmaf(bflo(uA[kc].x), wA, a[kc][0]); a[kc][1] = fmaf(bfhi(uA[kc].x), wA, a[kc][1]);
      a[kc][2] = fmaf(bflo(uA[kc].y), wA, a[kc][2]); a[kc][3] = fmaf(bfhi(uA[kc].y), wA, a[kc][3]);
      a[kc][4] = fmaf(bflo(uA[kc].z), wA, a[kc][4]); a[kc][5] = fmaf(bfhi(uA[kc].z), wA, a[kc][5]);
      a[kc][6] = fmaf(bflo(uA[kc].w), wA, a[kc][6]); a[kc][7] = fmaf(bfhi(uA[kc].w), wA, a[kc][7]);
      a[kc][0] = fmaf(bflo(uB[kc].x), wB, a[kc][0]); a[kc][1] = fmaf(bfhi(uB[kc].x), wB, a[kc][1]);
      a[kc][2] = fmaf(bflo(uB[kc].y), wB, a[kc][2]); a[kc][3] = fmaf(bfhi(uB[kc].y), wB, a[kc][3]);
      a[kc][4] = fmaf(bflo(uB[kc].z), wB, a[kc][4]); a[kc][5] = fmaf(bfhi(uB[kc].z), wB, a[kc][5]);
      a[kc][6] = fmaf(bflo(uB[kc].w), wB, a[kc][6]); a[kc][7] = fmaf(bfhi(uB[kc].w), wB, a[kc][7]);
    }
    if (kg == 0) {
      a5 = fmaf(vA.x, wA, a5); a64 = fmaf(vA.y, wA, a64);
      a5 = fmaf(vB.x, wB, a5); a64 = fmaf(vB.y, wB, a64);
    }
  }
  if (j < e_) {
    int2 sA = sedge[j];
    float wA = __int_as_float(sA.y);
    #pragma unroll
    for (int kc = 0; kc < 2; ++kc) {
      uint4 u = x4[(size_t)sA.x * 8 + kc * 4 + kg];
      a[kc][0] = fmaf(bflo(u.x), wA, a[kc][0]); a[kc][1] = fmaf(bfhi(u.x), wA, a[kc][1]);
      a[kc][2] = fmaf(bflo(u.y), wA, a[kc][2]); a[kc][3] = fmaf(bfhi(u.y), wA, a[kc][3]);
      a[kc][4] = fmaf(bflo(u.z), wA, a[kc][4]); a[kc][5] = fmaf(bfhi(u.z), wA, a[kc][5]);
      a[kc][6] = fmaf(bflo(u.w), wA, a[kc][6]); a[kc][7] = fmaf(bfhi(u.w), wA, a[kc][7]);
    }
    if (kg == 0) {
      float2 v = np[sA.x];
      a5 = fmaf(v.x, wA, a5); a64 = fmaf(v.y, wA, a64);
    }
  }
  bf16x8 af[2];
  #pragma unroll
  for (int kc = 0; kc < 2; ++kc) {
    uint4 pk;
    pk.x = (unsigned)f2bf(a[kc][0]) | ((unsigned)f2bf(a[kc][1]) << 16);
    pk.y = (unsigned)f2bf(a[kc][2]) | ((unsigned)f2bf(a[kc][3]) << 16);
    pk.z = (unsigned)f2bf(a[kc][4]) | ((unsigned)f2bf(a[kc][5]) << 16);
    pk.w = (unsigned)f2bf(a[kc][6]) | ((unsigned)f2bf(a[kc][7]) << 16);
    af[kc] = *(bf16x8*)&pk;
  }
  f32x4 acc[8];
  #pragma unroll
  for (int nt = 0; nt < 8; ++nt) acc[nt] = (f32x4){0.f, 0.f, 0.f, 0.f};
  const unsigned short* wp = Wpk0 + (size_t)l * 8;
  #pragma unroll
  for (int kc = 0; kc < 2; ++kc) {
    bf16x8 bf[8];
    #pragma unroll
    for (int nt = 0; nt < 8; ++nt)
      bf[nt] = *(const bf16x8*)(wp + (size_t)(nt * 2 + kc) * 512);
    #pragma unroll
    for (int nt = 0; nt < 8; ++nt)
      acc[nt] = __builtin_amdgcn_mfma_f32_16x16x32_bf16(af[kc], bf[nt], acc[nt], 0, 0, 0);
  }
  int colb = l & 15, rb = kg * 4;
  float2 ax[4];
  #pragma unroll
  for (int jj = 0; jj < 4; ++jj) {
    ax[jj].x = __shfl(a5, rb + jj, 64);
    ax[jj].y = __shfl(a64, rb + jj, 64);
  }
  #pragma unroll
  for (int nt = 0; nt < 8; ++nt) {
    int c = nt * 16 + colb;
    float w5 = cw0[5 * 128 + c], w64 = cw0[64 * 128 + c];
    float S = bnS[c], T = bnT[c];
    #pragma unroll
    for (int jj = 0; jj < 4; ++jj) {
      float z = acc[nt][jj] + ax[jj].x * w5 + ax[jj].y * w64;
      float v = fmaf(z, S, T);
      v = v > 0.f ? v : expf(v) - 1.f;   // ELU
      tile[wid][rb + jj][c] = f2bf(v);
    }
  }
  __shared__ int srow[4][16];
  if (kg == 0) srow[wid][r] = valid ? node : tileRow;
  __syncthreads();
  #pragma unroll
  for (int i = 0; i < 4; ++i) {
    int m = i * 64 + l;
    int rr = m >> 4, chunk = m & 15;
    uint4 v = *(const uint4*)&tile[wid][rr][chunk * 8];
    *(uint4*)&hOut[(size_t)srow[wid][rr] * 128 + chunk * 8] = v;
  }
}

// ---------- fused pooling + head (per-wave LDS pooled vector) ----------

__global__ __launch_bounds__(256)
void gcn_poolhead(const unsigned short* __restrict__ hB, const int* __restrict__ gstart,
                  const float* __restrict__ hw1, const float* __restrict__ hb1,
                  const float* __restrict__ hw2, const float* __restrict__ hb2,
                  float* __restrict__ out, int G) {
  __shared__ float pl[4][128];
  int wid = threadIdx.x >> 6, lane = threadIdx.x & 63;
  int g = blockIdx.x * 4 + wid;
  if (g >= G) return;
  int s = gstart[g], e = gstart[g + 1];
  const unsigned int* h32 = (const unsigned int*)hB;
  float ax = 0.f, ay = 0.f;
  int i = s;
  for (; i + 2 <= e; i += 2) {
    unsigned int u0 = h32[(size_t)i * 64 + lane];
    unsigned int u1 = h32[(size_t)(i + 1) * 64 + lane];
    ax += bflo(u0) + bflo(u1);
    ay += bfhi(u0) + bfhi(u1);
  }
  if (i < e) {
    unsigned int u = h32[(size_t)i * 64 + lane];
    ax += bflo(u); ay += bfhi(u);
  }
  float r = 1.0f / fmaxf((float)(e - s), 1.0f);
  pl[wid][lane * 2] = ax * r;
  pl[wid][lane * 2 + 1] = ay * r;
  float acc = hb1[lane];
  #pragma unroll 8
  for (int k = 0; k < 128; ++k) acc = fmaf(pl[wid][k], hw1[k * 64 + lane], acc);
  float t2 = acc > 0.f ? acc : expf(acc) - 1.f;   // ELU
  t2 *= hw2[lane];
  #pragma unroll
  for (int off = 32; off; off >>= 1) t2 += __shfl_down(t2, off, 64);
  if (lane == 0) out[g] = t2 + hb2[0];
}

// ---------- launch ----------

extern "C" void kernel_launch(void* const* d_in, const int* in_sizes, int n_in,
                              void* d_out, int out_size, void* d_ws, size_t ws_size,
                              hipStream_t stream) {
  const float* x   = (const float*)d_in[0];
  const int*   ei  = (const int*)d_in[1];
  const int*   batch = (const int*)d_in[2];
  const float* w1  = (const float*)d_in[3];
  const float* b1  = (const float*)d_in[4];
  const float* w2  = (const float*)d_in[5];
  const float* cw0 = (const float*)d_in[6];
  const float* cb0 = (const float*)d_in[7];
  const float* cwr = (const float*)d_in[8];
  const float* cbr = (const float*)d_in[9];
  const float* bng = (const float*)d_in[10];
  const float* bnb = (const float*)d_in[11];
  const float* bnm = (const float*)d_in[12];
  const float* bnv = (const float*)d_in[13];
  const float* hw1 = (const float*)d_in[14];
  const float* hb1 = (const float*)d_in[15];
  const float* hw2 = (const float*)d_in[16];
  const float* hb2 = (const float*)d_in[17];
  float* out = (float*)d_out;
  (void)n_in; (void)ws_size;

  const int n = in_sizes[0] / 64;
  const int e = in_sizes[1] / 2;
  const int G = out_size;
  const int* row = ei;
  const int* col = ei + e;
  const int nb128 = (n + 127) / 128;
  const int n_pad = nb128 * 128;
  const int nb1 = (n + 1023) / 1024;

  char* p = (char*)d_ws;
  auto take = [&](size_t bytes) { char* r = p; p += (bytes + 255) & ~(size_t)255; return r; };
  float* cnt    = (float*)take((size_t)SS * 4);
  float* sums   = (float*)take((size_t)SS * 64 * 4);
  float* attn   = (float*)take((size_t)SS * 4);
  float* dinv   = (float*)take((size_t)n * 4);
  int*   rowst  = (int*)take(((size_t)n + 1) * 4);
  int*   fill   = (int*)take((size_t)n * 4);
  int*   pos    = (int*)take((size_t)e * 4);
  int*   bsum   = (int*)take(128 * 4);
  int*   bh     = (int*)take((size_t)nb1 * 64 * 4);
  int*   binbase= (int*)take(64 * 4);
  int*   perm   = (int*)take((size_t)n * 4);
  int*   gstart = (int*)take(((size_t)G + 1) * 4);
  int2*  sedge  = (int2*)take((size_t)e * 8);
  float2* np    = (float2*)take((size_t)n * 8);
  unsigned int* xh = (unsigned int*)take((size_t)n * 32 * 4);
  unsigned short* hP0 = (unsigned short*)take((size_t)n_pad * HH * 2);
  unsigned short* hP1 = (unsigned short*)take((size_t)n_pad * HH * 2);
  unsigned short* wpk0 = (unsigned short*)take((size_t)8 * 2 * 64 * 8 * 2);
  unsigned short* wpkr = (unsigned short*)take((size_t)3 * 8 * 4 * 64 * 8 * 2);
  float* bnS    = (float*)take(4 * 128 * 4);
  float* bnT    = (float*)take(4 * 128 * 4);

  hipMemsetAsync(cnt, 0, (size_t)SS * 4, stream);
  hipMemsetAsync(sums, 0, (size_t)SS * 64 * 4, stream);
  hipMemsetAsync(fill, 0, (size_t)n * 4, stream);

  // FRONT1: the two atomic passes
  int nbPos = (e + 255) / 256;
  int nbSub = (n + 3) / 4;
  gcn_front1<<<nbPos + nbSub, 256, 0, stream>>>(col, fill, pos, x, cnt, sums, n, e, nbPos);

  gcn_scores<<<SS / 4, 256, 0, stream>>>(sums, cnt, w1, b1, w2, attn);
  gcn_softmax<<<1, 1024, 0, stream>>>(attn);

  gcn_scan1<<<nb1, 1024, 0, stream>>>(fill, rowst, bsum, dinv, bh, n);
  gcn_scan2<<<1, 128, 0, stream>>>(bsum, nb1);
  gcn_dscan<<<1, 64, 0, stream>>>(bh, binbase, nb1);
  gcn_scan3<<<nb1, 1024, 0, stream>>>(rowst, bsum, n, e);
  gcn_dscatter<<<nb1, 1024, 0, stream>>>(fill, bh, binbase, perm, n);

  // FRONT3: scatter + all remaining prep
  int nbSc = (e + 255) / 256;
  int nbNp = (n + 255) / 256;
  int nbXb = (n * 32 + 255) / 256;
  int nbGb = (G + 1 + 255) / 256;
  int nbW0 = 4, nbWr = 8, nbBnp = 2;
  int front3 = nbSc + nbNp + nbXb + nbGb + nbW0 + 3 * nbWr + nbBnp;
  gcn_front3<<<front3, 256, 0, stream>>>(x, attn, np, row, col, pos, rowst, dinv, sedge,
      xh, batch, gstart, cw0, cwr, wpk0, wpkr, cb0, cbr, bng, bnb, bnm, bnv, bnS, bnT,
      n, e, G, nbSc, nbNp, nbXb, nbGb, nbW0, nbWr);

  // fused layers (ping-pong hP0/hP1), degree-sorted tiles
  gcn_layer0_f<<<n_pad / 64, 256, 0, stream>>>(xh, np, sedge, rowst, dinv, perm, wpk0, cw0,
      bnS, bnT, hP0, n);
  gcn_layer_f<<<n_pad / 64, 256, 0, stream>>>(hP0, sedge, rowst, dinv, perm, wpkr,
      bnS + 128, bnT + 128, hP1, 0, n);
  gcn_layer_f<<<n_pad / 64, 256, 0, stream>>>(hP1, sedge, rowst, dinv, perm,
      wpkr + (size_t)8 * 4 * 64 * 8, bnS + 256, bnT + 256, hP0, 0, n);
  gcn_layer_f<<<n_pad / 64, 256, 0, stream>>>(hP0, sedge, rowst, dinv, perm,
      wpkr + (size_t)2 * 8 * 4 * 64 * 8, bnS + 384, bnT + 384, hP1, 1, n);

  gcn_poolhead<<<(G + 3) / 4, 256, 0, stream>>>(hP1, gstart, hw1, hb1, hw2, hb2, out, G);
}